// Round 4
// baseline (418.691 us; speedup 1.0000x reference)
//
#include <hip/hip_runtime.h>
#include <hip/hip_bf16.h>
#include <math.h>

#define B_ 16
#define T_ 12
#define N_ 325
#define DIMS_ 40
#define DAYS_ 288
#define MW 12          // bitmask words per mask row (11 used, 1 pad)
#define NQP 336        // padded N for mask rows / k-tiles (21*16)
#define PSTR 360       // S/P and Vt LDS row stride (halfwords); 720B = 2-way-free banks

typedef __attribute__((ext_vector_type(8))) short bf16x8;
typedef __attribute__((ext_vector_type(8))) unsigned short u16x8;
typedef __attribute__((ext_vector_type(4))) float f32x4;

__device__ __forceinline__ unsigned short f2b_rne(float f){
  unsigned u = __float_as_uint(f);
  return (unsigned short)((u + 0x7FFF + ((u >> 16) & 1)) >> 16);
}
__device__ __forceinline__ unsigned short f2b_trunc(float f){
  return (unsigned short)(__float_as_uint(f) >> 16);
}
__device__ __forceinline__ float b2f_us(unsigned short us){
  return __uint_as_float((unsigned)us << 16);
}

// ---------------- mask dtype detection + bitmask build ----------------
// modes: 0=uint8, 1=int32, 2=bf16, 3=f32
__global__ void mask_detect(const unsigned char* __restrict__ raw, int* __restrict__ mode){
  __shared__ int f3F_m1, f3F_m3, fNZ_o;
  if (threadIdx.x == 0){ f3F_m1 = 0; f3F_m3 = 0; fNZ_o = 0; }
  __syncthreads();
  for (int i = threadIdx.x; i < 4096; i += 256){
    unsigned char v = raw[i];
    int m4 = i & 3;
    if (v == 0x3F && m4 == 1) atomicOr(&f3F_m1, 1);
    if (v == 0x3F && m4 == 3) atomicOr(&f3F_m3, 1);
    if (v != 0 && m4 != 0)    atomicOr(&fNZ_o, 1);
  }
  __syncthreads();
  if (threadIdx.x == 0){
    int m;
    if (f3F_m1) m = 2;
    else if (f3F_m3) m = 3;
    else if (fNZ_o) m = 0;
    else m = 1;
    *mode = m;
  }
}

// bm has NQP rows; bit j of bm[q*MW+w] = masked(q, w*32+j); rows/cols >= N_ -> masked
__global__ void mask_bits(const unsigned char* __restrict__ raw, const int* __restrict__ mode_p,
                          unsigned* __restrict__ bm){
  int mode = *mode_p;
  int idx = blockIdx.x * 256 + threadIdx.x;
  if (idx >= NQP * MW) return;
  int q = idx / MW, w = idx % MW;
  unsigned bits = 0;
  if (q >= N_) { bm[idx] = 0xFFFFFFFFu; return; }
  for (int j = 0; j < 32; ++j){
    int k = w*32 + j;
    int v;
    if (k >= N_) v = 1;
    else {
      size_t i = (size_t)q*N_ + k;
      if (mode == 0)      v = raw[i] != 0;
      else if (mode == 1) v = ((const int*)raw)[i] != 0;
      else if (mode == 2) { unsigned short u = ((const unsigned short*)raw)[i]; v = (u & 0x7FFF) != 0; }
      else                { float f = ((const float*)raw)[i]; v = (f != 0.f); }
    }
    bits |= (unsigned)v << j;
  }
  bm[idx] = bits;
}

// ---------------- dynamic graph construct ----------------
__global__ void dg_a1(const float* __restrict__ p1, const float* __restrict__ pk,
                      const int* __restrict__ ind, float* __restrict__ A1){
  int b = blockIdx.x;
  __shared__ float te[DIMS_];
  int day = ind[b] % DAYS_; if (day < 0) day += DAYS_;
  for (int i = threadIdx.x; i < DIMS_; i += blockDim.x) te[i] = p1[day*DIMS_ + i];
  __syncthreads();
  for (int jk = threadIdx.x; jk < DIMS_*DIMS_; jk += blockDim.x){
    float acc = 0.f;
    for (int i = 0; i < DIMS_; ++i) acc += te[i] * pk[i*DIMS_*DIMS_ + jk];
    A1[b*DIMS_*DIMS_ + jk] = acc;
  }
}

__global__ void dg_adp(const float* __restrict__ p2, const float* __restrict__ p3,
                       const float* __restrict__ A1, float* __restrict__ adp){
  int bid = blockIdx.x; int b = bid / N_; int n = bid % N_;
  __shared__ float p2r[DIMS_], t2[DIMS_], sbuf[N_], red[128];
  int tid = threadIdx.x;
  if (tid < DIMS_) p2r[tid] = p2[n*DIMS_ + tid];
  __syncthreads();
  if (tid < DIMS_){
    float acc = 0.f;
    const float* a1 = A1 + b*DIMS_*DIMS_;
    for (int j = 0; j < DIMS_; ++j) acc += p2r[j] * a1[j*DIMS_ + tid];
    t2[tid] = acc;
  }
  __syncthreads();
  float lm = -INFINITY;
  for (int c = tid; c < N_; c += 128){
    float acc = 0.f;
    for (int k = 0; k < DIMS_; ++k) acc += p3[c*DIMS_ + k] * t2[k];
    acc = fmaxf(acc, 0.f);
    sbuf[c] = acc; lm = fmaxf(lm, acc);
  }
  red[tid] = lm; __syncthreads();
  for (int off = 64; off; off >>= 1){ if (tid < off) red[tid] = fmaxf(red[tid], red[tid+off]); __syncthreads(); }
  float m = red[0]; __syncthreads();
  float ls = 0.f;
  for (int c = tid; c < N_; c += 128){ float e = __expf(sbuf[c] - m); sbuf[c] = e; ls += e; }
  red[tid] = ls; __syncthreads();
  for (int off = 64; off; off >>= 1){ if (tid < off) red[tid] += red[tid+off]; __syncthreads(); }
  float inv = 1.f / red[0];
  float* outp = adp + ((size_t)b*N_ + n) * N_;
  for (int c = tid; c < N_; c += 128) outp[c] = sbuf[c] * inv;
}

// ---------------- weight prep ----------------
__global__ void prep_weights(const float* W_gcn, const float* b_gcn, const float* W_r2, const float* b_r2,
                             const float* Wtq, const float* Wtk, const float* Wtv,
                             const float* Wgq, const float* Wgk, const float* Wgv,
                             float* Wc, float* bc, float* Wall){
  if (blockIdx.x == 0){
    for (int idx = threadIdx.x; idx < 64*96; idx += blockDim.x){
      int d = idx / 96, c = idx % 96;
      float acc = 0.f;
      for (int o = 0; o < 32; ++o) acc += W_r2[d*32 + o] * W_gcn[o*96 + c];
      Wc[idx] = acc;
    }
    for (int d = threadIdx.x; d < 64; d += blockDim.x){
      float acc = b_r2[d];
      for (int o = 0; o < 32; ++o) acc += W_r2[d*32 + o] * b_gcn[o];
      bc[d] = acc;
    }
  } else {
    for (int idx = threadIdx.x; idx < 144*64; idx += blockDim.x){
      int j = idx >> 6, d = idx & 63;
      const float* src; int r;
      if      (j < 16) { src = Wtq; r = j; }
      else if (j < 32) { src = Wtk; r = j - 16; }
      else if (j < 48) { src = Wtv; r = j - 32; }
      else if (j < 80) { src = Wgq; r = j - 48; }
      else if (j < 112){ src = Wgk; r = j - 80; }
      else             { src = Wgv; r = j - 112; }
      Wall[idx] = src[r*64 + d];
    }
  }
}

// ---------------- h projection ----------------
__global__ void hproj(const float* __restrict__ x, const float* __restrict__ W_r1,
                      const float* __restrict__ b_r1, float* __restrict__ h){
  int bid = blockIdx.x; int b = bid / N_, n = bid % N_;
  __shared__ float xs[T_*65], Ws[32*65];
  int tid = threadIdx.x;
  for (int idx = tid; idx < 32*64; idx += 384){ int c = idx >> 6, d = idx & 63; Ws[c*65 + d] = W_r1[idx]; }
  for (int idx = tid; idx < T_*64; idx += 384){
    int t = idx >> 6, d = idx & 63;
    xs[t*65 + d] = x[(((size_t)b*T_ + t)*N_ + n)*64 + d];
  }
  __syncthreads();
  int c = tid / T_, t = tid % T_;
  float acc = b_r1[c];
  for (int d = 0; d < 64; ++d) acc += xs[t*65 + d] * Ws[c*65 + d];
  h[((size_t)b*N_ + n)*384 + c*T_ + t] = acc;
}

// ---------------- GCN hop ----------------
__global__ void gcn_mm(const float* __restrict__ adp, const float* __restrict__ in,
                       float* __restrict__ out){
  int bid = blockIdx.x;
  int b = bid / 41, wt = bid % 41;
  int w0 = wt * 8;
  __shared__ float a_s[8*64];
  int tid = threadIdx.x;
  float acc[8] = {0,0,0,0,0,0,0,0};
  const float* inb = in + (size_t)b*N_*384 + tid;
  const float* adpb = adp + (size_t)b*N_*N_;
  for (int v0 = 0; v0 < N_; v0 += 64){
    int vn = N_ - v0; if (vn > 64) vn = 64;
    __syncthreads();
    for (int idx = tid; idx < 8*64; idx += 384){
      int wr = idx >> 6, v = idx & 63;
      int w = w0 + wr;
      a_s[idx] = (w < N_ && v < vn) ? adpb[(size_t)w*N_ + v0 + v] : 0.f;
    }
    __syncthreads();
    for (int v = 0; v < vn; ++v){
      float hv = inb[(size_t)(v0 + v)*384];
      #pragma unroll
      for (int w8 = 0; w8 < 8; ++w8) acc[w8] += a_s[w8*64 + v] * hv;
    }
  }
  for (int w8 = 0; w8 < 8; ++w8){
    int w = w0 + w8;
    if (w < N_) out[((size_t)b*N_ + w)*384 + tid] = acc[w8];
  }
}

// ---------------- fused gcn-mlp + reshape2 ----------------
__global__ void xg_k(const float* __restrict__ h, const float* __restrict__ x1,
                     const float* __restrict__ x2, const float* __restrict__ Wc,
                     const float* __restrict__ bc, float* __restrict__ xg){
  int bid = blockIdx.x; int b = bid / N_, n = bid % N_;
  __shared__ float Wcs[64*97], cat_s[96*T_], bcs[64];
  int tid = threadIdx.x;
  for (int idx = tid; idx < 64*96; idx += 256){ int d = idx/96, c = idx%96; Wcs[d*97 + c] = Wc[idx]; }
  if (tid < 64) bcs[tid] = bc[tid];
  size_t base = ((size_t)b*N_ + n)*384;
  for (int idx = tid; idx < 384; idx += 256){
    cat_s[idx]       = h [base + idx];
    cat_s[384 + idx] = x1[base + idx];
    cat_s[768 + idx] = x2[base + idx];
  }
  __syncthreads();
  for (int o = tid; o < 768; o += 256){
    int t = o >> 6, d = o & 63;
    float acc = bcs[d];
    for (int c = 0; c < 96; ++c) acc += Wcs[d*97 + c] * cat_s[c*T_ + t];
    xg[(((size_t)b*T_ + t)*N_ + n)*64 + d] = acc;
  }
}

// ---------------- fused qkv projection ----------------
__global__ void qkv_k(const float* __restrict__ xg, const float* __restrict__ Wall,
                      float* __restrict__ qkv){
  int bid = blockIdx.x;
  int nt = bid % 21; int bt = bid / 21;
  int n0 = nt * 16;
  __shared__ float Ws[144*65], xs[16*64];
  int tid = threadIdx.x;
  for (int idx = tid; idx < 144*64; idx += 256){ int j = idx >> 6, d = idx & 63; Ws[j*65 + d] = Wall[idx]; }
  for (int idx = tid; idx < 16*64; idx += 256){
    int nn = idx >> 6, d = idx & 63; int n = n0 + nn;
    xs[idx] = (n < N_) ? xg[((size_t)bt*N_ + n)*64 + d] : 0.f;
  }
  __syncthreads();
  for (int idx = tid; idx < 16*144; idx += 256){
    int nn = idx / 144, j = idx % 144;
    int n = n0 + nn; if (n >= N_) continue;
    float acc = 0.f;
    const float* wrow = Ws + j*65; const float* xrow = xs + nn*64;
    for (int d = 0; d < 64; ++d) acc += wrow[d] * xrow[d];
    qkv[((size_t)bt*N_ + n)*144 + j] = acc;
  }
}

// ---------------- temporal attention ----------------
__global__ void tattn(const float* __restrict__ qkv, float* __restrict__ att){
  int bid = blockIdx.x; int b = bid / N_, n = bid % N_;
  __shared__ float qs[T_*48], ss[2*T_*T_];
  int tid = threadIdx.x;
  for (int idx = tid; idx < T_*48; idx += 64){
    int t = idx / 48, j = idx % 48;
    qs[idx] = qkv[(((size_t)b*T_ + t)*N_ + n)*144 + j];
  }
  __syncthreads();
  const float scale = 0.35355339059327373f;
  for (int idx = tid; idx < 2*T_*T_; idx += 64){
    int hh = idx / 144, r = (idx / T_) % T_, c = idx % T_;
    float acc = 0.f;
    for (int d = 0; d < 8; ++d) acc += qs[r*48 + hh*8 + d] * qs[c*48 + 16 + hh*8 + d];
    ss[idx] = acc * scale;
  }
  __syncthreads();
  if (tid < 2*T_){
    int hh = tid / T_, r = tid % T_;
    float* row = ss + hh*144 + r*T_;
    float m = -INFINITY; for (int k = 0; k < T_; ++k) m = fmaxf(m, row[k]);
    float s = 0.f; for (int k = 0; k < T_; ++k){ float e = __expf(row[k] - m); row[k] = e; s += e; }
    float inv = 1.f / s; for (int k = 0; k < T_; ++k) row[k] *= inv;
  }
  __syncthreads();
  for (int idx = tid; idx < T_*16; idx += 64){
    int t = idx / 16, o = idx % 16; int hh = o / 8, d = o % 8;
    float acc = 0.f;
    const float* row = ss + hh*144 + t*T_;
    for (int k = 0; k < T_; ++k) acc += row[k] * qs[k*48 + 32 + hh*8 + d];
    att[(((size_t)b*T_ + t)*N_ + n)*48 + o] = acc;
  }
}

// ---------------- geo attention: MFMA flash, block=(bt,h), 4 waves ----------------
// Fragment maps (mfma_f32_16x16x32_bf16, verified):
//   A: lane l holds A[l&15][8*(l>>4)+j]   B: lane l holds B[8*(l>>4)+j][l&15]
//   D: lane l reg r holds D[4*(l>>4)+r][l&15]
__global__ __launch_bounds__(256) void gattn(const float* __restrict__ qkv,
                                             const unsigned* __restrict__ bm,
                                             float* __restrict__ att){
  int bid = blockIdx.x;
  int h = bid & 3; int bt = bid >> 2;     // bt in [0, 192)
  __shared__ unsigned short Kb[NQP*8];          // K bf16, [k][d]
  __shared__ unsigned short Vt[16*PSTR];        // V^T bf16, [d][k], d>=8 and k>=N_ zero
  __shared__ unsigned short SP[4][16*PSTR];     // per-wave S/P strip
  __shared__ unsigned mbuf[4][16*12];           // per-wave mask rows
  __shared__ float rowinv[4][16];
  int tid = threadIdx.x;
  const float* qkb = qkv + (size_t)bt*N_*144;
  const float scale = 0.35355339059327373f;

  for (int idx = tid; idx < NQP*8; idx += 256){
    int k = idx >> 3, d = idx & 7;
    Kb[idx] = (k < N_) ? f2b_rne(qkb[(size_t)k*144 + 80 + h*8 + d] * scale) : (unsigned short)0;
  }
  for (int idx = tid; idx < 16*PSTR; idx += 256){
    int d = idx / PSTR, k = idx % PSTR;
    Vt[idx] = (d < 8 && k < N_) ? f2b_rne(qkb[(size_t)k*144 + 112 + h*8 + d]) : (unsigned short)0;
  }
  __syncthreads();

  int wv = tid >> 6, ln = tid & 63;
  int g = ln >> 4, r = ln & 15;
  unsigned short* S = &SP[wv][0];
  unsigned* mb = &mbuf[wv][0];

  for (int tile = wv; tile < 21; tile += 4){
    int qb = tile*16;
    // stage this tile's mask rows (16 x 11 words)
    for (int i = ln; i < 176; i += 64){
      int rr = i / 11, w = i % 11;
      mb[rr*12 + w] = bm[(qb + rr)*MW + w];
    }
    // Q fragment (lanes g==0 carry d=0..7; rest zero-padded K dims)
    bf16x8 aq = {0,0,0,0,0,0,0,0};
    if (g == 0){
      int q = qb + r; if (q > N_-1) q = N_-1;
      const float* qp = qkb + (size_t)q*144 + 48 + h*8;
      #pragma unroll
      for (int j = 0; j < 8; ++j) aq[j] = (short)f2b_rne(qp[j]);
    }
    // QK^T: 21 k-tiles -> S strip (bf16)
    for (int kt = 0; kt < 21; ++kt){
      bf16x8 bk = {0,0,0,0,0,0,0,0};
      if (g == 0) bk = *(const bf16x8*)&Kb[(kt*16 + r)*8];
      f32x4 dd = {0.f,0.f,0.f,0.f};
      dd = __builtin_amdgcn_mfma_f32_16x16x32_bf16(aq, bk, dd, 0, 0, 0);
      #pragma unroll
      for (int rg = 0; rg < 4; ++rg)
        S[(g*4 + rg)*PSTR + kt*16 + r] = f2b_trunc(dd[rg]);
    }
    // pass 1: apply mask -> -inf, row max. lane: row=r, quarter g scans cols [g*88, g*88+88)
    float mloc = -1e30f;
    #pragma unroll
    for (int i = 0; i < 11; ++i){
      int c0 = g*88 + i*8;
      u16x8* sp = (u16x8*)&S[r*PSTR + c0];
      u16x8 sv = *sp;
      unsigned w0 = mb[r*12 + (c0 >> 5)];
      unsigned w1 = mb[r*12 + ((c0 + 7) >> 5)];
      #pragma unroll
      for (int j = 0; j < 8; ++j){
        int c = c0 + j;
        unsigned wb = ((c >> 5) == (c0 >> 5)) ? w0 : w1;
        bool masked = (c >= N_) || ((wb >> (c & 31)) & 1u);
        if (masked) sv[j] = (unsigned short)0xFF80;   // bf16 -inf
        else mloc = fmaxf(mloc, b2f_us(sv[j]));
      }
      *sp = sv;
    }
    mloc = fmaxf(mloc, __shfl_xor(mloc, 16));
    mloc = fmaxf(mloc, __shfl_xor(mloc, 32));
    // pass 2: P = exp(S - m), row sum
    float sloc = 0.f;
    #pragma unroll
    for (int i = 0; i < 11; ++i){
      int c0 = g*88 + i*8;
      u16x8* sp = (u16x8*)&S[r*PSTR + c0];
      u16x8 sv = *sp;
      #pragma unroll
      for (int j = 0; j < 8; ++j){
        float e = __expf(b2f_us(sv[j]) - mloc);       // exp(-inf - m) = 0
        sloc += e;
        sv[j] = f2b_trunc(e);
      }
      *sp = sv;
    }
    sloc += __shfl_xor(sloc, 16);
    sloc += __shfl_xor(sloc, 32);
    if (g == 0) rowinv[wv][r] = (sloc > 0.f) ? 1.f / sloc : 0.f;
    // PV: 11 K=32 steps; A = P (row r, cols ks*32+8g..+7), B = V^T (same offset formula)
    f32x4 acc = {0.f,0.f,0.f,0.f};
    #pragma unroll
    for (int ks = 0; ks < 11; ++ks){
      bf16x8 ap = *(const bf16x8*)&S [r*PSTR + ks*32 + g*8];
      bf16x8 bv = *(const bf16x8*)&Vt[r*PSTR + ks*32 + g*8];
      acc = __builtin_amdgcn_mfma_f32_16x16x32_bf16(ap, bv, acc, 0, 0, 0);
    }
    #pragma unroll
    for (int rg = 0; rg < 4; ++rg){
      int row = g*4 + rg;
      int q = qb + row;
      if (q < N_ && r < 8)
        att[((size_t)bt*N_ + q)*48 + 16 + h*8 + r] = acc[rg] * rowinv[wv][row];
    }
  }
}

// ---------------- final projection ----------------
__global__ void proj_k(const float* __restrict__ att, const float* __restrict__ W_proj,
                       const float* __restrict__ b_proj, float* __restrict__ out){
  int bid = blockIdx.x;
  long r0 = (long)bid * 16;
  __shared__ float Ws[64*49], as[16*48], bs[64];
  int tid = threadIdx.x;
  for (int idx = tid; idx < 64*48; idx += 256){ int d = idx/48, j = idx%48; Ws[d*49 + j] = W_proj[idx]; }
  if (tid < 64) bs[tid] = b_proj[tid];
  for (int idx = tid; idx < 16*48; idx += 256){
    long r = r0 + idx/48;
    as[idx] = (r < (long)B_*T_*N_) ? att[r*48 + idx%48] : 0.f;
  }
  __syncthreads();
  for (int idx = tid; idx < 16*64; idx += 256){
    int rr = idx >> 6, d = idx & 63;
    long r = r0 + rr;
    if (r >= (long)B_*T_*N_) continue;
    float acc = bs[d];
    const float* w = Ws + d*49; const float* a = as + rr*48;
    for (int j = 0; j < 48; ++j) acc += w[j] * a[j];
    out[r*64 + d] = acc;
  }
}

extern "C" void kernel_launch(void* const* d_in, const int* in_sizes, int n_in,
                              void* d_out, int out_size, void* d_ws, size_t ws_size,
                              hipStream_t stream){
  const float* x      = (const float*)d_in[0];
  const int*   ind    = (const int*)  d_in[1];
  const unsigned char* gmask_raw = (const unsigned char*)d_in[4];
  const float* p1     = (const float*)d_in[5];
  const float* p2     = (const float*)d_in[6];
  const float* p3     = (const float*)d_in[7];
  const float* pk     = (const float*)d_in[8];
  const float* W_r1   = (const float*)d_in[9];
  const float* b_r1   = (const float*)d_in[10];
  const float* W_gcn  = (const float*)d_in[11];
  const float* b_gcn  = (const float*)d_in[12];
  const float* W_r2   = (const float*)d_in[13];
  const float* b_r2   = (const float*)d_in[14];
  const float* Wtq    = (const float*)d_in[15];
  const float* Wtk    = (const float*)d_in[16];
  const float* Wtv    = (const float*)d_in[17];
  const float* Wgq    = (const float*)d_in[18];
  const float* Wgk    = (const float*)d_in[19];
  const float* Wgv    = (const float*)d_in[20];
  const float* W_proj = (const float*)d_in[21];
  const float* b_proj = (const float*)d_in[22];
  float* out = (float*)d_out;

  float* ws = (float*)d_ws;
  float* adp  = ws; ws += (size_t)B_*N_*N_;
  float* A1   = ws; ws += B_*DIMS_*DIMS_;
  float* h    = ws; ws += (size_t)B_*N_*384;
  float* x1   = ws; ws += (size_t)B_*N_*384;
  float* x2   = ws; ws += (size_t)B_*N_*384;
  float* Wc   = ws; ws += 64*96;
  float* bc   = ws; ws += 64;
  float* Wall = ws; ws += 144*64;
  float* xg   = ws; ws += (size_t)B_*T_*N_*64;
  float* qkv  = ws; ws += (size_t)B_*T_*N_*144;
  float* att  = ws; ws += (size_t)B_*T_*N_*48;
  int*   mmode = (int*)ws; ws += 16;
  unsigned* bm = (unsigned*)ws; ws += NQP*MW;

  mask_detect <<<1,         256, 0, stream>>>(gmask_raw, mmode);
  mask_bits   <<<(NQP*MW+255)/256, 256, 0, stream>>>(gmask_raw, mmode, bm);
  dg_a1       <<<B_,        256, 0, stream>>>(p1, pk, ind, A1);
  dg_adp      <<<B_*N_,     128, 0, stream>>>(p2, p3, A1, adp);
  prep_weights<<<2,         256, 0, stream>>>(W_gcn, b_gcn, W_r2, b_r2,
                                              Wtq, Wtk, Wtv, Wgq, Wgk, Wgv, Wc, bc, Wall);
  hproj       <<<B_*N_,     384, 0, stream>>>(x, W_r1, b_r1, h);
  gcn_mm      <<<B_*41,     384, 0, stream>>>(adp, h,  x1);
  gcn_mm      <<<B_*41,     384, 0, stream>>>(adp, x1, x2);
  xg_k        <<<B_*N_,     256, 0, stream>>>(h, x1, x2, Wc, bc, xg);
  qkv_k       <<<192*21,    256, 0, stream>>>(xg, Wall, qkv);
  tattn       <<<B_*N_,      64, 0, stream>>>(qkv, att);
  gattn       <<<768,       256, 0, stream>>>(qkv, bm, att);
  proj_k      <<<3900,      256, 0, stream>>>(att, W_proj, b_proj, out);
}

// Round 6
// 294.782 us; speedup vs baseline: 1.4203x; 1.4203x over previous
//
#include <hip/hip_runtime.h>
#include <hip/hip_bf16.h>
#include <math.h>

#define B_ 16
#define T_ 12
#define N_ 325
#define DIMS_ 40
#define DAYS_ 288
#define MW 12          // bitmask words per mask row (11 used, 1 pad)
#define NQP 336        // padded q-rows for mask (21*16)

typedef __attribute__((ext_vector_type(8))) short bf16x8;
typedef __attribute__((ext_vector_type(4))) float f32x4;

// single f32 -> bf16 (RNE) via v_cvt_pk
__device__ __forceinline__ unsigned short cvt1(float f){
  unsigned w;
  asm("v_cvt_pk_bf16_f32 %0, %1, %2" : "=v"(w) : "v"(f), "v"(f));
  return (unsigned short)w;
}
// pack two f32 -> 2xbf16 (lo = a, hi = b)
__device__ __forceinline__ unsigned cvt2(float a, float b){
  unsigned w;
  asm("v_cvt_pk_bf16_f32 %0, %1, %2" : "=v"(w) : "v"(a), "v"(b));
  return w;
}
__device__ __forceinline__ bf16x8 u2b(uint4 u){ return __builtin_bit_cast(bf16x8, u); }

// ---------------- mask dtype detection + bitmask build ----------------
__global__ void mask_detect(const unsigned char* __restrict__ raw, int* __restrict__ mode){
  __shared__ int f3F_m1, f3F_m3, fNZ_o;
  if (threadIdx.x == 0){ f3F_m1 = 0; f3F_m3 = 0; fNZ_o = 0; }
  __syncthreads();
  for (int i = threadIdx.x; i < 4096; i += 256){
    unsigned char v = raw[i];
    int m4 = i & 3;
    if (v == 0x3F && m4 == 1) atomicOr(&f3F_m1, 1);
    if (v == 0x3F && m4 == 3) atomicOr(&f3F_m3, 1);
    if (v != 0 && m4 != 0)    atomicOr(&fNZ_o, 1);
  }
  __syncthreads();
  if (threadIdx.x == 0){
    int m;
    if (f3F_m1) m = 2;
    else if (f3F_m3) m = 3;
    else if (fNZ_o) m = 0;
    else m = 1;
    *mode = m;
  }
}

// bm has NQP rows; bit j of bm[q*MW+w] = masked(q, w*32+j); rows/cols >= N_ -> masked
__global__ void mask_bits(const unsigned char* __restrict__ raw, const int* __restrict__ mode_p,
                          unsigned* __restrict__ bm){
  int mode = *mode_p;
  int idx = blockIdx.x * 256 + threadIdx.x;
  if (idx >= NQP * MW) return;
  int q = idx / MW, w = idx % MW;
  if (q >= N_) { bm[idx] = 0xFFFFFFFFu; return; }
  unsigned bits = 0;
  for (int j = 0; j < 32; ++j){
    int k = w*32 + j;
    int v;
    if (k >= N_) v = 1;
    else {
      size_t i = (size_t)q*N_ + k;
      if (mode == 0)      v = raw[i] != 0;
      else if (mode == 1) v = ((const int*)raw)[i] != 0;
      else if (mode == 2) { unsigned short u = ((const unsigned short*)raw)[i]; v = (u & 0x7FFF) != 0; }
      else                { float f = ((const float*)raw)[i]; v = (f != 0.f); }
    }
    bits |= (unsigned)v << j;
  }
  bm[idx] = bits;
}

// ---------------- dynamic graph construct ----------------
__global__ void dg_a1(const float* __restrict__ p1, const float* __restrict__ pk,
                      const int* __restrict__ ind, float* __restrict__ A1){
  int b = blockIdx.x;
  __shared__ float te[DIMS_];
  int day = ind[b] % DAYS_; if (day < 0) day += DAYS_;
  for (int i = threadIdx.x; i < DIMS_; i += blockDim.x) te[i] = p1[day*DIMS_ + i];
  __syncthreads();
  for (int jk = threadIdx.x; jk < DIMS_*DIMS_; jk += blockDim.x){
    float acc = 0.f;
    for (int i = 0; i < DIMS_; ++i) acc += te[i] * pk[i*DIMS_*DIMS_ + jk];
    A1[b*DIMS_*DIMS_ + jk] = acc;
  }
}

__global__ void dg_adp(const float* __restrict__ p2, const float* __restrict__ p3,
                       const float* __restrict__ A1, float* __restrict__ adp){
  int bid = blockIdx.x; int b = bid / N_; int n = bid % N_;
  __shared__ float p2r[DIMS_], t2[DIMS_], sbuf[N_], red[128];
  int tid = threadIdx.x;
  if (tid < DIMS_) p2r[tid] = p2[n*DIMS_ + tid];
  __syncthreads();
  if (tid < DIMS_){
    float acc = 0.f;
    const float* a1 = A1 + b*DIMS_*DIMS_;
    for (int j = 0; j < DIMS_; ++j) acc += p2r[j] * a1[j*DIMS_ + tid];
    t2[tid] = acc;
  }
  __syncthreads();
  float lm = -INFINITY;
  for (int c = tid; c < N_; c += 128){
    float acc = 0.f;
    for (int k = 0; k < DIMS_; ++k) acc += p3[c*DIMS_ + k] * t2[k];
    acc = fmaxf(acc, 0.f);
    sbuf[c] = acc; lm = fmaxf(lm, acc);
  }
  red[tid] = lm; __syncthreads();
  for (int off = 64; off; off >>= 1){ if (tid < off) red[tid] = fmaxf(red[tid], red[tid+off]); __syncthreads(); }
  float m = red[0]; __syncthreads();
  float ls = 0.f;
  for (int c = tid; c < N_; c += 128){ float e = __expf(sbuf[c] - m); sbuf[c] = e; ls += e; }
  red[tid] = ls; __syncthreads();
  for (int off = 64; off; off >>= 1){ if (tid < off) red[tid] += red[tid+off]; __syncthreads(); }
  float inv = 1.f / red[0];
  float* outp = adp + ((size_t)b*N_ + n) * N_;
  for (int c = tid; c < N_; c += 128) outp[c] = sbuf[c] * inv;
}

// ---------------- weight prep ----------------
// block0: Wc = W_r2@W_gcn (LDS), bc; write Wcb = B-swizzled bf16 of Wc^T
//   Wcb[((kc*4+g)*64 + d)*8 + jj] = Wc[d][kc*32+g*8+jj]   (kc<3)
// block1: Wallb = B-swizzled bf16 of Wall^T (Wall rows: tq16,tk16,tv16,gq32,gk32,gv32)
//   Wallb[((kc*4+g)*144 + j)*8 + jj] = Wall[j][kc*32+g*8+jj]  (kc<2)
__global__ void prep_weights(const float* W_gcn, const float* b_gcn, const float* W_r2, const float* b_r2,
                             const float* Wtq, const float* Wtk, const float* Wtv,
                             const float* Wgq, const float* Wgk, const float* Wgv,
                             float* bc, unsigned short* Wcb, unsigned short* Wallb){
  int tid = threadIdx.x;
  if (blockIdx.x == 0){
    __shared__ float WcS[64*96];
    for (int idx = tid; idx < 64*96; idx += 256){
      int d = idx / 96, c = idx % 96;
      float acc = 0.f;
      for (int o = 0; o < 32; ++o) acc += W_r2[d*32 + o] * W_gcn[o*96 + c];
      WcS[idx] = acc;
    }
    for (int d = tid; d < 64; d += 256){
      float acc = b_r2[d];
      for (int o = 0; o < 32; ++o) acc += W_r2[d*32 + o] * b_gcn[o];
      bc[d] = acc;
    }
    __syncthreads();
    for (int idx = tid; idx < 3*4*64*8; idx += 256){
      int jj = idx & 7, rest = idx >> 3;
      int d = rest % 64, gk = rest / 64;
      int g = gk & 3, kc = gk >> 2;
      Wcb[idx] = cvt1(WcS[d*96 + kc*32 + g*8 + jj]);
    }
  } else {
    for (int idx = tid; idx < 2*4*144*8; idx += 256){
      int jj = idx & 7, rest = idx >> 3;
      int j = rest % 144, gk = rest / 144;
      int g = gk & 3, kc = gk >> 2;
      int dd = kc*32 + g*8 + jj;
      const float* src; int rsrc;
      if      (j < 16) { src = Wtq; rsrc = j; }
      else if (j < 32) { src = Wtk; rsrc = j - 16; }
      else if (j < 48) { src = Wtv; rsrc = j - 32; }
      else if (j < 80) { src = Wgq; rsrc = j - 48; }
      else if (j < 112){ src = Wgk; rsrc = j - 80; }
      else             { src = Wgv; rsrc = j - 112; }
      Wallb[idx] = cvt1(src[rsrc*64 + dd]);
    }
  }
}

// ---------------- h projection (unchanged) ----------------
__global__ void hproj(const float* __restrict__ x, const float* __restrict__ W_r1,
                      const float* __restrict__ b_r1, float* __restrict__ h){
  int bid = blockIdx.x; int b = bid / N_, n = bid % N_;
  __shared__ float xs[T_*65], Ws[32*65];
  int tid = threadIdx.x;
  for (int idx = tid; idx < 32*64; idx += 384){ int c = idx >> 6, d = idx & 63; Ws[c*65 + d] = W_r1[idx]; }
  for (int idx = tid; idx < T_*64; idx += 384){
    int t = idx >> 6, d = idx & 63;
    xs[t*65 + d] = x[(((size_t)b*T_ + t)*N_ + n)*64 + d];
  }
  __syncthreads();
  int c = tid / T_, t = tid % T_;
  float acc = b_r1[c];
  for (int d = 0; d < 64; ++d) acc += xs[t*65 + d] * Ws[c*65 + d];
  h[((size_t)b*N_ + n)*384 + c*T_ + t] = acc;
}

// ---------------- GCN hop (unchanged) ----------------
__global__ void gcn_mm(const float* __restrict__ adp, const float* __restrict__ in,
                       float* __restrict__ out){
  int bid = blockIdx.x;
  int b = bid / 41, wt = bid % 41;
  int w0 = wt * 8;
  __shared__ float a_s[8*64];
  int tid = threadIdx.x;
  float acc[8] = {0,0,0,0,0,0,0,0};
  const float* inb = in + (size_t)b*N_*384 + tid;
  const float* adpb = adp + (size_t)b*N_*N_;
  for (int v0 = 0; v0 < N_; v0 += 64){
    int vn = N_ - v0; if (vn > 64) vn = 64;
    __syncthreads();
    for (int idx = tid; idx < 8*64; idx += 384){
      int wr = idx >> 6, v = idx & 63;
      int w = w0 + wr;
      a_s[idx] = (w < N_ && v < vn) ? adpb[(size_t)w*N_ + v0 + v] : 0.f;
    }
    __syncthreads();
    for (int v = 0; v < vn; ++v){
      float hv = inb[(size_t)(v0 + v)*384];
      #pragma unroll
      for (int w8 = 0; w8 < 8; ++w8) acc[w8] += a_s[w8*64 + v] * hv;
    }
  }
  for (int w8 = 0; w8 < 8; ++w8){
    int w = w0 + w8;
    if (w < N_) out[((size_t)b*N_ + w)*384 + tid] = acc[w8];
  }
}

// ---------------- xg: MFMA GEMM per (b,n): out[t][d] = cat[t][c'] @ Wc^T + bc ----------------
// A staged in per-wave LDS [16 t][104 c'] bf16 (t rows 12-15 garbage -> D rows guarded).
__global__ __launch_bounds__(256) void xg_k(const float* __restrict__ h, const float* __restrict__ x1,
                                            const float* __restrict__ x2,
                                            const unsigned short* __restrict__ Wcb,
                                            const float* __restrict__ bc,
                                            unsigned short* __restrict__ xg_bf){
  __shared__ unsigned short catA[4][16*104];
  int tid = threadIdx.x, wv = tid >> 6, ln = tid & 63;
  int p = blockIdx.x*4 + wv;
  if (p >= B_*N_) return;
  int b = p / N_, n = p % N_;
  size_t base = ((size_t)b*N_ + n)*384;
  unsigned short* ca = &catA[wv][0];
  #pragma unroll
  for (int ii = 0; ii < 6; ++ii){
    int s2 = ln + 64*ii;
    int c = s2 / 12, t = s2 - c*12;
    unsigned short* row = ca + t*104;
    row[c]      = cvt1(h [base + s2]);
    row[32 + c] = cvt1(x1[base + s2]);
    row[64 + c] = cvt1(x2[base + s2]);
  }
  // per-wave LDS: same-wave DS ops are in-order; compiler inserts lgkmcnt
  int g = ln >> 4, r = ln & 15;
  bf16x8 a0 = *(const bf16x8*)&ca[r*104 +  0 + g*8];
  bf16x8 a1 = *(const bf16x8*)&ca[r*104 + 32 + g*8];
  bf16x8 a2 = *(const bf16x8*)&ca[r*104 + 64 + g*8];
  #pragma unroll
  for (int dt = 0; dt < 4; ++dt){
    f32x4 acc = {0.f,0.f,0.f,0.f};
    bf16x8 b0 = *(const bf16x8*)&Wcb[((0*4+g)*64 + dt*16 + r)*8];
    bf16x8 b1 = *(const bf16x8*)&Wcb[((1*4+g)*64 + dt*16 + r)*8];
    bf16x8 b2 = *(const bf16x8*)&Wcb[((2*4+g)*64 + dt*16 + r)*8];
    acc = __builtin_amdgcn_mfma_f32_16x16x32_bf16(a0, b0, acc, 0,0,0);
    acc = __builtin_amdgcn_mfma_f32_16x16x32_bf16(a1, b1, acc, 0,0,0);
    acc = __builtin_amdgcn_mfma_f32_16x16x32_bf16(a2, b2, acc, 0,0,0);
    float bias = bc[dt*16 + r];
    if (g < 3){
      #pragma unroll
      for (int rg = 0; rg < 4; ++rg){
        int t = g*4 + rg;   // < 12
        xg_bf[(((size_t)b*T_ + t)*N_ + n)*64 + dt*16 + r] = cvt1(acc[rg] + bias);
      }
    }
  }
}

// ---------------- qkv: MFMA GEMM, no LDS. A = xg_bf rows, B = Wallb swizzled ----------------
__global__ __launch_bounds__(256) void qkv_k(const unsigned short* __restrict__ xg_bf,
                                             const unsigned short* __restrict__ Wallb,
                                             float* __restrict__ qkv){
  int tid = threadIdx.x, wv = tid >> 6, ln = tid & 63;
  int bt = blockIdx.x / 6;
  int nt = (blockIdx.x % 6)*4 + wv;
  if (nt >= 21) return;
  int g = ln >> 4, r = ln & 15;
  int n0 = nt*16;
  int nc = min(n0 + r, N_-1);
  const unsigned short* arow = xg_bf + ((size_t)bt*N_ + nc)*64;
  bf16x8 a0 = *(const bf16x8*)&arow[g*8];
  bf16x8 a1 = *(const bf16x8*)&arow[32 + g*8];
  #pragma unroll
  for (int jt = 0; jt < 9; ++jt){
    f32x4 acc = {0.f,0.f,0.f,0.f};
    bf16x8 b0 = *(const bf16x8*)&Wallb[((0*4+g)*144 + jt*16 + r)*8];
    bf16x8 b1 = *(const bf16x8*)&Wallb[((1*4+g)*144 + jt*16 + r)*8];
    acc = __builtin_amdgcn_mfma_f32_16x16x32_bf16(a0, b0, acc, 0,0,0);
    acc = __builtin_amdgcn_mfma_f32_16x16x32_bf16(a1, b1, acc, 0,0,0);
    #pragma unroll
    for (int rg = 0; rg < 4; ++rg){
      int n = n0 + g*4 + rg;
      if (n < N_) qkv[((size_t)bt*N_ + n)*144 + jt*16 + r] = acc[rg];
    }
  }
}

// ---------------- temporal attention (unchanged) ----------------
__global__ void tattn(const float* __restrict__ qkv, float* __restrict__ att){
  int bid = blockIdx.x; int b = bid / N_, n = bid % N_;
  __shared__ float qs[T_*48], ss[2*T_*T_];
  int tid = threadIdx.x;
  for (int idx = tid; idx < T_*48; idx += 64){
    int t = idx / 48, j = idx % 48;
    qs[idx] = qkv[(((size_t)b*T_ + t)*N_ + n)*144 + j];
  }
  __syncthreads();
  const float scale = 0.35355339059327373f;
  for (int idx = tid; idx < 2*T_*T_; idx += 64){
    int hh = idx / 144, r = (idx / T_) % T_, c = idx % T_;
    float acc = 0.f;
    for (int d = 0; d < 8; ++d) acc += qs[r*48 + hh*8 + d] * qs[c*48 + 16 + hh*8 + d];
    ss[idx] = acc * scale;
  }
  __syncthreads();
  if (tid < 2*T_){
    int hh = tid / T_, r = tid % T_;
    float* row = ss + hh*144 + r*T_;
    float m = -INFINITY; for (int k = 0; k < T_; ++k) m = fmaxf(m, row[k]);
    float s = 0.f; for (int k = 0; k < T_; ++k){ float e = __expf(row[k] - m); row[k] = e; s += e; }
    float inv = 1.f / s; for (int k = 0; k < T_; ++k) row[k] *= inv;
  }
  __syncthreads();
  for (int idx = tid; idx < T_*16; idx += 64){
    int t = idx / 16, o = idx % 16; int hh = o / 8, d = o % 8;
    float acc = 0.f;
    const float* row = ss + hh*144 + t*T_;
    for (int k = 0; k < T_; ++k) acc += row[k] * qs[k*48 + 32 + hh*8 + d];
    att[(((size_t)b*T_ + t)*N_ + n)*48 + o] = acc;
  }
}

// ---------------- geo attention v3: swapped QK^T MFMA, in-register softmax ----------------
// S^T = mfma(K-frag, Q-frag): lane (g,r) reg rg holds S[q=qb+r][k=32ks+(16)+4g+rg].
// exp without max-sub (scores tiny; exact softmax identity); mask in-register via bm word ks.
// P^T -> PV B-frag via per-wave LDS exchange (16 uints/row); O = mfma(V^T, P^T); norm at store.
__global__ __launch_bounds__(256) void gattn(const float* __restrict__ qkv,
                                             const unsigned* __restrict__ bm,
                                             float* __restrict__ att){
  int bid = blockIdx.x;
  int sub = bid & 1; int h = (bid >> 1) & 3; int bt = bid >> 3;   // bt in [0,192)
  __shared__ unsigned short Kb[352*8];     // K bf16 pre-scaled by scale*log2(e), [k][d]
  __shared__ unsigned short Vt[16*360];    // V^T bf16 [d][k] (d 8-15 unwritten, rows discarded)
  __shared__ unsigned Pst[4][16*16];       // per-wave P exchange: row q-idx, 16 uints = 32 bf16 k's
  int tid = threadIdx.x;
  const float* qkb = qkv + (size_t)bt*N_*144;
  const float kscale = 0.35355339059327373f * 1.4426950408889634f;
  for (int row = tid; row < 352; row += 256){
    const float* kr = qkb + (size_t)min(row, N_-1)*144 + 80 + h*8;
    float4 k0 = *(const float4*)kr;
    float4 k1 = *(const float4*)(kr + 4);
    uint4 wv4 = { cvt2(k0.x*kscale, k0.y*kscale), cvt2(k0.z*kscale, k0.w*kscale),
                  cvt2(k1.x*kscale, k1.y*kscale), cvt2(k1.z*kscale, k1.w*kscale) };
    *(uint4*)&Kb[row*8] = wv4;
  }
  for (int idx = tid; idx < 352*4; idx += 256){
    int row = idx >> 2, dp = idx & 3;
    const float* vr = qkb + (size_t)min(row, N_-1)*144 + 112 + h*8 + dp*2;
    float2 v = *(const float2*)vr;
    unsigned w = cvt2(v.x, v.y);
    Vt[(dp*2  )*360 + row] = (unsigned short)w;
    Vt[(dp*2+1)*360 + row] = (unsigned short)(w >> 16);
  }
  __syncthreads();

  int wv = tid >> 6, ln = tid & 63;
  int g = ln >> 4, r = ln & 15;
  int g4 = g*4;
  unsigned* P = &Pst[wv][0];
  bool gzero = (g == 0);
  const bf16x8 z8 = {0,0,0,0,0,0,0,0};

  for (int tile = sub + 2*wv; tile < 21; tile += 8){
    int qb = tile*16;
    int qc = min(qb + r, N_-1);
    const uint4* bmp = (const uint4*)(bm + (size_t)(qb + r)*MW);
    uint4 m0 = bmp[0], m1 = bmp[1], m2 = bmp[2];
    unsigned bmw[11] = {m0.x,m0.y,m0.z,m0.w, m1.x,m1.y,m1.z,m1.w, m2.x,m2.y,m2.z};
    bf16x8 aq = z8;
    if (gzero){
      const float* qp = qkb + (size_t)qc*144 + 48 + h*8;
      float4 q0 = *(const float4*)qp;
      float4 q1 = *(const float4*)(qp + 4);
      uint4 u = { cvt2(q0.x,q0.y), cvt2(q0.z,q0.w), cvt2(q1.x,q1.y), cvt2(q1.z,q1.w) };
      aq = u2b(u);
    }
    float ssum = 0.f;
    f32x4 acc = {0.f,0.f,0.f,0.f};
    #pragma unroll
    for (int ks = 0; ks < 11; ++ks){
      bf16x8 akA = z8, akB = z8;
      if (gzero){
        akA = *(const bf16x8*)&Kb[(ks*32 + r)*8];
        akB = *(const bf16x8*)&Kb[(ks*32 + 16 + r)*8];
      }
      f32x4 dA = {0.f,0.f,0.f,0.f}, dB = {0.f,0.f,0.f,0.f};
      dA = __builtin_amdgcn_mfma_f32_16x16x32_bf16(akA, aq, dA, 0,0,0);
      dB = __builtin_amdgcn_mfma_f32_16x16x32_bf16(akB, aq, dB, 0,0,0);
      unsigned wm = bmw[ks];
      unsigned bA = (wm >> g4) & 0xFu;
      unsigned bB = (wm >> (g4 + 16)) & 0xFu;
      float pA[4], pB[4];
      #pragma unroll
      for (int rg = 0; rg < 4; ++rg){
        float eA = exp2f(dA[rg]);
        float eB = exp2f(dB[rg]);
        eA = (bA & (1u << rg)) ? 0.f : eA;
        eB = (bB & (1u << rg)) ? 0.f : eB;
        ssum += eA; ssum += eB;
        pA[rg] = eA; pB[rg] = eB;
      }
      *(uint2*)&P[r*16     + g*2] = make_uint2(cvt2(pA[0],pA[1]), cvt2(pA[2],pA[3]));
      *(uint2*)&P[r*16 + 8 + g*2] = make_uint2(cvt2(pB[0],pB[1]), cvt2(pB[2],pB[3]));
      bf16x8 av = *(const bf16x8*)&Vt[r*360 + ks*32 + g*8];
      uint4 pw = *(const uint4*)&P[r*16 + g*4];
      acc = __builtin_amdgcn_mfma_f32_16x16x32_bf16(av, u2b(pw), acc, 0,0,0);
    }
    ssum += __shfl_xor(ssum, 16);
    ssum += __shfl_xor(ssum, 32);
    float inv = (ssum > 0.f) ? __builtin_amdgcn_rcpf(ssum) : 0.f;
    int qq = qb + r;
    if (g < 2 && qq < N_){
      float4 o = make_float4(acc[0]*inv, acc[1]*inv, acc[2]*inv, acc[3]*inv);
      *(float4*)(att + ((size_t)bt*N_ + qq)*48 + 16 + h*8 + g4) = o;
    }
  }
}

// ---------------- final projection (unchanged) ----------------
__global__ void proj_k(const float* __restrict__ att, const float* __restrict__ W_proj,
                       const float* __restrict__ b_proj, float* __restrict__ out){
  int bid = blockIdx.x;
  long r0 = (long)bid * 16;
  __shared__ float Ws[64*49], as[16*48], bs[64];
  int tid = threadIdx.x;
  for (int idx = tid; idx < 64*48; idx += 256){ int d = idx/48, j = idx%48; Ws[d*49 + j] = W_proj[idx]; }
  if (tid < 64) bs[tid] = b_proj[tid];
  for (int idx = tid; idx < 16*48; idx += 256){
    long r = r0 + idx/48;
    as[idx] = (r < (long)B_*T_*N_) ? att[r*48 + idx%48] : 0.f;
  }
  __syncthreads();
  for (int idx = tid; idx < 16*64; idx += 256){
    int rr = idx >> 6, d = idx & 63;
    long r = r0 + rr;
    if (r >= (long)B_*T_*N_) continue;
    float acc = bs[d];
    const float* w = Ws + d*49; const float* a = as + rr*48;
    for (int j = 0; j < 48; ++j) acc += w[j] * a[j];
    out[r*64 + d] = acc;
  }
}

extern "C" void kernel_launch(void* const* d_in, const int* in_sizes, int n_in,
                              void* d_out, int out_size, void* d_ws, size_t ws_size,
                              hipStream_t stream){
  const float* x      = (const float*)d_in[0];
  const int*   ind    = (const int*)  d_in[1];
  const unsigned char* gmask_raw = (const unsigned char*)d_in[4];
  const float* p1     = (const float*)d_in[5];
  const float* p2     = (const float*)d_in[6];
  const float* p3     = (const float*)d_in[7];
  const float* pk     = (const float*)d_in[8];
  const float* W_r1   = (const float*)d_in[9];
  const float* b_r1   = (const float*)d_in[10];
  const float* W_gcn  = (const float*)d_in[11];
  const float* b_gcn  = (const float*)d_in[12];
  const float* W_r2   = (const float*)d_in[13];
  const float* b_r2   = (const float*)d_in[14];
  const float* Wtq    = (const float*)d_in[15];
  const float* Wtk    = (const float*)d_in[16];
  const float* Wtv    = (const float*)d_in[17];
  const float* Wgq    = (const float*)d_in[18];
  const float* Wgk    = (const float*)d_in[19];
  const float* Wgv    = (const float*)d_in[20];
  const float* W_proj = (const float*)d_in[21];
  const float* b_proj = (const float*)d_in[22];
  float* out = (float*)d_out;

  float* ws = (float*)d_ws;
  float* adp  = ws; ws += (size_t)B_*N_*N_;
  float* A1   = ws; ws += B_*DIMS_*DIMS_;
  float* h    = ws; ws += (size_t)B_*N_*384;
  float* x1   = ws; ws += (size_t)B_*N_*384;
  float* x2   = ws; ws += (size_t)B_*N_*384;
  float* bc   = ws; ws += 64;
  float* qkv  = ws; ws += (size_t)B_*T_*N_*144;
  float* att  = ws; ws += (size_t)B_*T_*N_*48;
  int*   mmode = (int*)ws; ws += 16;
  unsigned* bm = (unsigned*)ws; ws += NQP*MW;           // 4032 words
  unsigned short* us = (unsigned short*)ws;
  unsigned short* xg_bf = us; us += (size_t)B_*T_*N_*64; // bf16
  unsigned short* Wcb   = us; us += 3*4*64*8;            // 6144
  unsigned short* Wallb = us; us += 2*4*144*8;           // 9216

  mask_detect <<<1,         256, 0, stream>>>(gmask_raw, mmode);
  mask_bits   <<<(NQP*MW+255)/256, 256, 0, stream>>>(gmask_raw, mmode, bm);
  dg_a1       <<<B_,        256, 0, stream>>>(p1, pk, ind, A1);
  dg_adp      <<<B_*N_,     128, 0, stream>>>(p2, p3, A1, adp);
  prep_weights<<<2,         256, 0, stream>>>(W_gcn, b_gcn, W_r2, b_r2,
                                              Wtq, Wtk, Wtv, Wgq, Wgk, Wgv, bc, Wcb, Wallb);
  hproj       <<<B_*N_,     384, 0, stream>>>(x, W_r1, b_r1, h);
  gcn_mm      <<<B_*41,     384, 0, stream>>>(adp, h,  x1);
  gcn_mm      <<<B_*41,     384, 0, stream>>>(adp, x1, x2);
  xg_k        <<<(B_*N_+3)/4, 256, 0, stream>>>(h, x1, x2, Wcb, bc, xg_bf);
  qkv_k       <<<192*6,     256, 0, stream>>>(xg_bf, Wallb, qkv);
  tattn       <<<B_*N_,      64, 0, stream>>>(qkv, att);
  gattn       <<<192*4*2,   256, 0, stream>>>(qkv, bm, att);
  proj_k      <<<3900,      256, 0, stream>>>(att, W_proj, b_proj, out);
}

// Round 7
// 291.023 us; speedup vs baseline: 1.4387x; 1.0129x over previous
//
#include <hip/hip_runtime.h>
#include <hip/hip_bf16.h>
#include <math.h>

#define B_ 16
#define T_ 12
#define N_ 325
#define DIMS_ 40
#define DAYS_ 288
#define MW 12          // bitmask words per mask row (11 used, 1 pad)
#define NQP 336        // padded q-rows for mask (21*16)

typedef __attribute__((ext_vector_type(8))) short bf16x8;
typedef __attribute__((ext_vector_type(4))) float f32x4;

// single f32 -> bf16 (RNE) via v_cvt_pk
__device__ __forceinline__ unsigned short cvt1(float f){
  unsigned w;
  asm("v_cvt_pk_bf16_f32 %0, %1, %2" : "=v"(w) : "v"(f), "v"(f));
  return (unsigned short)w;
}
// pack two f32 -> 2xbf16 (lo = a, hi = b)
__device__ __forceinline__ unsigned cvt2(float a, float b){
  unsigned w;
  asm("v_cvt_pk_bf16_f32 %0, %1, %2" : "=v"(w) : "v"(a), "v"(b));
  return w;
}
__device__ __forceinline__ bf16x8 u2b(uint4 u){ return __builtin_bit_cast(bf16x8, u); }

// ---------------- mask dtype detection + bitmask build ----------------
__global__ void mask_detect(const unsigned char* __restrict__ raw, int* __restrict__ mode){
  __shared__ int f3F_m1, f3F_m3, fNZ_o;
  if (threadIdx.x == 0){ f3F_m1 = 0; f3F_m3 = 0; fNZ_o = 0; }
  __syncthreads();
  for (int i = threadIdx.x; i < 4096; i += 256){
    unsigned char v = raw[i];
    int m4 = i & 3;
    if (v == 0x3F && m4 == 1) atomicOr(&f3F_m1, 1);
    if (v == 0x3F && m4 == 3) atomicOr(&f3F_m3, 1);
    if (v != 0 && m4 != 0)    atomicOr(&fNZ_o, 1);
  }
  __syncthreads();
  if (threadIdx.x == 0){
    int m;
    if (f3F_m1) m = 2;
    else if (f3F_m3) m = 3;
    else if (fNZ_o) m = 0;
    else m = 1;
    *mode = m;
  }
}

// bm has NQP rows; bit j of bm[q*MW+w] = masked(q, w*32+j); rows/cols >= N_ -> masked
__global__ void mask_bits(const unsigned char* __restrict__ raw, const int* __restrict__ mode_p,
                          unsigned* __restrict__ bm){
  int mode = *mode_p;
  int idx = blockIdx.x * 256 + threadIdx.x;
  if (idx >= NQP * MW) return;
  int q = idx / MW, w = idx % MW;
  if (q >= N_) { bm[idx] = 0xFFFFFFFFu; return; }
  unsigned bits = 0;
  for (int j = 0; j < 32; ++j){
    int k = w*32 + j;
    int v;
    if (k >= N_) v = 1;
    else {
      size_t i = (size_t)q*N_ + k;
      if (mode == 0)      v = raw[i] != 0;
      else if (mode == 1) v = ((const int*)raw)[i] != 0;
      else if (mode == 2) { unsigned short u = ((const unsigned short*)raw)[i]; v = (u & 0x7FFF) != 0; }
      else                { float f = ((const float*)raw)[i]; v = (f != 0.f); }
    }
    bits |= (unsigned)v << j;
  }
  bm[idx] = bits;
}

// ---------------- dynamic graph construct ----------------
__global__ void dg_a1(const float* __restrict__ p1, const float* __restrict__ pk,
                      const int* __restrict__ ind, float* __restrict__ A1){
  int b = blockIdx.x;
  __shared__ float te[DIMS_];
  int day = ind[b] % DAYS_; if (day < 0) day += DAYS_;
  for (int i = threadIdx.x; i < DIMS_; i += blockDim.x) te[i] = p1[day*DIMS_ + i];
  __syncthreads();
  for (int jk = threadIdx.x; jk < DIMS_*DIMS_; jk += blockDim.x){
    float acc = 0.f;
    for (int i = 0; i < DIMS_; ++i) acc += te[i] * pk[i*DIMS_*DIMS_ + jk];
    A1[b*DIMS_*DIMS_ + jk] = acc;
  }
}

__global__ void dg_adp(const float* __restrict__ p2, const float* __restrict__ p3,
                       const float* __restrict__ A1, float* __restrict__ adp){
  int bid = blockIdx.x; int b = bid / N_; int n = bid % N_;
  __shared__ float p2r[DIMS_], t2[DIMS_], sbuf[N_], red[128];
  int tid = threadIdx.x;
  if (tid < DIMS_) p2r[tid] = p2[n*DIMS_ + tid];
  __syncthreads();
  if (tid < DIMS_){
    float acc = 0.f;
    const float* a1 = A1 + b*DIMS_*DIMS_;
    for (int j = 0; j < DIMS_; ++j) acc += p2r[j] * a1[j*DIMS_ + tid];
    t2[tid] = acc;
  }
  __syncthreads();
  float lm = -INFINITY;
  for (int c = tid; c < N_; c += 128){
    float acc = 0.f;
    for (int k = 0; k < DIMS_; ++k) acc += p3[c*DIMS_ + k] * t2[k];
    acc = fmaxf(acc, 0.f);
    sbuf[c] = acc; lm = fmaxf(lm, acc);
  }
  red[tid] = lm; __syncthreads();
  for (int off = 64; off; off >>= 1){ if (tid < off) red[tid] = fmaxf(red[tid], red[tid+off]); __syncthreads(); }
  float m = red[0]; __syncthreads();
  float ls = 0.f;
  for (int c = tid; c < N_; c += 128){ float e = __expf(sbuf[c] - m); sbuf[c] = e; ls += e; }
  red[tid] = ls; __syncthreads();
  for (int off = 64; off; off >>= 1){ if (tid < off) red[tid] += red[tid+off]; __syncthreads(); }
  float inv = 1.f / red[0];
  float* outp = adp + ((size_t)b*N_ + n) * N_;
  for (int c = tid; c < N_; c += 128) outp[c] = sbuf[c] * inv;
}

// ---------------- weight prep ----------------
// block0: Wc = W_r2@W_gcn (LDS), bc; write Wcb = B-swizzled bf16 of Wc^T
//   Wcb[((kc*4+g)*64 + d)*8 + jj] = Wc[d][kc*32+g*8+jj]   (kc<3)
// block1: Wallb = B-swizzled bf16 of Wall^T (Wall rows: tq16,tk16,tv16,gq32,gk32,gv32)
//   Wallb[((kc*4+g)*144 + j)*8 + jj] = Wall[j][kc*32+g*8+jj]  (kc<2)
__global__ void prep_weights(const float* W_gcn, const float* b_gcn, const float* W_r2, const float* b_r2,
                             const float* Wtq, const float* Wtk, const float* Wtv,
                             const float* Wgq, const float* Wgk, const float* Wgv,
                             float* bc, unsigned short* Wcb, unsigned short* Wallb){
  int tid = threadIdx.x;
  if (blockIdx.x == 0){
    __shared__ float WcS[64*96];
    for (int idx = tid; idx < 64*96; idx += 256){
      int d = idx / 96, c = idx % 96;
      float acc = 0.f;
      for (int o = 0; o < 32; ++o) acc += W_r2[d*32 + o] * W_gcn[o*96 + c];
      WcS[idx] = acc;
    }
    for (int d = tid; d < 64; d += 256){
      float acc = b_r2[d];
      for (int o = 0; o < 32; ++o) acc += W_r2[d*32 + o] * b_gcn[o];
      bc[d] = acc;
    }
    __syncthreads();
    for (int idx = tid; idx < 3*4*64*8; idx += 256){
      int jj = idx & 7, rest = idx >> 3;
      int d = rest % 64, gk = rest / 64;
      int g = gk & 3, kc = gk >> 2;
      Wcb[idx] = cvt1(WcS[d*96 + kc*32 + g*8 + jj]);
    }
  } else {
    for (int idx = tid; idx < 2*4*144*8; idx += 256){
      int jj = idx & 7, rest = idx >> 3;
      int j = rest % 144, gk = rest / 144;
      int g = gk & 3, kc = gk >> 2;
      int dd = kc*32 + g*8 + jj;
      const float* src; int rsrc;
      if      (j < 16) { src = Wtq; rsrc = j; }
      else if (j < 32) { src = Wtk; rsrc = j - 16; }
      else if (j < 48) { src = Wtv; rsrc = j - 32; }
      else if (j < 80) { src = Wgq; rsrc = j - 48; }
      else if (j < 112){ src = Wgk; rsrc = j - 80; }
      else             { src = Wgv; rsrc = j - 112; }
      Wallb[idx] = cvt1(src[rsrc*64 + dd]);
    }
  }
}

// ---------------- h projection (unchanged) ----------------
__global__ void hproj(const float* __restrict__ x, const float* __restrict__ W_r1,
                      const float* __restrict__ b_r1, float* __restrict__ h){
  int bid = blockIdx.x; int b = bid / N_, n = bid % N_;
  __shared__ float xs[T_*65], Ws[32*65];
  int tid = threadIdx.x;
  for (int idx = tid; idx < 32*64; idx += 384){ int c = idx >> 6, d = idx & 63; Ws[c*65 + d] = W_r1[idx]; }
  for (int idx = tid; idx < T_*64; idx += 384){
    int t = idx >> 6, d = idx & 63;
    xs[t*65 + d] = x[(((size_t)b*T_ + t)*N_ + n)*64 + d];
  }
  __syncthreads();
  int c = tid / T_, t = tid % T_;
  float acc = b_r1[c];
  for (int d = 0; d < 64; ++d) acc += xs[t*65 + d] * Ws[c*65 + d];
  h[((size_t)b*N_ + n)*384 + c*T_ + t] = acc;
}

// ---------------- GCN hop (unchanged) ----------------
__global__ void gcn_mm(const float* __restrict__ adp, const float* __restrict__ in,
                       float* __restrict__ out){
  int bid = blockIdx.x;
  int b = bid / 41, wt = bid % 41;
  int w0 = wt * 8;
  __shared__ float a_s[8*64];
  int tid = threadIdx.x;
  float acc[8] = {0,0,0,0,0,0,0,0};
  const float* inb = in + (size_t)b*N_*384 + tid;
  const float* adpb = adp + (size_t)b*N_*N_;
  for (int v0 = 0; v0 < N_; v0 += 64){
    int vn = N_ - v0; if (vn > 64) vn = 64;
    __syncthreads();
    for (int idx = tid; idx < 8*64; idx += 384){
      int wr = idx >> 6, v = idx & 63;
      int w = w0 + wr;
      a_s[idx] = (w < N_ && v < vn) ? adpb[(size_t)w*N_ + v0 + v] : 0.f;
    }
    __syncthreads();
    for (int v = 0; v < vn; ++v){
      float hv = inb[(size_t)(v0 + v)*384];
      #pragma unroll
      for (int w8 = 0; w8 < 8; ++w8) acc[w8] += a_s[w8*64 + v] * hv;
    }
  }
  for (int w8 = 0; w8 < 8; ++w8){
    int w = w0 + w8;
    if (w < N_) out[((size_t)b*N_ + w)*384 + tid] = acc[w8];
  }
}

// ---------------- xg: MFMA GEMM per (b,n) (unchanged) ----------------
__global__ __launch_bounds__(256) void xg_k(const float* __restrict__ h, const float* __restrict__ x1,
                                            const float* __restrict__ x2,
                                            const unsigned short* __restrict__ Wcb,
                                            const float* __restrict__ bc,
                                            unsigned short* __restrict__ xg_bf){
  __shared__ unsigned short catA[4][16*104];
  int tid = threadIdx.x, wv = tid >> 6, ln = tid & 63;
  int p = blockIdx.x*4 + wv;
  if (p >= B_*N_) return;
  int b = p / N_, n = p % N_;
  size_t base = ((size_t)b*N_ + n)*384;
  unsigned short* ca = &catA[wv][0];
  #pragma unroll
  for (int ii = 0; ii < 6; ++ii){
    int s2 = ln + 64*ii;
    int c = s2 / 12, t = s2 - c*12;
    unsigned short* row = ca + t*104;
    row[c]      = cvt1(h [base + s2]);
    row[32 + c] = cvt1(x1[base + s2]);
    row[64 + c] = cvt1(x2[base + s2]);
  }
  // per-wave LDS: same-wave DS ops are in-order; compiler inserts lgkmcnt
  int g = ln >> 4, r = ln & 15;
  bf16x8 a0 = *(const bf16x8*)&ca[r*104 +  0 + g*8];
  bf16x8 a1 = *(const bf16x8*)&ca[r*104 + 32 + g*8];
  bf16x8 a2 = *(const bf16x8*)&ca[r*104 + 64 + g*8];
  #pragma unroll
  for (int dt = 0; dt < 4; ++dt){
    f32x4 acc = {0.f,0.f,0.f,0.f};
    bf16x8 b0 = *(const bf16x8*)&Wcb[((0*4+g)*64 + dt*16 + r)*8];
    bf16x8 b1 = *(const bf16x8*)&Wcb[((1*4+g)*64 + dt*16 + r)*8];
    bf16x8 b2 = *(const bf16x8*)&Wcb[((2*4+g)*64 + dt*16 + r)*8];
    acc = __builtin_amdgcn_mfma_f32_16x16x32_bf16(a0, b0, acc, 0,0,0);
    acc = __builtin_amdgcn_mfma_f32_16x16x32_bf16(a1, b1, acc, 0,0,0);
    acc = __builtin_amdgcn_mfma_f32_16x16x32_bf16(a2, b2, acc, 0,0,0);
    float bias = bc[dt*16 + r];
    if (g < 3){
      #pragma unroll
      for (int rg = 0; rg < 4; ++rg){
        int t = g*4 + rg;   // < 12
        xg_bf[(((size_t)b*T_ + t)*N_ + n)*64 + dt*16 + r] = cvt1(acc[rg] + bias);
      }
    }
  }
}

// ---------------- qkv: MFMA GEMM, no LDS (unchanged) ----------------
__global__ __launch_bounds__(256) void qkv_k(const unsigned short* __restrict__ xg_bf,
                                             const unsigned short* __restrict__ Wallb,
                                             float* __restrict__ qkv){
  int tid = threadIdx.x, wv = tid >> 6, ln = tid & 63;
  int bt = blockIdx.x / 6;
  int nt = (blockIdx.x % 6)*4 + wv;
  if (nt >= 21) return;
  int g = ln >> 4, r = ln & 15;
  int n0 = nt*16;
  int nc = min(n0 + r, N_-1);
  const unsigned short* arow = xg_bf + ((size_t)bt*N_ + nc)*64;
  bf16x8 a0 = *(const bf16x8*)&arow[g*8];
  bf16x8 a1 = *(const bf16x8*)&arow[32 + g*8];
  #pragma unroll
  for (int jt = 0; jt < 9; ++jt){
    f32x4 acc = {0.f,0.f,0.f,0.f};
    bf16x8 b0 = *(const bf16x8*)&Wallb[((0*4+g)*144 + jt*16 + r)*8];
    bf16x8 b1 = *(const bf16x8*)&Wallb[((1*4+g)*144 + jt*16 + r)*8];
    acc = __builtin_amdgcn_mfma_f32_16x16x32_bf16(a0, b0, acc, 0,0,0);
    acc = __builtin_amdgcn_mfma_f32_16x16x32_bf16(a1, b1, acc, 0,0,0);
    #pragma unroll
    for (int rg = 0; rg < 4; ++rg){
      int n = n0 + g*4 + rg;
      if (n < N_) qkv[((size_t)bt*N_ + n)*144 + jt*16 + r] = acc[rg];
    }
  }
}

// ---------------- temporal attention (unchanged) ----------------
__global__ void tattn(const float* __restrict__ qkv, float* __restrict__ att){
  int bid = blockIdx.x; int b = bid / N_, n = bid % N_;
  __shared__ float qs[T_*48], ss[2*T_*T_];
  int tid = threadIdx.x;
  for (int idx = tid; idx < T_*48; idx += 64){
    int t = idx / 48, j = idx % 48;
    qs[idx] = qkv[(((size_t)b*T_ + t)*N_ + n)*144 + j];
  }
  __syncthreads();
  const float scale = 0.35355339059327373f;
  for (int idx = tid; idx < 2*T_*T_; idx += 64){
    int hh = idx / 144, r = (idx / T_) % T_, c = idx % T_;
    float acc = 0.f;
    for (int d = 0; d < 8; ++d) acc += qs[r*48 + hh*8 + d] * qs[c*48 + 16 + hh*8 + d];
    ss[idx] = acc * scale;
  }
  __syncthreads();
  if (tid < 2*T_){
    int hh = tid / T_, r = tid % T_;
    float* row = ss + hh*144 + r*T_;
    float m = -INFINITY; for (int k = 0; k < T_; ++k) m = fmaxf(m, row[k]);
    float s = 0.f; for (int k = 0; k < T_; ++k){ float e = __expf(row[k] - m); row[k] = e; s += e; }
    float inv = 1.f / s; for (int k = 0; k < T_; ++k) row[k] *= inv;
  }
  __syncthreads();
  for (int idx = tid; idx < T_*16; idx += 64){
    int t = idx / 16, o = idx % 16; int hh = o / 8, d = o % 8;
    float acc = 0.f;
    const float* row = ss + hh*144 + t*T_;
    for (int k = 0; k < T_; ++k) acc += row[k] * qs[k*48 + 32 + hh*8 + d];
    att[(((size_t)b*T_ + t)*N_ + n)*48 + o] = acc;
  }
}

// ---------------- geo attention v4: swapped QK^T + permuted-V staging ----------------
// S^T = mfma(K-frag, Q-frag): lane (g,r) reg rg holds P[q=r][key ks*32+4g+rg] (pA)
// and P[q=r][key ks*32+16+4g+rg] (pB). V is staged COLUMN-PERMUTED so the PV
// B-fragment is exactly [pA0..3, pB0..3] in-lane: pos(k) for k=m within chunk is
// 8*((m&15)>>2) + (m&3) + ((m&16)>>2)*... i.e. (m&~31)|(((m&15)>>2)<<3)|(m&3)|((m&16)>>2).
// -> zero cross-lane exchange, no P LDS buffer.
__global__ __launch_bounds__(256) void gattn(const float* __restrict__ qkv,
                                             const unsigned* __restrict__ bm,
                                             float* __restrict__ att){
  int bid = blockIdx.x;
  int sub = bid & 1; int h = (bid >> 1) & 3; int bt = bid >> 3;   // bt in [0,192)
  __shared__ unsigned short Kb[352*8];     // K bf16 pre-scaled by scale*log2(e), [k][d]
  __shared__ unsigned short Vt[16*360];    // V^T bf16 [d][pos], column-permuted (d 8-15 junk, discarded)
  int tid = threadIdx.x;
  const float* qkb = qkv + (size_t)bt*N_*144;
  const float kscale = 0.35355339059327373f * 1.4426950408889634f;
  for (int row = tid; row < 352; row += 256){
    const float* kr = qkb + (size_t)min(row, N_-1)*144 + 80 + h*8;
    float4 k0 = *(const float4*)kr;
    float4 k1 = *(const float4*)(kr + 4);
    uint4 wv4 = { cvt2(k0.x*kscale, k0.y*kscale), cvt2(k0.z*kscale, k0.w*kscale),
                  cvt2(k1.x*kscale, k1.y*kscale), cvt2(k1.z*kscale, k1.w*kscale) };
    *(uint4*)&Kb[row*8] = wv4;
  }
  for (int idx = tid; idx < 352*4; idx += 256){
    int row = idx >> 2, dp = idx & 3;           // row = actual key index
    int m = row & 31;
    int pos = (row & ~31) | (((m & 15) >> 2) << 3) | (m & 3) | ((m & 16) >> 2);
    const float* vr = qkb + (size_t)min(row, N_-1)*144 + 112 + h*8 + dp*2;
    float2 v = *(const float2*)vr;
    unsigned w = cvt2(v.x, v.y);
    Vt[(dp*2  )*360 + pos] = (unsigned short)w;
    Vt[(dp*2+1)*360 + pos] = (unsigned short)(w >> 16);
  }
  __syncthreads();

  int wv = tid >> 6, ln = tid & 63;
  int g = ln >> 4, r = ln & 15;
  int g4 = g*4;
  bool gzero = (g == 0);
  const bf16x8 z8 = {0,0,0,0,0,0,0,0};

  for (int tile = sub + 2*wv; tile < 21; tile += 8){
    int qb = tile*16;
    int qc = min(qb + r, N_-1);
    const uint4* bmp = (const uint4*)(bm + (size_t)(qb + r)*MW);
    uint4 m0 = bmp[0], m1 = bmp[1], m2 = bmp[2];
    unsigned bmw[11] = {m0.x,m0.y,m0.z,m0.w, m1.x,m1.y,m1.z,m1.w, m2.x,m2.y,m2.z};
    bf16x8 aq = z8;
    if (gzero){
      const float* qp = qkb + (size_t)qc*144 + 48 + h*8;
      float4 q0 = *(const float4*)qp;
      float4 q1 = *(const float4*)(qp + 4);
      uint4 u = { cvt2(q0.x,q0.y), cvt2(q0.z,q0.w), cvt2(q1.x,q1.y), cvt2(q1.z,q1.w) };
      aq = u2b(u);
    }
    float ssum = 0.f;
    f32x4 acc = {0.f,0.f,0.f,0.f};
    #pragma unroll
    for (int ks = 0; ks < 11; ++ks){
      bf16x8 akA = z8, akB = z8;
      if (gzero){
        akA = *(const bf16x8*)&Kb[(ks*32 + r)*8];
        akB = *(const bf16x8*)&Kb[(ks*32 + 16 + r)*8];
      }
      f32x4 dA = {0.f,0.f,0.f,0.f}, dB = {0.f,0.f,0.f,0.f};
      dA = __builtin_amdgcn_mfma_f32_16x16x32_bf16(akA, aq, dA, 0,0,0);
      dB = __builtin_amdgcn_mfma_f32_16x16x32_bf16(akB, aq, dB, 0,0,0);
      unsigned wm = bmw[ks];
      unsigned bA = (wm >> g4) & 0xFu;
      unsigned bB = (wm >> (g4 + 16)) & 0xFu;
      float pA[4], pB[4];
      #pragma unroll
      for (int rg = 0; rg < 4; ++rg){
        float eA = exp2f(dA[rg]);
        float eB = exp2f(dB[rg]);
        eA = (bA & (1u << rg)) ? 0.f : eA;
        eB = (bB & (1u << rg)) ? 0.f : eB;
        ssum += eA; ssum += eB;
        pA[rg] = eA; pB[rg] = eB;
      }
      // PV B-fragment directly from registers (V columns pre-permuted to match)
      uint4 pw = { cvt2(pA[0],pA[1]), cvt2(pA[2],pA[3]),
                   cvt2(pB[0],pB[1]), cvt2(pB[2],pB[3]) };
      bf16x8 av = *(const bf16x8*)&Vt[r*360 + ks*32 + g*8];
      acc = __builtin_amdgcn_mfma_f32_16x16x32_bf16(av, u2b(pw), acc, 0,0,0);
    }
    ssum += __shfl_xor(ssum, 16);
    ssum += __shfl_xor(ssum, 32);
    float inv = (ssum > 0.f) ? __builtin_amdgcn_rcpf(ssum) : 0.f;
    int qq = qb + r;
    if (g < 2 && qq < N_){
      float4 o = make_float4(acc[0]*inv, acc[1]*inv, acc[2]*inv, acc[3]*inv);
      *(float4*)(att + ((size_t)bt*N_ + qq)*48 + 16 + h*8 + g4) = o;
    }
  }
}

// ---------------- final projection (unchanged) ----------------
__global__ void proj_k(const float* __restrict__ att, const float* __restrict__ W_proj,
                       const float* __restrict__ b_proj, float* __restrict__ out){
  int bid = blockIdx.x;
  long r0 = (long)bid * 16;
  __shared__ float Ws[64*49], as[16*48], bs[64];
  int tid = threadIdx.x;
  for (int idx = tid; idx < 64*48; idx += 256){ int d = idx/48, j = idx%48; Ws[d*49 + j] = W_proj[idx]; }
  if (tid < 64) bs[tid] = b_proj[tid];
  for (int idx = tid; idx < 16*48; idx += 256){
    long r = r0 + idx/48;
    as[idx] = (r < (long)B_*T_*N_) ? att[r*48 + idx%48] : 0.f;
  }
  __syncthreads();
  for (int idx = tid; idx < 16*64; idx += 256){
    int rr = idx >> 6, d = idx & 63;
    long r = r0 + rr;
    if (r >= (long)B_*T_*N_) continue;
    float acc = bs[d];
    const float* w = Ws + d*49; const float* a = as + rr*48;
    for (int j = 0; j < 48; ++j) acc += w[j] * a[j];
    out[r*64 + d] = acc;
  }
}

extern "C" void kernel_launch(void* const* d_in, const int* in_sizes, int n_in,
                              void* d_out, int out_size, void* d_ws, size_t ws_size,
                              hipStream_t stream){
  const float* x      = (const float*)d_in[0];
  const int*   ind    = (const int*)  d_in[1];
  const unsigned char* gmask_raw = (const unsigned char*)d_in[4];
  const float* p1     = (const float*)d_in[5];
  const float* p2     = (const float*)d_in[6];
  const float* p3     = (const float*)d_in[7];
  const float* pk     = (const float*)d_in[8];
  const float* W_r1   = (const float*)d_in[9];
  const float* b_r1   = (const float*)d_in[10];
  const float* W_gcn  = (const float*)d_in[11];
  const float* b_gcn  = (const float*)d_in[12];
  const float* W_r2   = (const float*)d_in[13];
  const float* b_r2   = (const float*)d_in[14];
  const float* Wtq    = (const float*)d_in[15];
  const float* Wtk    = (const float*)d_in[16];
  const float* Wtv    = (const float*)d_in[17];
  const float* Wgq    = (const float*)d_in[18];
  const float* Wgk    = (const float*)d_in[19];
  const float* Wgv    = (const float*)d_in[20];
  const float* W_proj = (const float*)d_in[21];
  const float* b_proj = (const float*)d_in[22];
  float* out = (float*)d_out;

  float* ws = (float*)d_ws;
  float* adp  = ws; ws += (size_t)B_*N_*N_;
  float* A1   = ws; ws += B_*DIMS_*DIMS_;
  float* h    = ws; ws += (size_t)B_*N_*384;
  float* x1   = ws; ws += (size_t)B_*N_*384;
  float* x2   = ws; ws += (size_t)B_*N_*384;
  float* bc   = ws; ws += 64;
  float* qkv  = ws; ws += (size_t)B_*T_*N_*144;
  float* att  = ws; ws += (size_t)B_*T_*N_*48;
  int*   mmode = (int*)ws; ws += 16;
  unsigned* bm = (unsigned*)ws; ws += NQP*MW;           // 4032 words
  unsigned short* us = (unsigned short*)ws;
  unsigned short* xg_bf = us; us += (size_t)B_*T_*N_*64; // bf16
  unsigned short* Wcb   = us; us += 3*4*64*8;            // 6144
  unsigned short* Wallb = us; us += 2*4*144*8;           // 9216

  mask_detect <<<1,         256, 0, stream>>>(gmask_raw, mmode);
  mask_bits   <<<(NQP*MW+255)/256, 256, 0, stream>>>(gmask_raw, mmode, bm);
  dg_a1       <<<B_,        256, 0, stream>>>(p1, pk, ind, A1);
  dg_adp      <<<B_*N_,     128, 0, stream>>>(p2, p3, A1, adp);
  prep_weights<<<2,         256, 0, stream>>>(W_gcn, b_gcn, W_r2, b_r2,
                                              Wtq, Wtk, Wtv, Wgq, Wgk, Wgv, bc, Wcb, Wallb);
  hproj       <<<B_*N_,     384, 0, stream>>>(x, W_r1, b_r1, h);
  gcn_mm      <<<B_*41,     384, 0, stream>>>(adp, h,  x1);
  gcn_mm      <<<B_*41,     384, 0, stream>>>(adp, x1, x2);
  xg_k        <<<(B_*N_+3)/4, 256, 0, stream>>>(h, x1, x2, Wcb, bc, xg_bf);
  qkv_k       <<<192*6,     256, 0, stream>>>(xg_bf, Wallb, qkv);
  tattn       <<<B_*N_,      64, 0, stream>>>(qkv, att);
  gattn       <<<192*4*2,   256, 0, stream>>>(qkv, bm, att);
  proj_k      <<<3900,      256, 0, stream>>>(att, W_proj, b_proj, out);
}

// Round 8
// 238.404 us; speedup vs baseline: 1.7562x; 1.2207x over previous
//
#include <hip/hip_runtime.h>
#include <hip/hip_bf16.h>
#include <math.h>

#define B_ 16
#define T_ 12
#define N_ 325
#define DIMS_ 40
#define DAYS_ 288
#define MW 12          // bitmask words per mask row (11 used, 1 pad)
#define NQP 336        // padded q-rows for mask (21*16)
#define VP 352         // padded v/ct-row stride for transposed bf16 arrays (11*32)

typedef __attribute__((ext_vector_type(8))) short bf16x8;
typedef __attribute__((ext_vector_type(4))) float f32x4;

__device__ __forceinline__ unsigned short cvt1(float f){
  unsigned w;
  asm("v_cvt_pk_bf16_f32 %0, %1, %2" : "=v"(w) : "v"(f), "v"(f));
  return (unsigned short)w;
}
__device__ __forceinline__ unsigned cvt2(float a, float b){
  unsigned w;
  asm("v_cvt_pk_bf16_f32 %0, %1, %2" : "=v"(w) : "v"(a), "v"(b));
  return w;
}
__device__ __forceinline__ bf16x8 u2b(uint4 u){ return __builtin_bit_cast(bf16x8, u); }

// ---------------- mask dtype detection + bitmask build ----------------
__global__ void mask_detect(const unsigned char* __restrict__ raw, int* __restrict__ mode){
  __shared__ int f3F_m1, f3F_m3, fNZ_o;
  if (threadIdx.x == 0){ f3F_m1 = 0; f3F_m3 = 0; fNZ_o = 0; }
  __syncthreads();
  for (int i = threadIdx.x; i < 4096; i += 256){
    unsigned char v = raw[i];
    int m4 = i & 3;
    if (v == 0x3F && m4 == 1) atomicOr(&f3F_m1, 1);
    if (v == 0x3F && m4 == 3) atomicOr(&f3F_m3, 1);
    if (v != 0 && m4 != 0)    atomicOr(&fNZ_o, 1);
  }
  __syncthreads();
  if (threadIdx.x == 0){
    int m;
    if (f3F_m1) m = 2;
    else if (f3F_m3) m = 3;
    else if (fNZ_o) m = 0;
    else m = 1;
    *mode = m;
  }
}

__global__ void mask_bits(const unsigned char* __restrict__ raw, const int* __restrict__ mode_p,
                          unsigned* __restrict__ bm){
  int mode = *mode_p;
  int idx = blockIdx.x * 256 + threadIdx.x;
  if (idx >= NQP * MW) return;
  int q = idx / MW, w = idx % MW;
  if (q >= N_) { bm[idx] = 0xFFFFFFFFu; return; }
  unsigned bits = 0;
  for (int j = 0; j < 32; ++j){
    int k = w*32 + j;
    int v;
    if (k >= N_) v = 1;
    else {
      size_t i = (size_t)q*N_ + k;
      if (mode == 0)      v = raw[i] != 0;
      else if (mode == 1) v = ((const int*)raw)[i] != 0;
      else if (mode == 2) { unsigned short u = ((const unsigned short*)raw)[i]; v = (u & 0x7FFF) != 0; }
      else                { float f = ((const float*)raw)[i]; v = (f != 0.f); }
    }
    bits |= (unsigned)v << j;
  }
  bm[idx] = bits;
}

// ---------------- dynamic graph construct ----------------
__global__ void dg_a1(const float* __restrict__ p1, const float* __restrict__ pk,
                      const int* __restrict__ ind, float* __restrict__ A1){
  int b = blockIdx.x;
  __shared__ float te[DIMS_];
  int day = ind[b] % DAYS_; if (day < 0) day += DAYS_;
  for (int i = threadIdx.x; i < DIMS_; i += blockDim.x) te[i] = p1[day*DIMS_ + i];
  __syncthreads();
  for (int jk = threadIdx.x; jk < DIMS_*DIMS_; jk += blockDim.x){
    float acc = 0.f;
    for (int i = 0; i < DIMS_; ++i) acc += te[i] * pk[i*DIMS_*DIMS_ + jk];
    A1[b*DIMS_*DIMS_ + jk] = acc;
  }
}

// adp_bf[b][n][c] bf16, row stride VP, cols >= N_ zeroed (pad-safe for MFMA K)
__global__ void dg_adp(const float* __restrict__ p2, const float* __restrict__ p3,
                       const float* __restrict__ A1, unsigned short* __restrict__ adp_bf){
  int bid = blockIdx.x; int b = bid / N_; int n = bid % N_;
  __shared__ float p2r[DIMS_], t2[DIMS_], sbuf[N_], red[128];
  int tid = threadIdx.x;
  if (tid < DIMS_) p2r[tid] = p2[n*DIMS_ + tid];
  __syncthreads();
  if (tid < DIMS_){
    float acc = 0.f;
    const float* a1 = A1 + b*DIMS_*DIMS_;
    for (int j = 0; j < DIMS_; ++j) acc += p2r[j] * a1[j*DIMS_ + tid];
    t2[tid] = acc;
  }
  __syncthreads();
  float lm = -INFINITY;
  for (int c = tid; c < N_; c += 128){
    float acc = 0.f;
    for (int k = 0; k < DIMS_; ++k) acc += p3[c*DIMS_ + k] * t2[k];
    acc = fmaxf(acc, 0.f);
    sbuf[c] = acc; lm = fmaxf(lm, acc);
  }
  red[tid] = lm; __syncthreads();
  for (int off = 64; off; off >>= 1){ if (tid < off) red[tid] = fmaxf(red[tid], red[tid+off]); __syncthreads(); }
  float m = red[0]; __syncthreads();
  float ls = 0.f;
  for (int c = tid; c < N_; c += 128){ float e = __expf(sbuf[c] - m); sbuf[c] = e; ls += e; }
  red[tid] = ls; __syncthreads();
  for (int off = 64; off; off >>= 1){ if (tid < off) red[tid] += red[tid+off]; __syncthreads(); }
  float inv = 1.f / red[0];
  unsigned short* outp = adp_bf + ((size_t)b*N_ + n) * VP;
  for (int c = tid; c < VP; c += 128)
    outp[c] = (c < N_) ? cvt1(sbuf[c] * inv) : (unsigned short)0;
}

// ---------------- weight prep ----------------
__global__ void prep_weights(const float* W_gcn, const float* b_gcn, const float* W_r2, const float* b_r2,
                             const float* Wtq, const float* Wtk, const float* Wtv,
                             const float* Wgq, const float* Wgk, const float* Wgv,
                             const float* W_proj,
                             float* bc, unsigned short* Wcb, unsigned short* Wallb,
                             unsigned short* Wpb){
  int tid = threadIdx.x;
  if (blockIdx.x == 0){
    __shared__ float WcS[64*96];
    for (int idx = tid; idx < 64*96; idx += 256){
      int d = idx / 96, c = idx % 96;
      float acc = 0.f;
      for (int o = 0; o < 32; ++o) acc += W_r2[d*32 + o] * W_gcn[o*96 + c];
      WcS[idx] = acc;
    }
    for (int d = tid; d < 64; d += 256){
      float acc = b_r2[d];
      for (int o = 0; o < 32; ++o) acc += W_r2[d*32 + o] * b_gcn[o];
      bc[d] = acc;
    }
    __syncthreads();
    for (int idx = tid; idx < 3*4*64*8; idx += 256){
      int jj = idx & 7, rest = idx >> 3;
      int d = rest % 64, gk = rest / 64;
      int g = gk & 3, kc = gk >> 2;
      Wcb[idx] = cvt1(WcS[d*96 + kc*32 + g*8 + jj]);
    }
  } else if (blockIdx.x == 1){
    for (int idx = tid; idx < 2*4*144*8; idx += 256){
      int jj = idx & 7, rest = idx >> 3;
      int j = rest % 144, gk = rest / 144;
      int g = gk & 3, kc = gk >> 2;
      int dd = kc*32 + g*8 + jj;
      const float* src; int rsrc;
      if      (j < 16) { src = Wtq; rsrc = j; }
      else if (j < 32) { src = Wtk; rsrc = j - 16; }
      else if (j < 48) { src = Wtv; rsrc = j - 32; }
      else if (j < 80) { src = Wgq; rsrc = j - 48; }
      else if (j < 112){ src = Wgk; rsrc = j - 80; }
      else             { src = Wgv; rsrc = j - 112; }
      Wallb[idx] = cvt1(src[rsrc*64 + dd]);
    }
  } else {
    for (int idx = tid; idx < 2*4*64*8; idx += 256){
      int jj = idx & 7, rest = idx >> 3;
      int d = rest % 64, gk = rest / 64;
      int g = gk & 3, kc = gk >> 2;
      int k = kc*32 + g*8 + jj;
      Wpb[idx] = (k < 48) ? cvt1(W_proj[d*48 + k]) : (unsigned short)0;
    }
  }
}

// ---------------- h projection -> TRANSPOSED bf16: ht[b][ct=t*32+c][n], stride VP ----------------
__global__ void hproj(const float* __restrict__ x, const float* __restrict__ W_r1,
                      const float* __restrict__ b_r1, unsigned short* __restrict__ ht){
  int bid = blockIdx.x; int b = bid / N_, n = bid % N_;
  __shared__ float xs[T_*65], Ws[32*65];
  int tid = threadIdx.x;
  for (int idx = tid; idx < 32*64; idx += 384){ int c = idx >> 6, d = idx & 63; Ws[c*65 + d] = W_r1[idx]; }
  for (int idx = tid; idx < T_*64; idx += 384){
    int t = idx >> 6, d = idx & 63;
    xs[t*65 + d] = x[(((size_t)b*T_ + t)*N_ + n)*64 + d];
  }
  __syncthreads();
  int c = tid / T_, t = tid % T_;
  float acc = b_r1[c];
  for (int d = 0; d < 64; ++d) acc += xs[t*65 + d] * Ws[c*65 + d];
  ht[((size_t)b*384 + t*32 + c)*VP + n] = cvt1(acc);
}

// ---------------- GCN hop as MFMA GEMM, no LDS ----------------
// out_t[ct][w] = sum_v adp[w][v] * in_t[ct][v]  (transposed bf16, stride VP)
__global__ __launch_bounds__(256) void gcn_mfma(const unsigned short* __restrict__ adp_bf,
                                                const unsigned short* __restrict__ in_t,
                                                unsigned short* __restrict__ out_t){
  int bi = blockIdx.x;
  int b = bi / 36, rest = bi % 36;
  int wt = rest / 6, ctb = rest % 6;
  int tid = threadIdx.x, wv = tid >> 6, ln = tid & 63, g = ln >> 4, r = ln & 15;
  int w0 = wt*64 + wv*16;
  int ct0 = ctb*64;
  int wr = min(w0 + r, N_-1);
  const unsigned short* arow  = adp_bf + ((size_t)b*N_ + wr)*VP;
  const unsigned short* bbase = in_t  + ((size_t)b*384 + ct0)*VP;
  f32x4 acc0={0.f,0.f,0.f,0.f}, acc1=acc0, acc2=acc0, acc3=acc0;
  #pragma unroll
  for (int ks = 0; ks < 11; ++ks){
    int ko = ks*32 + g*8;
    bf16x8 a  = *(const bf16x8*)&arow[ko];
    bf16x8 b0 = *(const bf16x8*)&bbase[(size_t)( 0 + r)*VP + ko];
    bf16x8 b1 = *(const bf16x8*)&bbase[(size_t)(16 + r)*VP + ko];
    bf16x8 b2 = *(const bf16x8*)&bbase[(size_t)(32 + r)*VP + ko];
    bf16x8 b3 = *(const bf16x8*)&bbase[(size_t)(48 + r)*VP + ko];
    acc0 = __builtin_amdgcn_mfma_f32_16x16x32_bf16(a, b0, acc0, 0,0,0);
    acc1 = __builtin_amdgcn_mfma_f32_16x16x32_bf16(a, b1, acc1, 0,0,0);
    acc2 = __builtin_amdgcn_mfma_f32_16x16x32_bf16(a, b2, acc2, 0,0,0);
    ac3:;
    acc3 = __builtin_amdgcn_mfma_f32_16x16x32_bf16(a, b3, acc3, 0,0,0);
  }
  if (w0 + 15 < VP){
    f32x4 av[4] = {acc0, acc1, acc2, acc3};
    #pragma unroll
    for (int dt = 0; dt < 4; ++dt){
      int ct = ct0 + dt*16 + r;
      uint2 pk2 = { cvt2(av[dt][0], av[dt][1]), cvt2(av[dt][2], av[dt][3]) };
      *(uint2*)&out_t[((size_t)b*384 + ct)*VP + w0 + g*4] = pk2;
    }
  }
}

// ---------------- xg: MFMA GEMM per (b,n), staging from transposed bf16 arrays ----------------
__global__ __launch_bounds__(256) void xg_k(const unsigned short* __restrict__ ht,
                                            const unsigned short* __restrict__ x1t,
                                            const unsigned short* __restrict__ x2t,
                                            const unsigned short* __restrict__ Wcb,
                                            const float* __restrict__ bc,
                                            unsigned short* __restrict__ xg_bf){
  __shared__ unsigned short catA[4][16*104];
  int tid = threadIdx.x, wv = tid >> 6, ln = tid & 63;
  int p = blockIdx.x*4 + wv;
  int b = p / N_, n = p % N_;
  unsigned short* ca = &catA[wv][0];
  #pragma unroll
  for (int ii = 0; ii < 6; ++ii){
    int s2 = ln + 64*ii;            // s2 = ct = t*32+c
    int t = s2 >> 5, c = s2 & 31;
    size_t gi = ((size_t)b*384 + s2)*VP + n;
    unsigned short* row = ca + t*104;
    row[c]      = ht [gi];
    row[32 + c] = x1t[gi];
    row[64 + c] = x2t[gi];
  }
  int g = ln >> 4, r = ln & 15;
  bf16x8 a0 = *(const bf16x8*)&ca[r*104 +  0 + g*8];
  bf16x8 a1 = *(const bf16x8*)&ca[r*104 + 32 + g*8];
  bf16x8 a2 = *(const bf16x8*)&ca[r*104 + 64 + g*8];
  #pragma unroll
  for (int dt = 0; dt < 4; ++dt){
    f32x4 acc = {0.f,0.f,0.f,0.f};
    bf16x8 b0 = *(const bf16x8*)&Wcb[((0*4+g)*64 + dt*16 + r)*8];
    bf16x8 b1 = *(const bf16x8*)&Wcb[((1*4+g)*64 + dt*16 + r)*8];
    bf16x8 b2 = *(const bf16x8*)&Wcb[((2*4+g)*64 + dt*16 + r)*8];
    acc = __builtin_amdgcn_mfma_f32_16x16x32_bf16(a0, b0, acc, 0,0,0);
    acc = __builtin_amdgcn_mfma_f32_16x16x32_bf16(a1, b1, acc, 0,0,0);
    acc = __builtin_amdgcn_mfma_f32_16x16x32_bf16(a2, b2, acc, 0,0,0);
    float bias = bc[dt*16 + r];
    if (g < 3){
      #pragma unroll
      for (int rg = 0; rg < 4; ++rg){
        int t = g*4 + rg;   // < 12
        xg_bf[(((size_t)b*T_ + t)*N_ + n)*64 + dt*16 + r] = cvt1(acc[rg] + bias);
      }
    }
  }
}

// ---------------- qkv: MFMA GEMM, no LDS (unchanged) ----------------
__global__ __launch_bounds__(256) void qkv_k(const unsigned short* __restrict__ xg_bf,
                                             const unsigned short* __restrict__ Wallb,
                                             float* __restrict__ qkv){
  int tid = threadIdx.x, wv = tid >> 6, ln = tid & 63;
  int bt = blockIdx.x / 6;
  int nt = (blockIdx.x % 6)*4 + wv;
  if (nt >= 21) return;
  int g = ln >> 4, r = ln & 15;
  int n0 = nt*16;
  int nc = min(n0 + r, N_-1);
  const unsigned short* arow = xg_bf + ((size_t)bt*N_ + nc)*64;
  bf16x8 a0 = *(const bf16x8*)&arow[g*8];
  bf16x8 a1 = *(const bf16x8*)&arow[32 + g*8];
  #pragma unroll
  for (int jt = 0; jt < 9; ++jt){
    f32x4 acc = {0.f,0.f,0.f,0.f};
    bf16x8 b0 = *(const bf16x8*)&Wallb[((0*4+g)*144 + jt*16 + r)*8];
    bf16x8 b1 = *(const bf16x8*)&Wallb[((1*4+g)*144 + jt*16 + r)*8];
    acc = __builtin_amdgcn_mfma_f32_16x16x32_bf16(a0, b0, acc, 0,0,0);
    acc = __builtin_amdgcn_mfma_f32_16x16x32_bf16(a1, b1, acc, 0,0,0);
    #pragma unroll
    for (int rg = 0; rg < 4; ++rg){
      int n = n0 + g*4 + rg;
      if (n < N_) qkv[((size_t)bt*N_ + n)*144 + jt*16 + r] = acc[rg];
    }
  }
}

// ---------------- temporal attention (unchanged) ----------------
__global__ void tattn(const float* __restrict__ qkv, float* __restrict__ att){
  int bid = blockIdx.x; int b = bid / N_, n = bid % N_;
  __shared__ float qs[T_*48], ss[2*T_*T_];
  int tid = threadIdx.x;
  for (int idx = tid; idx < T_*48; idx += 64){
    int t = idx / 48, j = idx % 48;
    qs[idx] = qkv[(((size_t)b*T_ + t)*N_ + n)*144 + j];
  }
  __syncthreads();
  const float scale = 0.35355339059327373f;
  for (int idx = tid; idx < 2*T_*T_; idx += 64){
    int hh = idx / 144, r = (idx / T_) % T_, c = idx % T_;
    float acc = 0.f;
    for (int d = 0; d < 8; ++d) acc += qs[r*48 + hh*8 + d] * qs[c*48 + 16 + hh*8 + d];
    ss[idx] = acc * scale;
  }
  __syncthreads();
  if (tid < 2*T_){
    int hh = tid / T_, r = tid % T_;
    float* row = ss + hh*144 + r*T_;
    float m = -INFINITY; for (int k = 0; k < T_; ++k) m = fmaxf(m, row[k]);
    float s = 0.f; for (int k = 0; k < T_; ++k){ float e = __expf(row[k] - m); row[k] = e; s += e; }
    float inv = 1.f / s; for (int k = 0; k < T_; ++k) row[k] *= inv;
  }
  __syncthreads();
  for (int idx = tid; idx < T_*16; idx += 64){
    int t = idx / 16, o = idx % 16; int hh = o / 8, d = o % 8;
    float acc = 0.f;
    const float* row = ss + hh*144 + t*T_;
    for (int k = 0; k < T_; ++k) acc += row[k] * qs[k*48 + 32 + hh*8 + d];
    att[(((size_t)b*T_ + t)*N_ + n)*48 + o] = acc;
  }
}

// ---------------- geo attention v4 (unchanged from round 7) ----------------
__global__ __launch_bounds__(256) void gattn(const float* __restrict__ qkv,
                                             const unsigned* __restrict__ bm,
                                             float* __restrict__ att){
  int bid = blockIdx.x;
  int sub = bid & 1; int h = (bid >> 1) & 3; int bt = bid >> 3;
  __shared__ unsigned short Kb[352*8];
  __shared__ unsigned short Vt[16*360];
  int tid = threadIdx.x;
  const float* qkb = qkv + (size_t)bt*N_*144;
  const float kscale = 0.35355339059327373f * 1.4426950408889634f;
  for (int row = tid; row < 352; row += 256){
    const float* kr = qkb + (size_t)min(row, N_-1)*144 + 80 + h*8;
    float4 k0 = *(const float4*)kr;
    float4 k1 = *(const float4*)(kr + 4);
    uint4 wv4 = { cvt2(k0.x*kscale, k0.y*kscale), cvt2(k0.z*kscale, k0.w*kscale),
                  cvt2(k1.x*kscale, k1.y*kscale), cvt2(k1.z*kscale, k1.w*kscale) };
    *(uint4*)&Kb[row*8] = wv4;
  }
  for (int idx = tid; idx < 352*4; idx += 256){
    int row = idx >> 2, dp = idx & 3;
    int m = row & 31;
    int pos = (row & ~31) | (((m & 15) >> 2) << 3) | (m & 3) | ((m & 16) >> 2);
    const float* vr = qkb + (size_t)min(row, N_-1)*144 + 112 + h*8 + dp*2;
    float2 v = *(const float2*)vr;
    unsigned w = cvt2(v.x, v.y);
    Vt[(dp*2  )*360 + pos] = (unsigned short)w;
    Vt[(dp*2+1)*360 + pos] = (unsigned short)(w >> 16);
  }
  __syncthreads();

  int wv = tid >> 6, ln = tid & 63;
  int g = ln >> 4, r = ln & 15;
  int g4 = g*4;
  bool gzero = (g == 0);
  const bf16x8 z8 = {0,0,0,0,0,0,0,0};

  for (int tile = sub + 2*wv; tile < 21; tile += 8){
    int qb = tile*16;
    int qc = min(qb + r, N_-1);
    const uint4* bmp = (const uint4*)(bm + (size_t)(qb + r)*MW);
    uint4 m0 = bmp[0], m1 = bmp[1], m2 = bmp[2];
    unsigned bmw[11] = {m0.x,m0.y,m0.z,m0.w, m1.x,m1.y,m1.z,m1.w, m2.x,m2.y,m2.z};
    bf16x8 aq = z8;
    if (gzero){
      const float* qp = qkb + (size_t)qc*144 + 48 + h*8;
      float4 q0 = *(const float4*)qp;
      float4 q1 = *(const float4*)(qp + 4);
      uint4 u = { cvt2(q0.x,q0.y), cvt2(q0.z,q0.w), cvt2(q1.x,q1.y), cvt2(q1.z,q1.w) };
      aq = u2b(u);
    }
    float ssum = 0.f;
    f32x4 acc = {0.f,0.f,0.f,0.f};
    #pragma unroll
    for (int ks = 0; ks < 11; ++ks){
      bf16x8 akA = z8, akB = z8;
      if (gzero){
        akA = *(const bf16x8*)&Kb[(ks*32 + r)*8];
        akB = *(const bf16x8*)&Kb[(ks*32 + 16 + r)*8];
      }
      f32x4 dA = {0.f,0.f,0.f,0.f}, dB = {0.f,0.f,0.f,0.f};
      dA = __builtin_amdgcn_mfma_f32_16x16x32_bf16(akA, aq, dA, 0,0,0);
      dB = __builtin_amdgcn_mfma_f32_16x16x32_bf16(akB, aq, dB, 0,0,0);
      unsigned wm = bmw[ks];
      unsigned bA = (wm >> g4) & 0xFu;
      unsigned bB = (wm >> (g4 + 16)) & 0xFu;
      float pA[4], pB[4];
      #pragma unroll
      for (int rg = 0; rg < 4; ++rg){
        float eA = exp2f(dA[rg]);
        float eB = exp2f(dB[rg]);
        eA = (bA & (1u << rg)) ? 0.f : eA;
        eB = (bB & (1u << rg)) ? 0.f : eB;
        ssum += eA; ssum += eB;
        pA[rg] = eA; pB[rg] = eB;
      }
      uint4 pw = { cvt2(pA[0],pA[1]), cvt2(pA[2],pA[3]),
                   cvt2(pB[0],pB[1]), cvt2(pB[2],pB[3]) };
      bf16x8 av = *(const bf16x8*)&Vt[r*360 + ks*32 + g*8];
      acc = __builtin_amdgcn_mfma_f32_16x16x32_bf16(av, u2b(pw), acc, 0,0,0);
    }
    ssum += __shfl_xor(ssum, 16);
    ssum += __shfl_xor(ssum, 32);
    float inv = (ssum > 0.f) ? __builtin_amdgcn_rcpf(ssum) : 0.f;
    int qq = qb + r;
    if (g < 2 && qq < N_){
      float4 o = make_float4(acc[0]*inv, acc[1]*inv, acc[2]*inv, acc[3]*inv);
      *(float4*)(att + ((size_t)bt*N_ + qq)*48 + 16 + h*8 + g4) = o;
    }
  }
}

// ---------------- final projection: MFMA GEMM ----------------
__global__ __launch_bounds__(256) void proj_k(const float* __restrict__ att,
                                              const unsigned short* __restrict__ Wpb,
                                              const float* __restrict__ b_proj,
                                              float* __restrict__ out){
  int tid = threadIdx.x, wv = tid >> 6, ln = tid & 63;
  int g = ln >> 4, r = ln & 15;
  long r0 = ((long)blockIdx.x*4 + wv)*16;
  const float* arow = att + (r0 + r)*48;
  float4 qa = *(const float4*)&arow[g*8];
  float4 qb = *(const float4*)&arow[g*8 + 4];
  uint4 u0 = { cvt2(qa.x,qa.y), cvt2(qa.z,qa.w), cvt2(qb.x,qb.y), cvt2(qb.z,qb.w) };
  bf16x8 a0 = u2b(u0);
  bf16x8 a1 = {0,0,0,0,0,0,0,0};
  if (g < 2){
    float4 qc = *(const float4*)&arow[32 + g*8];
    float4 qd = *(const float4*)&arow[36 + g*8];
    uint4 u1 = { cvt2(qc.x,qc.y), cvt2(qc.z,qc.w), cvt2(qd.x,qd.y), cvt2(qd.z,qd.w) };
    a1 = u2b(u1);
  }
  #pragma unroll
  for (int dt = 0; dt < 4; ++dt){
    f32x4 acc = {0.f,0.f,0.f,0.f};
    bf16x8 b0 = *(const bf16x8*)&Wpb[((0*4+g)*64 + dt*16 + r)*8];
    bf16x8 b1 = *(const bf16x8*)&Wpb[((1*4+g)*64 + dt*16 + r)*8];
    acc = __builtin_amdgcn_mfma_f32_16x16x32_bf16(a0, b0, acc, 0,0,0);
    acc = __builtin_amdgcn_mfma_f32_16x16x32_bf16(a1, b1, acc, 0,0,0);
    float bias = b_proj[dt*16 + r];
    #pragma unroll
    for (int rg = 0; rg < 4; ++rg)
      out[(r0 + g*4 + rg)*64 + dt*16 + r] = acc[rg] + bias;
  }
}

extern "C" void kernel_launch(void* const* d_in, const int* in_sizes, int n_in,
                              void* d_out, int out_size, void* d_ws, size_t ws_size,
                              hipStream_t stream){
  const float* x      = (const float*)d_in[0];
  const int*   ind    = (const int*)  d_in[1];
  const unsigned char* gmask_raw = (const unsigned char*)d_in[4];
  const float* p1     = (const float*)d_in[5];
  const float* p2     = (const float*)d_in[6];
  const float* p3     = (const float*)d_in[7];
  const float* pk     = (const float*)d_in[8];
  const float* W_r1   = (const float*)d_in[9];
  const float* b_r1   = (const float*)d_in[10];
  const float* W_gcn  = (const float*)d_in[11];
  const float* b_gcn  = (const float*)d_in[12];
  const float* W_r2   = (const float*)d_in[13];
  const float* b_r2   = (const float*)d_in[14];
  const float* Wtq    = (const float*)d_in[15];
  const float* Wtk    = (const float*)d_in[16];
  const float* Wtv    = (const float*)d_in[17];
  const float* Wgq    = (const float*)d_in[18];
  const float* Wgk    = (const float*)d_in[19];
  const float* Wgv    = (const float*)d_in[20];
  const float* W_proj = (const float*)d_in[21];
  const float* b_proj = (const float*)d_in[22];
  float* out = (float*)d_out;

  float* ws = (float*)d_ws;
  float* A1   = ws; ws += B_*DIMS_*DIMS_;
  float* bc   = ws; ws += 64;
  float* qkv  = ws; ws += (size_t)B_*T_*N_*144;
  float* att  = ws; ws += (size_t)B_*T_*N_*48;
  int*   mmode = (int*)ws; ws += 16;
  unsigned* bm = (unsigned*)ws; ws += NQP*MW;
  unsigned short* us = (unsigned short*)ws;
  unsigned short* adp_bf = us; us += (size_t)B_*N_*VP;
  unsigned short* ht     = us; us += (size_t)B_*384*VP;
  unsigned short* x1t    = us; us += (size_t)B_*384*VP;
  unsigned short* x2t    = us; us += (size_t)B_*384*VP;
  unsigned short* xg_bf  = us; us += (size_t)B_*T_*N_*64;
  unsigned short* Wcb    = us; us += 3*4*64*8;
  unsigned short* Wallb  = us; us += 2*4*144*8;
  unsigned short* Wpb    = us; us += 2*4*64*8;

  mask_detect <<<1,         256, 0, stream>>>(gmask_raw, mmode);
  mask_bits   <<<(NQP*MW+255)/256, 256, 0, stream>>>(gmask_raw, mmode, bm);
  dg_a1       <<<B_,        256, 0, stream>>>(p1, pk, ind, A1);
  dg_adp      <<<B_*N_,     128, 0, stream>>>(p2, p3, A1, adp_bf);
  prep_weights<<<3,         256, 0, stream>>>(W_gcn, b_gcn, W_r2, b_r2,
                                              Wtq, Wtk, Wtv, Wgq, Wgk, Wgv,
                                              W_proj, bc, Wcb, Wallb, Wpb);
  hproj       <<<B_*N_,     384, 0, stream>>>(x, W_r1, b_r1, ht);
  gcn_mfma    <<<B_*36,     256, 0, stream>>>(adp_bf, ht,  x1t);
  gcn_mfma    <<<B_*36,     256, 0, stream>>>(adp_bf, x1t, x2t);
  xg_k        <<<(B_*N_)/4, 256, 0, stream>>>(ht, x1t, x2t, Wcb, bc, xg_bf);
  qkv_k       <<<192*6,     256, 0, stream>>>(xg_bf, Wallb, qkv);
  tattn       <<<B_*N_,      64, 0, stream>>>(qkv, att);
  gattn       <<<192*4*2,   256, 0, stream>>>(qkv, bm, att);
  proj_k      <<<(B_*T_*N_/16)/4, 256, 0, stream>>>(att, Wpb, b_proj, out);
}

// Round 9
// 221.439 us; speedup vs baseline: 1.8908x; 1.0766x over previous
//
#include <hip/hip_runtime.h>
#include <hip/hip_bf16.h>
#include <math.h>

#define B_ 16
#define T_ 12
#define N_ 325
#define DIMS_ 40
#define DAYS_ 288
#define MW 12          // bitmask words per mask row (11 used, 1 pad)
#define NQP 336        // padded q-rows for mask (21*16)
#define VP 352         // padded v/ct-row stride for transposed bf16 arrays (11*32)

typedef __attribute__((ext_vector_type(8))) short bf16x8;
typedef __attribute__((ext_vector_type(4))) float f32x4;

__device__ __forceinline__ unsigned short cvt1(float f){
  unsigned w;
  asm("v_cvt_pk_bf16_f32 %0, %1, %2" : "=v"(w) : "v"(f), "v"(f));
  return (unsigned short)w;
}
__device__ __forceinline__ unsigned cvt2(float a, float b){
  unsigned w;
  asm("v_cvt_pk_bf16_f32 %0, %1, %2" : "=v"(w) : "v"(a), "v"(b));
  return w;
}
__device__ __forceinline__ bf16x8 u2b(uint4 u){ return __builtin_bit_cast(bf16x8, u); }

// ---------------- mask dtype detection ----------------
__global__ void mask_detect(const unsigned char* __restrict__ raw, int* __restrict__ mode){
  __shared__ int f3F_m1, f3F_m3, fNZ_o;
  if (threadIdx.x == 0){ f3F_m1 = 0; f3F_m3 = 0; fNZ_o = 0; }
  __syncthreads();
  for (int i = threadIdx.x; i < 4096; i += 256){
    unsigned char v = raw[i];
    int m4 = i & 3;
    if (v == 0x3F && m4 == 1) atomicOr(&f3F_m1, 1);
    if (v == 0x3F && m4 == 3) atomicOr(&f3F_m3, 1);
    if (v != 0 && m4 != 0)    atomicOr(&fNZ_o, 1);
  }
  __syncthreads();
  if (threadIdx.x == 0){
    int m;
    if (f3F_m1) m = 2;
    else if (f3F_m3) m = 3;
    else if (fNZ_o) m = 0;
    else m = 1;
    *mode = m;
  }
}

// ---------------- fused setup: blocks 0-15 dg_a1, blocks 16-31 mask_bits ----------------
__global__ void setup_k(const float* __restrict__ p1, const float* __restrict__ pk,
                        const int* __restrict__ ind, float* __restrict__ A1,
                        const unsigned char* __restrict__ raw, const int* __restrict__ mode_p,
                        unsigned* __restrict__ bm){
  if (blockIdx.x < 16){
    int b = blockIdx.x;
    __shared__ float te[DIMS_];
    int day = ind[b] % DAYS_; if (day < 0) day += DAYS_;
    for (int i = threadIdx.x; i < DIMS_; i += blockDim.x) te[i] = p1[day*DIMS_ + i];
    __syncthreads();
    for (int jk = threadIdx.x; jk < DIMS_*DIMS_; jk += blockDim.x){
      float acc = 0.f;
      for (int i = 0; i < DIMS_; ++i) acc += te[i] * pk[i*DIMS_*DIMS_ + jk];
      A1[b*DIMS_*DIMS_ + jk] = acc;
    }
  } else {
    int idx = (blockIdx.x - 16) * 256 + threadIdx.x;
    if (idx >= NQP * MW) return;
    int mode = *mode_p;
    int q = idx / MW, w = idx % MW;
    if (q >= N_) { bm[idx] = 0xFFFFFFFFu; return; }
    unsigned bits = 0;
    for (int j = 0; j < 32; ++j){
      int k = w*32 + j;
      int v;
      if (k >= N_) v = 1;
      else {
        size_t i = (size_t)q*N_ + k;
        if (mode == 0)      v = raw[i] != 0;
        else if (mode == 1) v = ((const int*)raw)[i] != 0;
        else if (mode == 2) { unsigned short u = ((const unsigned short*)raw)[i]; v = (u & 0x7FFF) != 0; }
        else                { float f = ((const float*)raw)[i]; v = (f != 0.f); }
      }
      bits |= (unsigned)v << j;
    }
    bm[idx] = bits;
  }
}

// adp_bf[b][n][c] bf16, row stride VP, cols >= N_ zeroed (pad-safe for MFMA K)
__global__ void dg_adp(const float* __restrict__ p2, const float* __restrict__ p3,
                       const float* __restrict__ A1, unsigned short* __restrict__ adp_bf){
  int bid = blockIdx.x; int b = bid / N_; int n = bid % N_;
  __shared__ float p2r[DIMS_], t2[DIMS_], sbuf[N_], red[128];
  int tid = threadIdx.x;
  if (tid < DIMS_) p2r[tid] = p2[n*DIMS_ + tid];
  __syncthreads();
  if (tid < DIMS_){
    float acc = 0.f;
    const float* a1 = A1 + b*DIMS_*DIMS_;
    for (int j = 0; j < DIMS_; ++j) acc += p2r[j] * a1[j*DIMS_ + tid];
    t2[tid] = acc;
  }
  __syncthreads();
  float lm = -INFINITY;
  for (int c = tid; c < N_; c += 128){
    float acc = 0.f;
    for (int k = 0; k < DIMS_; ++k) acc += p3[c*DIMS_ + k] * t2[k];
    acc = fmaxf(acc, 0.f);
    sbuf[c] = acc; lm = fmaxf(lm, acc);
  }
  red[tid] = lm; __syncthreads();
  for (int off = 64; off; off >>= 1){ if (tid < off) red[tid] = fmaxf(red[tid], red[tid+off]); __syncthreads(); }
  float m = red[0]; __syncthreads();
  float ls = 0.f;
  for (int c = tid; c < N_; c += 128){ float e = __expf(sbuf[c] - m); sbuf[c] = e; ls += e; }
  red[tid] = ls; __syncthreads();
  for (int off = 64; off; off >>= 1){ if (tid < off) red[tid] += red[tid+off]; __syncthreads(); }
  float inv = 1.f / red[0];
  unsigned short* outp = adp_bf + ((size_t)b*N_ + n) * VP;
  for (int c = tid; c < VP; c += 128)
    outp[c] = (c < N_) ? cvt1(sbuf[c] * inv) : (unsigned short)0;
}

// ---------------- weight prep ----------------
__global__ void prep_weights(const float* W_gcn, const float* b_gcn, const float* W_r2, const float* b_r2,
                             const float* Wtq, const float* Wtk, const float* Wtv,
                             const float* Wgq, const float* Wgk, const float* Wgv,
                             const float* W_proj,
                             float* bc, unsigned short* Wcb, unsigned short* Wallb,
                             unsigned short* Wpb){
  int tid = threadIdx.x;
  if (blockIdx.x == 0){
    __shared__ float WcS[64*96];
    for (int idx = tid; idx < 64*96; idx += 256){
      int d = idx / 96, c = idx % 96;
      float acc = 0.f;
      for (int o = 0; o < 32; ++o) acc += W_r2[d*32 + o] * W_gcn[o*96 + c];
      WcS[idx] = acc;
    }
    for (int d = tid; d < 64; d += 256){
      float acc = b_r2[d];
      for (int o = 0; o < 32; ++o) acc += W_r2[d*32 + o] * b_gcn[o];
      bc[d] = acc;
    }
    __syncthreads();
    for (int idx = tid; idx < 3*4*64*8; idx += 256){
      int jj = idx & 7, rest = idx >> 3;
      int d = rest % 64, gk = rest / 64;
      int g = gk & 3, kc = gk >> 2;
      Wcb[idx] = cvt1(WcS[d*96 + kc*32 + g*8 + jj]);
    }
  } else if (blockIdx.x == 1){
    for (int idx = tid; idx < 2*4*144*8; idx += 256){
      int jj = idx & 7, rest = idx >> 3;
      int j = rest % 144, gk = rest / 144;
      int g = gk & 3, kc = gk >> 2;
      int dd = kc*32 + g*8 + jj;
      const float* src; int rsrc;
      if      (j < 16) { src = Wtq; rsrc = j; }
      else if (j < 32) { src = Wtk; rsrc = j - 16; }
      else if (j < 48) { src = Wtv; rsrc = j - 32; }
      else if (j < 80) { src = Wgq; rsrc = j - 48; }
      else if (j < 112){ src = Wgk; rsrc = j - 80; }
      else             { src = Wgv; rsrc = j - 112; }
      Wallb[idx] = cvt1(src[rsrc*64 + dd]);
    }
  } else {
    for (int idx = tid; idx < 2*4*64*8; idx += 256){
      int jj = idx & 7, rest = idx >> 3;
      int d = rest % 64, gk = rest / 64;
      int g = gk & 3, kc = gk >> 2;
      int k = kc*32 + g*8 + jj;
      Wpb[idx] = (k < 48) ? cvt1(W_proj[d*48 + k]) : (unsigned short)0;
    }
  }
}

// ---------------- h projection -> TRANSPOSED bf16: ht[b][ct=t*32+c][n], stride VP ----------------
__global__ void hproj(const float* __restrict__ x, const float* __restrict__ W_r1,
                      const float* __restrict__ b_r1, unsigned short* __restrict__ ht){
  int bid = blockIdx.x; int b = bid / N_, n = bid % N_;
  __shared__ float xs[T_*65], Ws[32*65];
  int tid = threadIdx.x;
  for (int idx = tid; idx < 32*64; idx += 384){ int c = idx >> 6, d = idx & 63; Ws[c*65 + d] = W_r1[idx]; }
  for (int idx = tid; idx < T_*64; idx += 384){
    int t = idx >> 6, d = idx & 63;
    xs[t*65 + d] = x[(((size_t)b*T_ + t)*N_ + n)*64 + d];
  }
  __syncthreads();
  int c = tid / T_, t = tid % T_;
  float acc = b_r1[c];
  for (int d = 0; d < 64; ++d) acc += xs[t*65 + d] * Ws[c*65 + d];
  ht[((size_t)b*384 + t*32 + c)*VP + n] = cvt1(acc);
}

// ---------------- GCN hop as MFMA GEMM, no LDS ----------------
__global__ __launch_bounds__(256) void gcn_mfma(const unsigned short* __restrict__ adp_bf,
                                                const unsigned short* __restrict__ in_t,
                                                unsigned short* __restrict__ out_t){
  int bi = blockIdx.x;
  int b = bi / 36, rest = bi % 36;
  int wt = rest / 6, ctb = rest % 6;
  int tid = threadIdx.x, wv = tid >> 6, ln = tid & 63, g = ln >> 4, r = ln & 15;
  int w0 = wt*64 + wv*16;
  int ct0 = ctb*64;
  int wr = min(w0 + r, N_-1);
  const unsigned short* arow  = adp_bf + ((size_t)b*N_ + wr)*VP;
  const unsigned short* bbase = in_t  + ((size_t)b*384 + ct0)*VP;
  f32x4 acc0={0.f,0.f,0.f,0.f}, acc1=acc0, acc2=acc0, acc3=acc0;
  #pragma unroll
  for (int ks = 0; ks < 11; ++ks){
    int ko = ks*32 + g*8;
    bf16x8 a  = *(const bf16x8*)&arow[ko];
    bf16x8 b0 = *(const bf16x8*)&bbase[(size_t)( 0 + r)*VP + ko];
    bf16x8 b1 = *(const bf16x8*)&bbase[(size_t)(16 + r)*VP + ko];
    bf16x8 b2 = *(const bf16x8*)&bbase[(size_t)(32 + r)*VP + ko];
    bf16x8 b3 = *(const bf16x8*)&bbase[(size_t)(48 + r)*VP + ko];
    acc0 = __builtin_amdgcn_mfma_f32_16x16x32_bf16(a, b0, acc0, 0,0,0);
    acc1 = __builtin_amdgcn_mfma_f32_16x16x32_bf16(a, b1, acc1, 0,0,0);
    acc2 = __builtin_amdgcn_mfma_f32_16x16x32_bf16(a, b2, acc2, 0,0,0);
    acc3 = __builtin_amdgcn_mfma_f32_16x16x32_bf16(a, b3, acc3, 0,0,0);
  }
  if (w0 + 15 < VP){
    f32x4 av[4] = {acc0, acc1, acc2, acc3};
    #pragma unroll
    for (int dt = 0; dt < 4; ++dt){
      int ct = ct0 + dt*16 + r;
      uint2 pk2 = { cvt2(av[dt][0], av[dt][1]), cvt2(av[dt][2], av[dt][3]) };
      *(uint2*)&out_t[((size_t)b*384 + ct)*VP + w0 + g*4] = pk2;
    }
  }
}

// ---------------- xg: MFMA GEMM per (b,n), staging from transposed bf16 arrays ----------------
__global__ __launch_bounds__(256) void xg_k(const unsigned short* __restrict__ ht,
                                            const unsigned short* __restrict__ x1t,
                                            const unsigned short* __restrict__ x2t,
                                            const unsigned short* __restrict__ Wcb,
                                            const float* __restrict__ bc,
                                            unsigned short* __restrict__ xg_bf){
  __shared__ unsigned short catA[4][16*104];
  int tid = threadIdx.x, wv = tid >> 6, ln = tid & 63;
  int p = blockIdx.x*4 + wv;
  int b = p / N_, n = p % N_;
  unsigned short* ca = &catA[wv][0];
  #pragma unroll
  for (int ii = 0; ii < 6; ++ii){
    int s2 = ln + 64*ii;            // s2 = ct = t*32+c
    int t = s2 >> 5, c = s2 & 31;
    size_t gi = ((size_t)b*384 + s2)*VP + n;
    unsigned short* row = ca + t*104;
    row[c]      = ht [gi];
    row[32 + c] = x1t[gi];
    row[64 + c] = x2t[gi];
  }
  int g = ln >> 4, r = ln & 15;
  bf16x8 a0 = *(const bf16x8*)&ca[r*104 +  0 + g*8];
  bf16x8 a1 = *(const bf16x8*)&ca[r*104 + 32 + g*8];
  bf16x8 a2 = *(const bf16x8*)&ca[r*104 + 64 + g*8];
  #pragma unroll
  for (int dt = 0; dt < 4; ++dt){
    f32x4 acc = {0.f,0.f,0.f,0.f};
    bf16x8 b0 = *(const bf16x8*)&Wcb[((0*4+g)*64 + dt*16 + r)*8];
    bf16x8 b1 = *(const bf16x8*)&Wcb[((1*4+g)*64 + dt*16 + r)*8];
    bf16x8 b2 = *(const bf16x8*)&Wcb[((2*4+g)*64 + dt*16 + r)*8];
    acc = __builtin_amdgcn_mfma_f32_16x16x32_bf16(a0, b0, acc, 0,0,0);
    acc = __builtin_amdgcn_mfma_f32_16x16x32_bf16(a1, b1, acc, 0,0,0);
    acc = __builtin_amdgcn_mfma_f32_16x16x32_bf16(a2, b2, acc, 0,0,0);
    float bias = bc[dt*16 + r];
    if (g < 3){
      #pragma unroll
      for (int rg = 0; rg < 4; ++rg){
        int t = g*4 + rg;   // < 12
        xg_bf[(((size_t)b*T_ + t)*N_ + n)*64 + dt*16 + r] = cvt1(acc[rg] + bias);
      }
    }
  }
}

// ---------------- qkv: MFMA GEMM, no LDS (unchanged) ----------------
__global__ __launch_bounds__(256) void qkv_k(const unsigned short* __restrict__ xg_bf,
                                             const unsigned short* __restrict__ Wallb,
                                             float* __restrict__ qkv){
  int tid = threadIdx.x, wv = tid >> 6, ln = tid & 63;
  int bt = blockIdx.x / 6;
  int nt = (blockIdx.x % 6)*4 + wv;
  if (nt >= 21) return;
  int g = ln >> 4, r = ln & 15;
  int n0 = nt*16;
  int nc = min(n0 + r, N_-1);
  const unsigned short* arow = xg_bf + ((size_t)bt*N_ + nc)*64;
  bf16x8 a0 = *(const bf16x8*)&arow[g*8];
  bf16x8 a1 = *(const bf16x8*)&arow[32 + g*8];
  #pragma unroll
  for (int jt = 0; jt < 9; ++jt){
    f32x4 acc = {0.f,0.f,0.f,0.f};
    bf16x8 b0 = *(const bf16x8*)&Wallb[((0*4+g)*144 + jt*16 + r)*8];
    bf16x8 b1 = *(const bf16x8*)&Wallb[((1*4+g)*144 + jt*16 + r)*8];
    acc = __builtin_amdgcn_mfma_f32_16x16x32_bf16(a0, b0, acc, 0,0,0);
    acc = __builtin_amdgcn_mfma_f32_16x16x32_bf16(a1, b1, acc, 0,0,0);
    #pragma unroll
    for (int rg = 0; rg < 4; ++rg){
      int n = n0 + g*4 + rg;
      if (n < N_) qkv[((size_t)bt*N_ + n)*144 + jt*16 + r] = acc[rg];
    }
  }
}

// ---------------- temporal attention v2: 4 n per block, per-wave LDS ----------------
__global__ __launch_bounds__(256) void tattn(const float* __restrict__ qkv, float* __restrict__ att){
  __shared__ float qs_a[4][T_*48], ss_a[4][2*T_*T_];
  int tid = threadIdx.x, wv = tid >> 6, ln = tid & 63;
  int p = blockIdx.x*4 + wv;          // p < 5200 always (1300*4)
  int b = p / N_, n = p % N_;
  float* qs = &qs_a[wv][0];
  float* ss = &ss_a[wv][0];
  for (int idx = ln; idx < T_*48; idx += 64){
    int t = idx / 48, j = idx % 48;
    qs[idx] = qkv[(((size_t)b*T_ + t)*N_ + n)*144 + j];
  }
  const float scale = 0.35355339059327373f;
  for (int idx = ln; idx < 2*T_*T_; idx += 64){
    int hh = idx / 144, r = (idx / T_) % T_, c = idx % T_;
    float acc = 0.f;
    for (int d = 0; d < 8; ++d) acc += qs[r*48 + hh*8 + d] * qs[c*48 + 16 + hh*8 + d];
    ss[idx] = acc * scale;
  }
  if (ln < 2*T_){
    int hh = ln / T_, r = ln % T_;
    float* row = ss + hh*144 + r*T_;
    float m = -INFINITY; for (int k = 0; k < T_; ++k) m = fmaxf(m, row[k]);
    float s = 0.f; for (int k = 0; k < T_; ++k){ float e = __expf(row[k] - m); row[k] = e; s += e; }
    float inv = 1.f / s; for (int k = 0; k < T_; ++k) row[k] *= inv;
  }
  for (int idx = ln; idx < T_*16; idx += 64){
    int t = idx / 16, o = idx % 16; int hh = o / 8, d = o % 8;
    float acc = 0.f;
    const float* row = ss + hh*144 + t*T_;
    for (int k = 0; k < T_; ++k) acc += row[k] * qs[k*48 + 32 + hh*8 + d];
    att[(((size_t)b*T_ + t)*N_ + n)*48 + o] = acc;
  }
}

// ---------------- geo attention v5: balanced slots + XCD affinity ----------------
// grid 2304: xcd = bid&7 keeps all 12 blocks of one bt on one XCD (L2-resident qkv slice).
// 12 wave-slots per (bt,h): slot = sub*4+wv, tiles {slot, slot+12} -> <=2 tiles/slot.
__global__ __launch_bounds__(256) void gattn(const float* __restrict__ qkv,
                                             const unsigned* __restrict__ bm,
                                             float* __restrict__ att){
  int bid = blockIdx.x;
  int xcd = bid & 7, idx4 = bid >> 3;          // idx4 in [0,288)
  int bt = xcd*24 + idx4/12;                   // [0,192)
  int hs = idx4 % 12;
  int h = hs / 3, sub = hs % 3;
  __shared__ unsigned short Kb[352*8];
  __shared__ unsigned short Vt[16*360];
  int tid = threadIdx.x;
  const float* qkb = qkv + (size_t)bt*N_*144;
  const float kscale = 0.35355339059327373f * 1.4426950408889634f;
  for (int row = tid; row < 352; row += 256){
    const float* kr = qkb + (size_t)min(row, N_-1)*144 + 80 + h*8;
    float4 k0 = *(const float4*)kr;
    float4 k1 = *(const float4*)(kr + 4);
    uint4 wv4 = { cvt2(k0.x*kscale, k0.y*kscale), cvt2(k0.z*kscale, k0.w*kscale),
                  cvt2(k1.x*kscale, k1.y*kscale), cvt2(k1.z*kscale, k1.w*kscale) };
    *(uint4*)&Kb[row*8] = wv4;
  }
  for (int idx = tid; idx < 352*4; idx += 256){
    int row = idx >> 2, dp = idx & 3;
    int m = row & 31;
    int pos = (row & ~31) | (((m & 15) >> 2) << 3) | (m & 3) | ((m & 16) >> 2);
    const float* vr = qkb + (size_t)min(row, N_-1)*144 + 112 + h*8 + dp*2;
    float2 v = *(const float2*)vr;
    unsigned w = cvt2(v.x, v.y);
    Vt[(dp*2  )*360 + pos] = (unsigned short)w;
    Vt[(dp*2+1)*360 + pos] = (unsigned short)(w >> 16);
  }
  __syncthreads();

  int wv = tid >> 6, ln = tid & 63;
  int g = ln >> 4, r = ln & 15;
  int g4 = g*4;
  bool gzero = (g == 0);
  const bf16x8 z8 = {0,0,0,0,0,0,0,0};
  int slot = sub*4 + wv;                       // [0,12)

  for (int tile = slot; tile < 21; tile += 12){
    int qb = tile*16;
    int qc = min(qb + r, N_-1);
    const uint4* bmp = (const uint4*)(bm + (size_t)(qb + r)*MW);
    uint4 m0 = bmp[0], m1 = bmp[1], m2 = bmp[2];
    unsigned bmw[11] = {m0.x,m0.y,m0.z,m0.w, m1.x,m1.y,m1.z,m1.w, m2.x,m2.y,m2.z};
    bf16x8 aq = z8;
    if (gzero){
      const float* qp = qkb + (size_t)qc*144 + 48 + h*8;
      float4 q0 = *(const float4*)qp;
      float4 q1 = *(const float4*)(qp + 4);
      uint4 u = { cvt2(q0.x,q0.y), cvt2(q0.z,q0.w), cvt2(q1.x,q1.y), cvt2(q1.z,q1.w) };
      aq = u2b(u);
    }
    float ssum = 0.f;
    f32x4 acc = {0.f,0.f,0.f,0.f};
    #pragma unroll
    for (int ks = 0; ks < 11; ++ks){
      bf16x8 akA = z8, akB = z8;
      if (gzero){
        akA = *(const bf16x8*)&Kb[(ks*32 + r)*8];
        akB = *(const bf16x8*)&Kb[(ks*32 + 16 + r)*8];
      }
      f32x4 dA = {0.f,0.f,0.f,0.f}, dB = {0.f,0.f,0.f,0.f};
      dA = __builtin_amdgcn_mfma_f32_16x16x32_bf16(akA, aq, dA, 0,0,0);
      dB = __builtin_amdgcn_mfma_f32_16x16x32_bf16(akB, aq, dB, 0,0,0);
      unsigned wm = bmw[ks];
      unsigned bA = (wm >> g4) & 0xFu;
      unsigned bB = (wm >> (g4 + 16)) & 0xFu;
      float pA[4], pB[4];
      #pragma unroll
      for (int rg = 0; rg < 4; ++rg){
        float eA = exp2f(dA[rg]);
        float eB = exp2f(dB[rg]);
        eA = (bA & (1u << rg)) ? 0.f : eA;
        eB = (bB & (1u << rg)) ? 0.f : eB;
        ssum += eA; ssum += eB;
        pA[rg] = eA; pB[rg] = eB;
      }
      uint4 pw = { cvt2(pA[0],pA[1]), cvt2(pA[2],pA[3]),
                   cvt2(pB[0],pB[1]), cvt2(pB[2],pB[3]) };
      bf16x8 av = *(const bf16x8*)&Vt[r*360 + ks*32 + g*8];
      acc = __builtin_amdgcn_mfma_f32_16x16x32_bf16(av, u2b(pw), acc, 0,0,0);
    }
    ssum += __shfl_xor(ssum, 16);
    ssum += __shfl_xor(ssum, 32);
    float inv = (ssum > 0.f) ? __builtin_amdgcn_rcpf(ssum) : 0.f;
    int qq = qb + r;
    if (g < 2 && qq < N_){
      float4 o = make_float4(acc[0]*inv, acc[1]*inv, acc[2]*inv, acc[3]*inv);
      *(float4*)(att + ((size_t)bt*N_ + qq)*48 + 16 + h*8 + g4) = o;
    }
  }
}

// ---------------- final projection: MFMA GEMM ----------------
__global__ __launch_bounds__(256) void proj_k(const float* __restrict__ att,
                                              const unsigned short* __restrict__ Wpb,
                                              const float* __restrict__ b_proj,
                                              float* __restrict__ out){
  int tid = threadIdx.x, wv = tid >> 6, ln = tid & 63;
  int g = ln >> 4, r = ln & 15;
  long r0 = ((long)blockIdx.x*4 + wv)*16;
  const float* arow = att + (r0 + r)*48;
  float4 qa = *(const float4*)&arow[g*8];
  float4 qb = *(const float4*)&arow[g*8 + 4];
  uint4 u0 = { cvt2(qa.x,qa.y), cvt2(qa.z,qa.w), cvt2(qb.x,qb.y), cvt2(qb.z,qb.w) };
  bf16x8 a0 = u2b(u0);
  bf16x8 a1 = {0,0,0,0,0,0,0,0};
  if (g < 2){
    float4 qc = *(const float4*)&arow[32 + g*8];
    float4 qd = *(const float4*)&arow[36 + g*8];
    uint4 u1 = { cvt2(qc.x,qc.y), cvt2(qc.z,qc.w), cvt2(qd.x,qd.y), cvt2(qd.z,qd.w) };
    a1 = u2b(u1);
  }
  #pragma unroll
  for (int dt = 0; dt < 4; ++dt){
    f32x4 acc = {0.f,0.f,0.f,0.f};
    bf16x8 b0 = *(const bf16x8*)&Wpb[((0*4+g)*64 + dt*16 + r)*8];
    bf16x8 b1 = *(const bf16x8*)&Wpb[((1*4+g)*64 + dt*16 + r)*8];
    acc = __builtin_amdgcn_mfma_f32_16x16x32_bf16(a0, b0, acc, 0,0,0);
    acc = __builtin_amdgcn_mfma_f32_16x16x32_bf16(a1, b1, acc, 0,0,0);
    float bias = b_proj[dt*16 + r];
    #pragma unroll
    for (int rg = 0; rg < 4; ++rg)
      out[(r0 + g*4 + rg)*64 + dt*16 + r] = acc[rg] + bias;
  }
}

extern "C" void kernel_launch(void* const* d_in, const int* in_sizes, int n_in,
                              void* d_out, int out_size, void* d_ws, size_t ws_size,
                              hipStream_t stream){
  const float* x      = (const float*)d_in[0];
  const int*   ind    = (const int*)  d_in[1];
  const unsigned char* gmask_raw = (const unsigned char*)d_in[4];
  const float* p1     = (const float*)d_in[5];
  const float* p2     = (const float*)d_in[6];
  const float* p3     = (const float*)d_in[7];
  const float* pk     = (const float*)d_in[8];
  const float* W_r1   = (const float*)d_in[9];
  const float* b_r1   = (const float*)d_in[10];
  const float* W_gcn  = (const float*)d_in[11];
  const float* b_gcn  = (const float*)d_in[12];
  const float* W_r2   = (const float*)d_in[13];
  const float* b_r2   = (const float*)d_in[14];
  const float* Wtq    = (const float*)d_in[15];
  const float* Wtk    = (const float*)d_in[16];
  const float* Wtv    = (const float*)d_in[17];
  const float* Wgq    = (const float*)d_in[18];
  const float* Wgk    = (const float*)d_in[19];
  const float* Wgv    = (const float*)d_in[20];
  const float* W_proj = (const float*)d_in[21];
  const float* b_proj = (const float*)d_in[22];
  float* out = (float*)d_out;

  float* ws = (float*)d_ws;
  float* A1   = ws; ws += B_*DIMS_*DIMS_;
  float* bc   = ws; ws += 64;
  float* qkv  = ws; ws += (size_t)B_*T_*N_*144;
  float* att  = ws; ws += (size_t)B_*T_*N_*48;
  int*   mmode = (int*)ws; ws += 16;
  unsigned* bm = (unsigned*)ws; ws += NQP*MW;
  unsigned short* us = (unsigned short*)ws;
  unsigned short* adp_bf = us; us += (size_t)B_*N_*VP;
  unsigned short* ht     = us; us += (size_t)B_*384*VP;
  unsigned short* x1t    = us; us += (size_t)B_*384*VP;
  unsigned short* x2t    = us; us += (size_t)B_*384*VP;
  unsigned short* xg_bf  = us; us += (size_t)B_*T_*N_*64;
  unsigned short* Wcb    = us; us += 3*4*64*8;
  unsigned short* Wallb  = us; us += 2*4*144*8;
  unsigned short* Wpb    = us; us += 2*4*64*8;

  mask_detect <<<1,         256, 0, stream>>>(gmask_raw, mmode);
  setup_k     <<<32,        256, 0, stream>>>(p1, pk, ind, A1, gmask_raw, mmode, bm);
  dg_adp      <<<B_*N_,     128, 0, stream>>>(p2, p3, A1, adp_bf);
  prep_weights<<<3,         256, 0, stream>>>(W_gcn, b_gcn, W_r2, b_r2,
                                              Wtq, Wtk, Wtv, Wgq, Wgk, Wgv,
                                              W_proj, bc, Wcb, Wallb, Wpb);
  hproj       <<<B_*N_,     384, 0, stream>>>(x, W_r1, b_r1, ht);
  gcn_mfma    <<<B_*36,     256, 0, stream>>>(adp_bf, ht,  x1t);
  gcn_mfma    <<<B_*36,     256, 0, stream>>>(adp_bf, x1t, x2t);
  xg_k        <<<(B_*N_)/4, 256, 0, stream>>>(ht, x1t, x2t, Wcb, bc, xg_bf);
  qkv_k       <<<192*6,     256, 0, stream>>>(xg_bf, Wallb, qkv);
  tattn       <<<(B_*N_)/4, 256, 0, stream>>>(qkv, att);
  gattn       <<<192*12,    256, 0, stream>>>(qkv, bm, att);
  proj_k      <<<(B_*T_*N_/16)/4, 256, 0, stream>>>(att, Wpb, b_proj, out);
}

// Round 10
// 202.007 us; speedup vs baseline: 2.0727x; 1.0962x over previous
//
#include <hip/hip_runtime.h>
#include <hip/hip_bf16.h>
#include <math.h>

#define B_ 16
#define T_ 12
#define N_ 325
#define DIMS_ 40
#define DAYS_ 288
#define MW 12          // bitmask words per mask row (11 used, 1 pad)
#define NQP 336        // padded q-rows for mask (21*16)
#define VP 352         // padded v/ct-row stride for transposed bf16 arrays (11*32)

typedef __attribute__((ext_vector_type(8))) short bf16x8;
typedef __attribute__((ext_vector_type(4))) float f32x4;

__device__ __forceinline__ unsigned short cvt1(float f){
  unsigned w;
  asm("v_cvt_pk_bf16_f32 %0, %1, %2" : "=v"(w) : "v"(f), "v"(f));
  return (unsigned short)w;
}
__device__ __forceinline__ unsigned cvt2(float a, float b){
  unsigned w;
  asm("v_cvt_pk_bf16_f32 %0, %1, %2" : "=v"(w) : "v"(a), "v"(b));
  return w;
}
__device__ __forceinline__ bf16x8 u2b(uint4 u){ return __builtin_bit_cast(bf16x8, u); }

// ---------------- mask dtype detection ----------------
__global__ void mask_detect(const unsigned char* __restrict__ raw, int* __restrict__ mode){
  __shared__ int f3F_m1, f3F_m3, fNZ_o;
  if (threadIdx.x == 0){ f3F_m1 = 0; f3F_m3 = 0; fNZ_o = 0; }
  __syncthreads();
  for (int i = threadIdx.x; i < 4096; i += 256){
    unsigned char v = raw[i];
    int m4 = i & 3;
    if (v == 0x3F && m4 == 1) atomicOr(&f3F_m1, 1);
    if (v == 0x3F && m4 == 3) atomicOr(&f3F_m3, 1);
    if (v != 0 && m4 != 0)    atomicOr(&fNZ_o, 1);
  }
  __syncthreads();
  if (threadIdx.x == 0){
    int m;
    if (f3F_m1) m = 2;
    else if (f3F_m3) m = 3;
    else if (fNZ_o) m = 0;
    else m = 1;
    *mode = m;
  }
}

// ---------------- fused setup: 0-15 dg_a1, 16-31 mask_bits, 32 p3 transpose ----------------
__global__ void setup_k(const float* __restrict__ p1, const float* __restrict__ pk,
                        const int* __restrict__ ind, float* __restrict__ A1,
                        const unsigned char* __restrict__ raw, const int* __restrict__ mode_p,
                        unsigned* __restrict__ bm,
                        const float* __restrict__ p3, float* __restrict__ p3t){
  if (blockIdx.x < 16){
    int b = blockIdx.x;
    __shared__ float te[DIMS_];
    int day = ind[b] % DAYS_; if (day < 0) day += DAYS_;
    for (int i = threadIdx.x; i < DIMS_; i += blockDim.x) te[i] = p1[day*DIMS_ + i];
    __syncthreads();
    for (int jk = threadIdx.x; jk < DIMS_*DIMS_; jk += blockDim.x){
      float acc = 0.f;
      for (int i = 0; i < DIMS_; ++i) acc += te[i] * pk[i*DIMS_*DIMS_ + jk];
      A1[b*DIMS_*DIMS_ + jk] = acc;
    }
  } else if (blockIdx.x < 32){
    int idx = (blockIdx.x - 16) * 256 + threadIdx.x;
    if (idx >= NQP * MW) return;
    int mode = *mode_p;
    int q = idx / MW, w = idx % MW;
    if (q >= N_) { bm[idx] = 0xFFFFFFFFu; return; }
    unsigned bits = 0;
    for (int j = 0; j < 32; ++j){
      int k = w*32 + j;
      int v;
      if (k >= N_) v = 1;
      else {
        size_t i = (size_t)q*N_ + k;
        if (mode == 0)      v = raw[i] != 0;
        else if (mode == 1) v = ((const int*)raw)[i] != 0;
        else if (mode == 2) { unsigned short u = ((const unsigned short*)raw)[i]; v = (u & 0x7FFF) != 0; }
        else                { float f = ((const float*)raw)[i]; v = (f != 0.f); }
      }
      bits |= (unsigned)v << j;
    }
    bm[idx] = bits;
  } else {
    for (int idx = threadIdx.x; idx < DIMS_*N_; idx += 256){
      int k = idx / N_, c = idx % N_;
      p3t[idx] = p3[c*DIMS_ + k];
    }
  }
}

// adp_bf[b][n][c] bf16, row stride VP, cols >= N_ zeroed (pad-safe for MFMA K)
__global__ void dg_adp(const float* __restrict__ p2, const float* __restrict__ p3t,
                       const float* __restrict__ A1, unsigned short* __restrict__ adp_bf){
  int bid = blockIdx.x; int b = bid / N_; int n = bid % N_;
  __shared__ float p2r[DIMS_], t2[DIMS_], sbuf[N_], red[128];
  int tid = threadIdx.x;
  if (tid < DIMS_) p2r[tid] = p2[n*DIMS_ + tid];
  __syncthreads();
  if (tid < DIMS_){
    float acc = 0.f;
    const float* a1 = A1 + b*DIMS_*DIMS_;
    for (int j = 0; j < DIMS_; ++j) acc += p2r[j] * a1[j*DIMS_ + tid];
    t2[tid] = acc;
  }
  __syncthreads();
  float lm = -INFINITY;
  for (int c = tid; c < N_; c += 128){
    float acc = 0.f;
    for (int k = 0; k < DIMS_; ++k) acc += p3t[k*N_ + c] * t2[k];   // coalesced across lanes
    acc = fmaxf(acc, 0.f);
    sbuf[c] = acc; lm = fmaxf(lm, acc);
  }
  red[tid] = lm; __syncthreads();
  for (int off = 64; off; off >>= 1){ if (tid < off) red[tid] = fmaxf(red[tid], red[tid+off]); __syncthreads(); }
  float m = red[0]; __syncthreads();
  float ls = 0.f;
  for (int c = tid; c < N_; c += 128){ float e = __expf(sbuf[c] - m); sbuf[c] = e; ls += e; }
  red[tid] = ls; __syncthreads();
  for (int off = 64; off; off >>= 1){ if (tid < off) red[tid] += red[tid+off]; __syncthreads(); }
  float inv = 1.f / red[0];
  unsigned short* outp = adp_bf + ((size_t)b*N_ + n) * VP;
  for (int c = tid; c < VP; c += 128)
    outp[c] = (c < N_) ? cvt1(sbuf[c] * inv) : (unsigned short)0;
}

// ---------------- weight prep ----------------
__global__ void prep_weights(const float* W_gcn, const float* b_gcn, const float* W_r2, const float* b_r2,
                             const float* Wtq, const float* Wtk, const float* Wtv,
                             const float* Wgq, const float* Wgk, const float* Wgv,
                             const float* W_proj, const float* W_r1,
                             float* bc, unsigned short* Wcb, unsigned short* Wallb,
                             unsigned short* Wpb, unsigned short* Wr1b){
  int tid = threadIdx.x;
  if (blockIdx.x == 0){
    __shared__ float WcS[64*96];
    for (int idx = tid; idx < 64*96; idx += 256){
      int d = idx / 96, c = idx % 96;
      float acc = 0.f;
      for (int o = 0; o < 32; ++o) acc += W_r2[d*32 + o] * W_gcn[o*96 + c];
      WcS[idx] = acc;
    }
    for (int d = tid; d < 64; d += 256){
      float acc = b_r2[d];
      for (int o = 0; o < 32; ++o) acc += W_r2[d*32 + o] * b_gcn[o];
      bc[d] = acc;
    }
    __syncthreads();
    for (int idx = tid; idx < 3*4*64*8; idx += 256){
      int jj = idx & 7, rest = idx >> 3;
      int d = rest % 64, gk = rest / 64;
      int g = gk & 3, kc = gk >> 2;
      Wcb[idx] = cvt1(WcS[d*96 + kc*32 + g*8 + jj]);
    }
  } else if (blockIdx.x == 1){
    for (int idx = tid; idx < 2*4*144*8; idx += 256){
      int jj = idx & 7, rest = idx >> 3;
      int j = rest % 144, gk = rest / 144;
      int g = gk & 3, kc = gk >> 2;
      int dd = kc*32 + g*8 + jj;
      const float* src; int rsrc;
      if      (j < 16) { src = Wtq; rsrc = j; }
      else if (j < 32) { src = Wtk; rsrc = j - 16; }
      else if (j < 48) { src = Wtv; rsrc = j - 32; }
      else if (j < 80) { src = Wgq; rsrc = j - 48; }
      else if (j < 112){ src = Wgk; rsrc = j - 80; }
      else             { src = Wgv; rsrc = j - 112; }
      Wallb[idx] = cvt1(src[rsrc*64 + dd]);
    }
  } else if (blockIdx.x == 2){
    for (int idx = tid; idx < 2*4*64*8; idx += 256){
      int jj = idx & 7, rest = idx >> 3;
      int d = rest % 64, gk = rest / 64;
      int g = gk & 3, kc = gk >> 2;
      int k = kc*32 + g*8 + jj;
      Wpb[idx] = (k < 48) ? cvt1(W_proj[d*48 + k]) : (unsigned short)0;
    }
  } else {
    // Wr1b[((kc*4+g)*32 + c)*8 + jj] = W_r1[c][kc*32+g*8+jj]
    for (int idx = tid; idx < 2*4*32*8; idx += 256){
      int jj = idx & 7, rest = idx >> 3;
      int c = rest % 32, gk = rest / 32;
      int g = gk & 3, kc = gk >> 2;
      Wr1b[idx] = cvt1(W_r1[c*64 + kc*32 + g*8 + jj]);
    }
  }
}

// ---------------- hproj as MFMA GEMM, no LDS ----------------
// For fixed bt: H[c][n] = b_r1[c] + sum_d W_r1[c][d] x[bt][n][d]; write ht[b][t*32+c][n].
__global__ __launch_bounds__(256) void hproj_mfma(const float* __restrict__ x,
                                                  const unsigned short* __restrict__ Wr1b,
                                                  const float* __restrict__ b_r1,
                                                  unsigned short* __restrict__ ht){
  int tid = threadIdx.x, wv = tid >> 6, ln = tid & 63;
  int bt = blockIdx.x / 6;
  int nt = (blockIdx.x % 6)*4 + wv;
  if (nt >= 21) return;
  int g = ln >> 4, r = ln & 15;
  int n0 = nt*16;
  int nc = min(n0 + r, N_-1);
  int b = bt / T_, t = bt % T_;
  const float* xrow = x + ((size_t)bt*N_ + nc)*64;
  float4 xa = *(const float4*)&xrow[g*8];
  float4 xb = *(const float4*)&xrow[g*8 + 4];
  uint4 u0 = { cvt2(xa.x,xa.y), cvt2(xa.z,xa.w), cvt2(xb.x,xb.y), cvt2(xb.z,xb.w) };
  bf16x8 bv0 = u2b(u0);
  float4 xc = *(const float4*)&xrow[32 + g*8];
  float4 xd = *(const float4*)&xrow[32 + g*8 + 4];
  uint4 u1 = { cvt2(xc.x,xc.y), cvt2(xc.z,xc.w), cvt2(xd.x,xd.y), cvt2(xd.z,xd.w) };
  bf16x8 bv1 = u2b(u1);
  int n = n0 + r;
  #pragma unroll
  for (int ct = 0; ct < 2; ++ct){
    f32x4 acc = {0.f,0.f,0.f,0.f};
    bf16x8 a0 = *(const bf16x8*)&Wr1b[((0*4+g)*32 + ct*16 + r)*8];
    bf16x8 a1 = *(const bf16x8*)&Wr1b[((1*4+g)*32 + ct*16 + r)*8];
    acc = __builtin_amdgcn_mfma_f32_16x16x32_bf16(a0, bv0, acc, 0,0,0);
    acc = __builtin_amdgcn_mfma_f32_16x16x32_bf16(a1, bv1, acc, 0,0,0);
    if (n < N_){
      #pragma unroll
      for (int rg = 0; rg < 4; ++rg){
        int c = ct*16 + g*4 + rg;
        ht[((size_t)b*384 + t*32 + c)*VP + n] = cvt1(acc[rg] + b_r1[c]);
      }
    }
  }
}

// ---------------- GCN hop as MFMA GEMM, no LDS (unchanged) ----------------
__global__ __launch_bounds__(256) void gcn_mfma(const unsigned short* __restrict__ adp_bf,
                                                const unsigned short* __restrict__ in_t,
                                                unsigned short* __restrict__ out_t){
  int bi = blockIdx.x;
  int b = bi / 36, rest = bi % 36;
  int wt = rest / 6, ctb = rest % 6;
  int tid = threadIdx.x, wv = tid >> 6, ln = tid & 63, g = ln >> 4, r = ln & 15;
  int w0 = wt*64 + wv*16;
  int ct0 = ctb*64;
  int wr = min(w0 + r, N_-1);
  const unsigned short* arow  = adp_bf + ((size_t)b*N_ + wr)*VP;
  const unsigned short* bbase = in_t  + ((size_t)b*384 + ct0)*VP;
  f32x4 acc0={0.f,0.f,0.f,0.f}, acc1=acc0, acc2=acc0, acc3=acc0;
  #pragma unroll
  for (int ks = 0; ks < 11; ++ks){
    int ko = ks*32 + g*8;
    bf16x8 a  = *(const bf16x8*)&arow[ko];
    bf16x8 b0 = *(const bf16x8*)&bbase[(size_t)( 0 + r)*VP + ko];
    bf16x8 b1 = *(const bf16x8*)&bbase[(size_t)(16 + r)*VP + ko];
    bf16x8 b2 = *(const bf16x8*)&bbase[(size_t)(32 + r)*VP + ko];
    bf16x8 b3 = *(const bf16x8*)&bbase[(size_t)(48 + r)*VP + ko];
    acc0 = __builtin_amdgcn_mfma_f32_16x16x32_bf16(a, b0, acc0, 0,0,0);
    acc1 = __builtin_amdgcn_mfma_f32_16x16x32_bf16(a, b1, acc1, 0,0,0);
    acc2 = __builtin_amdgcn_mfma_f32_16x16x32_bf16(a, b2, acc2, 0,0,0);
    acc3 = __builtin_amdgcn_mfma_f32_16x16x32_bf16(a, b3, acc3, 0,0,0);
  }
  if (w0 + 15 < VP){
    f32x4 av[4] = {acc0, acc1, acc2, acc3};
    #pragma unroll
    for (int dt = 0; dt < 4; ++dt){
      int ct = ct0 + dt*16 + r;
      uint2 pk2 = { cvt2(av[dt][0], av[dt][1]), cvt2(av[dt][2], av[dt][3]) };
      *(uint2*)&out_t[((size_t)b*384 + ct)*VP + w0 + g*4] = pk2;
    }
  }
}

// ---------------- xg: MFMA GEMM per (b,n) (unchanged) ----------------
__global__ __launch_bounds__(256) void xg_k(const unsigned short* __restrict__ ht,
                                            const unsigned short* __restrict__ x1t,
                                            const unsigned short* __restrict__ x2t,
                                            const unsigned short* __restrict__ Wcb,
                                            const float* __restrict__ bc,
                                            unsigned short* __restrict__ xg_bf){
  __shared__ unsigned short catA[4][16*104];
  int tid = threadIdx.x, wv = tid >> 6, ln = tid & 63;
  int p = blockIdx.x*4 + wv;
  int b = p / N_, n = p % N_;
  unsigned short* ca = &catA[wv][0];
  #pragma unroll
  for (int ii = 0; ii < 6; ++ii){
    int s2 = ln + 64*ii;            // s2 = ct = t*32+c
    int t = s2 >> 5, c = s2 & 31;
    size_t gi = ((size_t)b*384 + s2)*VP + n;
    unsigned short* row = ca + t*104;
    row[c]      = ht [gi];
    row[32 + c] = x1t[gi];
    row[64 + c] = x2t[gi];
  }
  int g = ln >> 4, r = ln & 15;
  bf16x8 a0 = *(const bf16x8*)&ca[r*104 +  0 + g*8];
  bf16x8 a1 = *(const bf16x8*)&ca[r*104 + 32 + g*8];
  bf16x8 a2 = *(const bf16x8*)&ca[r*104 + 64 + g*8];
  #pragma unroll
  for (int dt = 0; dt < 4; ++dt){
    f32x4 acc = {0.f,0.f,0.f,0.f};
    bf16x8 b0 = *(const bf16x8*)&Wcb[((0*4+g)*64 + dt*16 + r)*8];
    bf16x8 b1 = *(const bf16x8*)&Wcb[((1*4+g)*64 + dt*16 + r)*8];
    bf16x8 b2 = *(const bf16x8*)&Wcb[((2*4+g)*64 + dt*16 + r)*8];
    acc = __builtin_amdgcn_mfma_f32_16x16x32_bf16(a0, b0, acc, 0,0,0);
    acc = __builtin_amdgcn_mfma_f32_16x16x32_bf16(a1, b1, acc, 0,0,0);
    acc = __builtin_amdgcn_mfma_f32_16x16x32_bf16(a2, b2, acc, 0,0,0);
    float bias = bc[dt*16 + r];
    if (g < 3){
      #pragma unroll
      for (int rg = 0; rg < 4; ++rg){
        int t = g*4 + rg;   // < 12
        xg_bf[(((size_t)b*T_ + t)*N_ + n)*64 + dt*16 + r] = cvt1(acc[rg] + bias);
      }
    }
  }
}

// ---------------- qkv: MFMA GEMM, no LDS (unchanged) ----------------
__global__ __launch_bounds__(256) void qkv_k(const unsigned short* __restrict__ xg_bf,
                                             const unsigned short* __restrict__ Wallb,
                                             float* __restrict__ qkv){
  int tid = threadIdx.x, wv = tid >> 6, ln = tid & 63;
  int bt = blockIdx.x / 6;
  int nt = (blockIdx.x % 6)*4 + wv;
  if (nt >= 21) return;
  int g = ln >> 4, r = ln & 15;
  int n0 = nt*16;
  int nc = min(n0 + r, N_-1);
  const unsigned short* arow = xg_bf + ((size_t)bt*N_ + nc)*64;
  bf16x8 a0 = *(const bf16x8*)&arow[g*8];
  bf16x8 a1 = *(const bf16x8*)&arow[32 + g*8];
  #pragma unroll
  for (int jt = 0; jt < 9; ++jt){
    f32x4 acc = {0.f,0.f,0.f,0.f};
    bf16x8 b0 = *(const bf16x8*)&Wallb[((0*4+g)*144 + jt*16 + r)*8];
    bf16x8 b1 = *(const bf16x8*)&Wallb[((1*4+g)*144 + jt*16 + r)*8];
    acc = __builtin_amdgcn_mfma_f32_16x16x32_bf16(a0, b0, acc, 0,0,0);
    acc = __builtin_amdgcn_mfma_f32_16x16x32_bf16(a1, b1, acc, 0,0,0);
    #pragma unroll
    for (int rg = 0; rg < 4; ++rg){
      int n = n0 + g*4 + rg;
      if (n < N_) qkv[((size_t)bt*N_ + n)*144 + jt*16 + r] = acc[rg];
    }
  }
}

// ---------------- temporal attention v2 (unchanged) ----------------
__global__ __launch_bounds__(256) void tattn(const float* __restrict__ qkv, float* __restrict__ att){
  __shared__ float qs_a[4][T_*48], ss_a[4][2*T_*T_];
  int tid = threadIdx.x, wv = tid >> 6, ln = tid & 63;
  int p = blockIdx.x*4 + wv;
  int b = p / N_, n = p % N_;
  float* qs = &qs_a[wv][0];
  float* ss = &ss_a[wv][0];
  for (int idx = ln; idx < T_*48; idx += 64){
    int t = idx / 48, j = idx % 48;
    qs[idx] = qkv[(((size_t)b*T_ + t)*N_ + n)*144 + j];
  }
  const float scale = 0.35355339059327373f;
  for (int idx = ln; idx < 2*T_*T_; idx += 64){
    int hh = idx / 144, r = (idx / T_) % T_, c = idx % T_;
    float acc = 0.f;
    for (int d = 0; d < 8; ++d) acc += qs[r*48 + hh*8 + d] * qs[c*48 + 16 + hh*8 + d];
    ss[idx] = acc * scale;
  }
  if (ln < 2*T_){
    int hh = ln / T_, r = ln % T_;
    float* row = ss + hh*144 + r*T_;
    float m = -INFINITY; for (int k = 0; k < T_; ++k) m = fmaxf(m, row[k]);
    float s = 0.f; for (int k = 0; k < T_; ++k){ float e = __expf(row[k] - m); row[k] = e; s += e; }
    float inv = 1.f / s; for (int k = 0; k < T_; ++k) row[k] *= inv;
  }
  for (int idx = ln; idx < T_*16; idx += 64){
    int t = idx / 16, o = idx % 16; int hh = o / 8, d = o % 8;
    float acc = 0.f;
    const float* row = ss + hh*144 + t*T_;
    for (int k = 0; k < T_; ++k) acc += row[k] * qs[k*48 + 32 + hh*8 + d];
    att[(((size_t)b*T_ + t)*N_ + n)*48 + o] = acc;
  }
}

// ---------------- geo attention v5 (unchanged) ----------------
__global__ __launch_bounds__(256) void gattn(const float* __restrict__ qkv,
                                             const unsigned* __restrict__ bm,
                                             float* __restrict__ att){
  int bid = blockIdx.x;
  int xcd = bid & 7, idx4 = bid >> 3;
  int bt = xcd*24 + idx4/12;
  int hs = idx4 % 12;
  int h = hs / 3, sub = hs % 3;
  __shared__ unsigned short Kb[352*8];
  __shared__ unsigned short Vt[16*360];
  int tid = threadIdx.x;
  const float* qkb = qkv + (size_t)bt*N_*144;
  const float kscale = 0.35355339059327373f * 1.4426950408889634f;
  for (int row = tid; row < 352; row += 256){
    const float* kr = qkb + (size_t)min(row, N_-1)*144 + 80 + h*8;
    float4 k0 = *(const float4*)kr;
    float4 k1 = *(const float4*)(kr + 4);
    uint4 wv4 = { cvt2(k0.x*kscale, k0.y*kscale), cvt2(k0.z*kscale, k0.w*kscale),
                  cvt2(k1.x*kscale, k1.y*kscale), cvt2(k1.z*kscale, k1.w*kscale) };
    *(uint4*)&Kb[row*8] = wv4;
  }
  for (int idx = tid; idx < 352*4; idx += 256){
    int row = idx >> 2, dp = idx & 3;
    int m = row & 31;
    int pos = (row & ~31) | (((m & 15) >> 2) << 3) | (m & 3) | ((m & 16) >> 2);
    const float* vr = qkb + (size_t)min(row, N_-1)*144 + 112 + h*8 + dp*2;
    float2 v = *(const float2*)vr;
    unsigned w = cvt2(v.x, v.y);
    Vt[(dp*2  )*360 + pos] = (unsigned short)w;
    Vt[(dp*2+1)*360 + pos] = (unsigned short)(w >> 16);
  }
  __syncthreads();

  int wv = tid >> 6, ln = tid & 63;
  int g = ln >> 4, r = ln & 15;
  int g4 = g*4;
  bool gzero = (g == 0);
  const bf16x8 z8 = {0,0,0,0,0,0,0,0};
  int slot = sub*4 + wv;

  for (int tile = slot; tile < 21; tile += 12){
    int qb = tile*16;
    int qc = min(qb + r, N_-1);
    const uint4* bmp = (const uint4*)(bm + (size_t)(qb + r)*MW);
    uint4 m0 = bmp[0], m1 = bmp[1], m2 = bmp[2];
    unsigned bmw[11] = {m0.x,m0.y,m0.z,m0.w, m1.x,m1.y,m1.z,m1.w, m2.x,m2.y,m2.z};
    bf16x8 aq = z8;
    if (gzero){
      const float* qp = qkb + (size_t)qc*144 + 48 + h*8;
      float4 q0 = *(const float4*)qp;
      float4 q1 = *(const float4*)(qp + 4);
      uint4 u = { cvt2(q0.x,q0.y), cvt2(q0.z,q0.w), cvt2(q1.x,q1.y), cvt2(q1.z,q1.w) };
      aq = u2b(u);
    }
    float ssum = 0.f;
    f32x4 acc = {0.f,0.f,0.f,0.f};
    #pragma unroll
    for (int ks = 0; ks < 11; ++ks){
      bf16x8 akA = z8, akB = z8;
      if (gzero){
        akA = *(const bf16x8*)&Kb[(ks*32 + r)*8];
        akB = *(const bf16x8*)&Kb[(ks*32 + 16 + r)*8];
      }
      f32x4 dA = {0.f,0.f,0.f,0.f}, dB = {0.f,0.f,0.f,0.f};
      dA = __builtin_amdgcn_mfma_f32_16x16x32_bf16(akA, aq, dA, 0,0,0);
      dB = __builtin_amdgcn_mfma_f32_16x16x32_bf16(akB, aq, dB, 0,0,0);
      unsigned wm = bmw[ks];
      unsigned bA = (wm >> g4) & 0xFu;
      unsigned bB = (wm >> (g4 + 16)) & 0xFu;
      float pA[4], pB[4];
      #pragma unroll
      for (int rg = 0; rg < 4; ++rg){
        float eA = exp2f(dA[rg]);
        float eB = exp2f(dB[rg]);
        eA = (bA & (1u << rg)) ? 0.f : eA;
        eB = (bB & (1u << rg)) ? 0.f : eB;
        ssum += eA; ssum += eB;
        pA[rg] = eA; pB[rg] = eB;
      }
      uint4 pw = { cvt2(pA[0],pA[1]), cvt2(pA[2],pA[3]),
                   cvt2(pB[0],pB[1]), cvt2(pB[2],pB[3]) };
      bf16x8 av = *(const bf16x8*)&Vt[r*360 + ks*32 + g*8];
      acc = __builtin_amdgcn_mfma_f32_16x16x32_bf16(av, u2b(pw), acc, 0,0,0);
    }
    ssum += __shfl_xor(ssum, 16);
    ssum += __shfl_xor(ssum, 32);
    float inv = (ssum > 0.f) ? __builtin_amdgcn_rcpf(ssum) : 0.f;
    int qq = qb + r;
    if (g < 2 && qq < N_){
      float4 o = make_float4(acc[0]*inv, acc[1]*inv, acc[2]*inv, acc[3]*inv);
      *(float4*)(att + ((size_t)bt*N_ + qq)*48 + 16 + h*8 + g4) = o;
    }
  }
}

// ---------------- final projection: MFMA GEMM (unchanged) ----------------
__global__ __launch_bounds__(256) void proj_k(const float* __restrict__ att,
                                              const unsigned short* __restrict__ Wpb,
                                              const float* __restrict__ b_proj,
                                              float* __restrict__ out){
  int tid = threadIdx.x, wv = tid >> 6, ln = tid & 63;
  int g = ln >> 4, r = ln & 15;
  long r0 = ((long)blockIdx.x*4 + wv)*16;
  const float* arow = att + (r0 + r)*48;
  float4 qa = *(const float4*)&arow[g*8];
  float4 qb = *(const float4*)&arow[g*8 + 4];
  uint4 u0 = { cvt2(qa.x,qa.y), cvt2(qa.z,qa.w), cvt2(qb.x,qb.y), cvt2(qb.z,qb.w) };
  bf16x8 a0 = u2b(u0);
  bf16x8 a1 = {0,0,0,0,0,0,0,0};
  if (g < 2){
    float4 qc = *(const float4*)&arow[32 + g*8];
    float4 qd = *(const float4*)&arow[36 + g*8];
    uint4 u1 = { cvt2(qc.x,qc.y), cvt2(qc.z,qc.w), cvt2(qd.x,qd.y), cvt2(qd.z,qd.w) };
    a1 = u2b(u1);
  }
  #pragma unroll
  for (int dt = 0; dt < 4; ++dt){
    f32x4 acc = {0.f,0.f,0.f,0.f};
    bf16x8 b0 = *(const bf16x8*)&Wpb[((0*4+g)*64 + dt*16 + r)*8];
    bf16x8 b1 = *(const bf16x8*)&Wpb[((1*4+g)*64 + dt*16 + r)*8];
    acc = __builtin_amdgcn_mfma_f32_16x16x32_bf16(a0, b0, acc, 0,0,0);
    acc = __builtin_amdgcn_mfma_f32_16x16x32_bf16(a1, b1, acc, 0,0,0);
    float bias = b_proj[dt*16 + r];
    #pragma unroll
    for (int rg = 0; rg < 4; ++rg)
      out[(r0 + g*4 + rg)*64 + dt*16 + r] = acc[rg] + bias;
  }
}

extern "C" void kernel_launch(void* const* d_in, const int* in_sizes, int n_in,
                              void* d_out, int out_size, void* d_ws, size_t ws_size,
                              hipStream_t stream){
  const float* x      = (const float*)d_in[0];
  const int*   ind    = (const int*)  d_in[1];
  const unsigned char* gmask_raw = (const unsigned char*)d_in[4];
  const float* p1     = (const float*)d_in[5];
  const float* p2     = (const float*)d_in[6];
  const float* p3     = (const float*)d_in[7];
  const float* pk     = (const float*)d_in[8];
  const float* W_r1   = (const float*)d_in[9];
  const float* b_r1   = (const float*)d_in[10];
  const float* W_gcn  = (const float*)d_in[11];
  const float* b_gcn  = (const float*)d_in[12];
  const float* W_r2   = (const float*)d_in[13];
  const float* b_r2   = (const float*)d_in[14];
  const float* Wtq    = (const float*)d_in[15];
  const float* Wtk    = (const float*)d_in[16];
  const float* Wtv    = (const float*)d_in[17];
  const float* Wgq    = (const float*)d_in[18];
  const float* Wgk    = (const float*)d_in[19];
  const float* Wgv    = (const float*)d_in[20];
  const float* W_proj = (const float*)d_in[21];
  const float* b_proj = (const float*)d_in[22];
  float* out = (float*)d_out;

  float* ws = (float*)d_ws;
  float* A1   = ws; ws += B_*DIMS_*DIMS_;
  float* bc   = ws; ws += 64;
  float* p3t  = ws; ws += DIMS_*N_;
  float* qkv  = ws; ws += (size_t)B_*T_*N_*144;
  float* att  = ws; ws += (size_t)B_*T_*N_*48;
  int*   mmode = (int*)ws; ws += 16;
  unsigned* bm = (unsigned*)ws; ws += NQP*MW;
  unsigned short* us = (unsigned short*)ws;
  unsigned short* adp_bf = us; us += (size_t)B_*N_*VP;
  unsigned short* ht     = us; us += (size_t)B_*384*VP;
  unsigned short* x1t    = us; us += (size_t)B_*384*VP;
  unsigned short* x2t    = us; us += (size_t)B_*384*VP;
  unsigned short* xg_bf  = us; us += (size_t)B_*T_*N_*64;
  unsigned short* Wcb    = us; us += 3*4*64*8;
  unsigned short* Wallb  = us; us += 2*4*144*8;
  unsigned short* Wpb    = us; us += 2*4*64*8;
  unsigned short* Wr1b   = us; us += 2*4*32*8;

  mask_detect <<<1,         256, 0, stream>>>(gmask_raw, mmode);
  setup_k     <<<33,        256, 0, stream>>>(p1, pk, ind, A1, gmask_raw, mmode, bm, p3, p3t);
  dg_adp      <<<B_*N_,     128, 0, stream>>>(p2, p3t, A1, adp_bf);
  prep_weights<<<4,         256, 0, stream>>>(W_gcn, b_gcn, W_r2, b_r2,
                                              Wtq, Wtk, Wtv, Wgq, Wgk, Wgv,
                                              W_proj, W_r1, bc, Wcb, Wallb, Wpb, Wr1b);
  hproj_mfma  <<<192*6,     256, 0, stream>>>(x, Wr1b, b_r1, ht);
  gcn_mfma    <<<B_*36,     256, 0, stream>>>(adp_bf, ht,  x1t);
  gcn_mfma    <<<B_*36,     256, 0, stream>>>(adp_bf, x1t, x2t);
  xg_k        <<<(B_*N_)/4, 256, 0, stream>>>(ht, x1t, x2t, Wcb, bc, xg_bf);
  qkv_k       <<<192*6,     256, 0, stream>>>(xg_bf, Wallb, qkv);
  tattn       <<<(B_*N_)/4, 256, 0, stream>>>(qkv, att);
  gattn       <<<192*12,    256, 0, stream>>>(qkv, bm, att);
  proj_k      <<<(B_*T_*N_/16)/4, 256, 0, stream>>>(att, Wpb, b_proj, out);
}

// Round 11
// 200.831 us; speedup vs baseline: 2.0848x; 1.0059x over previous
//
#include <hip/hip_runtime.h>
#include <hip/hip_bf16.h>
#include <math.h>

#define B_ 16
#define T_ 12
#define N_ 325
#define DIMS_ 40
#define DAYS_ 288
#define MW 12          // bitmask words per mask row (11 used, 1 pad)
#define NQP 336        // padded q-rows for mask (21*16)
#define VP 352         // padded v/ct-row stride for transposed bf16 arrays (11*32)

typedef __attribute__((ext_vector_type(8))) short bf16x8;
typedef __attribute__((ext_vector_type(4))) float f32x4;

__device__ __forceinline__ unsigned short cvt1(float f){
  unsigned w;
  asm("v_cvt_pk_bf16_f32 %0, %1, %2" : "=v"(w) : "v"(f), "v"(f));
  return (unsigned short)w;
}
__device__ __forceinline__ unsigned cvt2(float a, float b){
  unsigned w;
  asm("v_cvt_pk_bf16_f32 %0, %1, %2" : "=v"(w) : "v"(a), "v"(b));
  return w;
}
__device__ __forceinline__ bf16x8 u2b(uint4 u){ return __builtin_bit_cast(bf16x8, u); }

// ---------------- mask dtype detection ----------------
__global__ void mask_detect(const unsigned char* __restrict__ raw, int* __restrict__ mode){
  __shared__ int f3F_m1, f3F_m3, fNZ_o;
  if (threadIdx.x == 0){ f3F_m1 = 0; f3F_m3 = 0; fNZ_o = 0; }
  __syncthreads();
  for (int i = threadIdx.x; i < 4096; i += 256){
    unsigned char v = raw[i];
    int m4 = i & 3;
    if (v == 0x3F && m4 == 1) atomicOr(&f3F_m1, 1);
    if (v == 0x3F && m4 == 3) atomicOr(&f3F_m3, 1);
    if (v != 0 && m4 != 0)    atomicOr(&fNZ_o, 1);
  }
  __syncthreads();
  if (threadIdx.x == 0){
    int m;
    if (f3F_m1) m = 2;
    else if (f3F_m3) m = 3;
    else if (fNZ_o) m = 0;
    else m = 1;
    *mode = m;
  }
}

// ---------------- fused setup: 0-15 dg_a1, 16-31 mask_bits, 32 p3 transpose ----------------
__global__ void setup_k(const float* __restrict__ p1, const float* __restrict__ pk,
                        const int* __restrict__ ind, float* __restrict__ A1,
                        const unsigned char* __restrict__ raw, const int* __restrict__ mode_p,
                        unsigned* __restrict__ bm,
                        const float* __restrict__ p3, float* __restrict__ p3t){
  if (blockIdx.x < 16){
    int b = blockIdx.x;
    __shared__ float te[DIMS_];
    int day = ind[b] % DAYS_; if (day < 0) day += DAYS_;
    for (int i = threadIdx.x; i < DIMS_; i += blockDim.x) te[i] = p1[day*DIMS_ + i];
    __syncthreads();
    for (int jk = threadIdx.x; jk < DIMS_*DIMS_; jk += blockDim.x){
      float acc = 0.f;
      for (int i = 0; i < DIMS_; ++i) acc += te[i] * pk[i*DIMS_*DIMS_ + jk];
      A1[b*DIMS_*DIMS_ + jk] = acc;
    }
  } else if (blockIdx.x < 32){
    int idx = (blockIdx.x - 16) * 256 + threadIdx.x;
    if (idx >= NQP * MW) return;
    int mode = *mode_p;
    int q = idx / MW, w = idx % MW;
    if (q >= N_) { bm[idx] = 0xFFFFFFFFu; return; }
    unsigned bits = 0;
    for (int j = 0; j < 32; ++j){
      int k = w*32 + j;
      int v;
      if (k >= N_) v = 1;
      else {
        size_t i = (size_t)q*N_ + k;
        if (mode == 0)      v = raw[i] != 0;
        else if (mode == 1) v = ((const int*)raw)[i] != 0;
        else if (mode == 2) { unsigned short u = ((const unsigned short*)raw)[i]; v = (u & 0x7FFF) != 0; }
        else                { float f = ((const float*)raw)[i]; v = (f != 0.f); }
      }
      bits |= (unsigned)v << j;
    }
    bm[idx] = bits;
  } else {
    for (int idx = threadIdx.x; idx < DIMS_*N_; idx += 256){
      int k = idx / N_, c = idx % N_;
      p3t[idx] = p3[c*DIMS_ + k];
    }
  }
}

// adp_bf[b][n][c] bf16, row stride VP, cols >= N_ zeroed (pad-safe for MFMA K)
__global__ void dg_adp(const float* __restrict__ p2, const float* __restrict__ p3t,
                       const float* __restrict__ A1, unsigned short* __restrict__ adp_bf){
  int bid = blockIdx.x; int b = bid / N_; int n = bid % N_;
  __shared__ float p2r[DIMS_], t2[DIMS_], sbuf[N_], red[128];
  int tid = threadIdx.x;
  if (tid < DIMS_) p2r[tid] = p2[n*DIMS_ + tid];
  __syncthreads();
  if (tid < DIMS_){
    float acc = 0.f;
    const float* a1 = A1 + b*DIMS_*DIMS_;
    for (int j = 0; j < DIMS_; ++j) acc += p2r[j] * a1[j*DIMS_ + tid];
    t2[tid] = acc;
  }
  __syncthreads();
  float lm = -INFINITY;
  for (int c = tid; c < N_; c += 128){
    float acc = 0.f;
    for (int k = 0; k < DIMS_; ++k) acc += p3t[k*N_ + c] * t2[k];   // coalesced across lanes
    acc = fmaxf(acc, 0.f);
    sbuf[c] = acc; lm = fmaxf(lm, acc);
  }
  red[tid] = lm; __syncthreads();
  for (int off = 64; off; off >>= 1){ if (tid < off) red[tid] = fmaxf(red[tid], red[tid+off]); __syncthreads(); }
  float m = red[0]; __syncthreads();
  float ls = 0.f;
  for (int c = tid; c < N_; c += 128){ float e = __expf(sbuf[c] - m); sbuf[c] = e; ls += e; }
  red[tid] = ls; __syncthreads();
  for (int off = 64; off; off >>= 1){ if (tid < off) red[tid] += red[tid+off]; __syncthreads(); }
  float inv = 1.f / red[0];
  unsigned short* outp = adp_bf + ((size_t)b*N_ + n) * VP;
  for (int c = tid; c < VP; c += 128)
    outp[c] = (c < N_) ? cvt1(sbuf[c] * inv) : (unsigned short)0;
}

// ---------------- weight prep ----------------
__global__ void prep_weights(const float* W_gcn, const float* b_gcn, const float* W_r2, const float* b_r2,
                             const float* Wtq, const float* Wtk, const float* Wtv,
                             const float* Wgq, const float* Wgk, const float* Wgv,
                             const float* W_proj, const float* W_r1,
                             float* bc, unsigned short* Wcb, unsigned short* Wallb,
                             unsigned short* Wpb, unsigned short* Wr1b){
  int tid = threadIdx.x;
  if (blockIdx.x == 0){
    __shared__ float WcS[64*96];
    for (int idx = tid; idx < 64*96; idx += 256){
      int d = idx / 96, c = idx % 96;
      float acc = 0.f;
      for (int o = 0; o < 32; ++o) acc += W_r2[d*32 + o] * W_gcn[o*96 + c];
      WcS[idx] = acc;
    }
    for (int d = tid; d < 64; d += 256){
      float acc = b_r2[d];
      for (int o = 0; o < 32; ++o) acc += W_r2[d*32 + o] * b_gcn[o];
      bc[d] = acc;
    }
    __syncthreads();
    for (int idx = tid; idx < 3*4*64*8; idx += 256){
      int jj = idx & 7, rest = idx >> 3;
      int d = rest % 64, gk = rest / 64;
      int g = gk & 3, kc = gk >> 2;
      Wcb[idx] = cvt1(WcS[d*96 + kc*32 + g*8 + jj]);
    }
  } else if (blockIdx.x == 1){
    for (int idx = tid; idx < 2*4*144*8; idx += 256){
      int jj = idx & 7, rest = idx >> 3;
      int j = rest % 144, gk = rest / 144;
      int g = gk & 3, kc = gk >> 2;
      int dd = kc*32 + g*8 + jj;
      const float* src; int rsrc;
      if      (j < 16) { src = Wtq; rsrc = j; }
      else if (j < 32) { src = Wtk; rsrc = j - 16; }
      else if (j < 48) { src = Wtv; rsrc = j - 32; }
      else if (j < 80) { src = Wgq; rsrc = j - 48; }
      else if (j < 112){ src = Wgk; rsrc = j - 80; }
      else             { src = Wgv; rsrc = j - 112; }
      Wallb[idx] = cvt1(src[rsrc*64 + dd]);
    }
  } else if (blockIdx.x == 2){
    for (int idx = tid; idx < 2*4*64*8; idx += 256){
      int jj = idx & 7, rest = idx >> 3;
      int d = rest % 64, gk = rest / 64;
      int g = gk & 3, kc = gk >> 2;
      int k = kc*32 + g*8 + jj;
      Wpb[idx] = (k < 48) ? cvt1(W_proj[d*48 + k]) : (unsigned short)0;
    }
  } else {
    for (int idx = tid; idx < 2*4*32*8; idx += 256){
      int jj = idx & 7, rest = idx >> 3;
      int c = rest % 32, gk = rest / 32;
      int g = gk & 3, kc = gk >> 2;
      Wr1b[idx] = cvt1(W_r1[c*64 + kc*32 + g*8 + jj]);
    }
  }
}

// ---------------- hproj as MFMA GEMM, no LDS ----------------
__global__ __launch_bounds__(256) void hproj_mfma(const float* __restrict__ x,
                                                  const unsigned short* __restrict__ Wr1b,
                                                  const float* __restrict__ b_r1,
                                                  unsigned short* __restrict__ ht){
  int tid = threadIdx.x, wv = tid >> 6, ln = tid & 63;
  int bt = blockIdx.x / 6;
  int nt = (blockIdx.x % 6)*4 + wv;
  if (nt >= 21) return;
  int g = ln >> 4, r = ln & 15;
  int n0 = nt*16;
  int nc = min(n0 + r, N_-1);
  int b = bt / T_, t = bt % T_;
  const float* xrow = x + ((size_t)bt*N_ + nc)*64;
  float4 xa = *(const float4*)&xrow[g*8];
  float4 xb = *(const float4*)&xrow[g*8 + 4];
  uint4 u0 = { cvt2(xa.x,xa.y), cvt2(xa.z,xa.w), cvt2(xb.x,xb.y), cvt2(xb.z,xb.w) };
  bf16x8 bv0 = u2b(u0);
  float4 xc = *(const float4*)&xrow[32 + g*8];
  float4 xd = *(const float4*)&xrow[32 + g*8 + 4];
  uint4 u1 = { cvt2(xc.x,xc.y), cvt2(xc.z,xc.w), cvt2(xd.x,xd.y), cvt2(xd.z,xd.w) };
  bf16x8 bv1 = u2b(u1);
  int n = n0 + r;
  #pragma unroll
  for (int ct = 0; ct < 2; ++ct){
    f32x4 acc = {0.f,0.f,0.f,0.f};
    bf16x8 a0 = *(const bf16x8*)&Wr1b[((0*4+g)*32 + ct*16 + r)*8];
    bf16x8 a1 = *(const bf16x8*)&Wr1b[((1*4+g)*32 + ct*16 + r)*8];
    acc = __builtin_amdgcn_mfma_f32_16x16x32_bf16(a0, bv0, acc, 0,0,0);
    acc = __builtin_amdgcn_mfma_f32_16x16x32_bf16(a1, bv1, acc, 0,0,0);
    if (n < N_){
      #pragma unroll
      for (int rg = 0; rg < 4; ++rg){
        int c = ct*16 + g*4 + rg;
        ht[((size_t)b*384 + t*32 + c)*VP + n] = cvt1(acc[rg] + b_r1[c]);
      }
    }
  }
}

// ---------------- GCN hop as MFMA GEMM, no LDS (unchanged) ----------------
__global__ __launch_bounds__(256) void gcn_mfma(const unsigned short* __restrict__ adp_bf,
                                                const unsigned short* __restrict__ in_t,
                                                unsigned short* __restrict__ out_t){
  int bi = blockIdx.x;
  int b = bi / 36, rest = bi % 36;
  int wt = rest / 6, ctb = rest % 6;
  int tid = threadIdx.x, wv = tid >> 6, ln = tid & 63, g = ln >> 4, r = ln & 15;
  int w0 = wt*64 + wv*16;
  int ct0 = ctb*64;
  int wr = min(w0 + r, N_-1);
  const unsigned short* arow  = adp_bf + ((size_t)b*N_ + wr)*VP;
  const unsigned short* bbase = in_t  + ((size_t)b*384 + ct0)*VP;
  f32x4 acc0={0.f,0.f,0.f,0.f}, acc1=acc0, acc2=acc0, acc3=acc0;
  #pragma unroll
  for (int ks = 0; ks < 11; ++ks){
    int ko = ks*32 + g*8;
    bf16x8 a  = *(const bf16x8*)&arow[ko];
    bf16x8 b0 = *(const bf16x8*)&bbase[(size_t)( 0 + r)*VP + ko];
    bf16x8 b1 = *(const bf16x8*)&bbase[(size_t)(16 + r)*VP + ko];
    bf16x8 b2 = *(const bf16x8*)&bbase[(size_t)(32 + r)*VP + ko];
    bf16x8 b3 = *(const bf16x8*)&bbase[(size_t)(48 + r)*VP + ko];
    acc0 = __builtin_amdgcn_mfma_f32_16x16x32_bf16(a, b0, acc0, 0,0,0);
    acc1 = __builtin_amdgcn_mfma_f32_16x16x32_bf16(a, b1, acc1, 0,0,0);
    acc2 = __builtin_amdgcn_mfma_f32_16x16x32_bf16(a, b2, acc2, 0,0,0);
    acc3 = __builtin_amdgcn_mfma_f32_16x16x32_bf16(a, b3, acc3, 0,0,0);
  }
  if (w0 + 15 < VP){
    f32x4 av[4] = {acc0, acc1, acc2, acc3};
    #pragma unroll
    for (int dt = 0; dt < 4; ++dt){
      int ct = ct0 + dt*16 + r;
      uint2 pk2 = { cvt2(av[dt][0], av[dt][1]), cvt2(av[dt][2], av[dt][3]) };
      *(uint2*)&out_t[((size_t)b*384 + ct)*VP + w0 + g*4] = pk2;
    }
  }
}

// ---------------- xg: MFMA GEMM per (b,n) (unchanged) ----------------
__global__ __launch_bounds__(256) void xg_k(const unsigned short* __restrict__ ht,
                                            const unsigned short* __restrict__ x1t,
                                            const unsigned short* __restrict__ x2t,
                                            const unsigned short* __restrict__ Wcb,
                                            const float* __restrict__ bc,
                                            unsigned short* __restrict__ xg_bf){
  __shared__ unsigned short catA[4][16*104];
  int tid = threadIdx.x, wv = tid >> 6, ln = tid & 63;
  int p = blockIdx.x*4 + wv;
  int b = p / N_, n = p % N_;
  unsigned short* ca = &catA[wv][0];
  #pragma unroll
  for (int ii = 0; ii < 6; ++ii){
    int s2 = ln + 64*ii;            // s2 = ct = t*32+c
    int t = s2 >> 5, c = s2 & 31;
    size_t gi = ((size_t)b*384 + s2)*VP + n;
    unsigned short* row = ca + t*104;
    row[c]      = ht [gi];
    row[32 + c] = x1t[gi];
    row[64 + c] = x2t[gi];
  }
  int g = ln >> 4, r = ln & 15;
  bf16x8 a0 = *(const bf16x8*)&ca[r*104 +  0 + g*8];
  bf16x8 a1 = *(const bf16x8*)&ca[r*104 + 32 + g*8];
  bf16x8 a2 = *(const bf16x8*)&ca[r*104 + 64 + g*8];
  #pragma unroll
  for (int dt = 0; dt < 4; ++dt){
    f32x4 acc = {0.f,0.f,0.f,0.f};
    bf16x8 b0 = *(const bf16x8*)&Wcb[((0*4+g)*64 + dt*16 + r)*8];
    bf16x8 b1 = *(const bf16x8*)&Wcb[((1*4+g)*64 + dt*16 + r)*8];
    bf16x8 b2 = *(const bf16x8*)&Wcb[((2*4+g)*64 + dt*16 + r)*8];
    acc = __builtin_amdgcn_mfma_f32_16x16x32_bf16(a0, b0, acc, 0,0,0);
    acc = __builtin_amdgcn_mfma_f32_16x16x32_bf16(a1, b1, acc, 0,0,0);
    acc = __builtin_amdgcn_mfma_f32_16x16x32_bf16(a2, b2, acc, 0,0,0);
    float bias = bc[dt*16 + r];
    if (g < 3){
      #pragma unroll
      for (int rg = 0; rg < 4; ++rg){
        int t = g*4 + rg;   // < 12
        xg_bf[(((size_t)b*T_ + t)*N_ + n)*64 + dt*16 + r] = cvt1(acc[rg] + bias);
      }
    }
  }
}

// ---------------- qkv v2: t-channels -> qkv48 (f32); geo channels -> attention-ready bf16 ----------------
// Qg[bt][h][n][8]; Kg[bt][h][k][8] scaled by scale*log2e; Vg[bt][h][d(16 rows, 8 written)][pos] permuted.
__global__ __launch_bounds__(256) void qkv_k(const unsigned short* __restrict__ xg_bf,
                                             const unsigned short* __restrict__ Wallb,
                                             float* __restrict__ qkv48,
                                             unsigned short* __restrict__ Qg,
                                             unsigned short* __restrict__ Kg,
                                             unsigned short* __restrict__ Vg){
  int tid = threadIdx.x, wv = tid >> 6, ln = tid & 63;
  int bt = blockIdx.x / 6;
  int nt = (blockIdx.x % 6)*4 + wv;
  if (nt >= 21) return;
  int g = ln >> 4, r = ln & 15;
  int n0 = nt*16;
  int nc = min(n0 + r, N_-1);
  const unsigned short* arow = xg_bf + ((size_t)bt*N_ + nc)*64;
  bf16x8 a0 = *(const bf16x8*)&arow[g*8];
  bf16x8 a1 = *(const bf16x8*)&arow[32 + g*8];
  const float kscale = 0.35355339059327373f * 1.4426950408889634f;
  int hh = r >> 3, dd = r & 7;
  #pragma unroll
  for (int jt = 0; jt < 9; ++jt){
    f32x4 acc = {0.f,0.f,0.f,0.f};
    bf16x8 b0 = *(const bf16x8*)&Wallb[((0*4+g)*144 + jt*16 + r)*8];
    bf16x8 b1 = *(const bf16x8*)&Wallb[((1*4+g)*144 + jt*16 + r)*8];
    acc = __builtin_amdgcn_mfma_f32_16x16x32_bf16(a0, b0, acc, 0,0,0);
    acc = __builtin_amdgcn_mfma_f32_16x16x32_bf16(a1, b1, acc, 0,0,0);
    #pragma unroll
    for (int rg = 0; rg < 4; ++rg){
      int n = n0 + g*4 + rg;
      if (n >= N_) continue;
      float v = acc[rg];
      if (jt < 3){
        qkv48[((size_t)bt*N_ + n)*48 + jt*16 + r] = v;
      } else if (jt < 5){
        int h = (jt-3)*2 + hh;
        Qg[(((size_t)bt*4 + h)*N_ + n)*8 + dd] = cvt1(v);
      } else if (jt < 7){
        int h = (jt-5)*2 + hh;
        Kg[(((size_t)bt*4 + h)*352 + n)*8 + dd] = cvt1(v * kscale);
      } else {
        int h = (jt-7)*2 + hh;
        int m = n & 31;
        int pos = (n & ~31) | (((m & 15) >> 2) << 3) | (m & 3) | ((m & 16) >> 2);
        Vg[(((size_t)bt*4 + h)*16 + dd)*352 + pos] = cvt1(v);
      }
    }
  }
}

// ---------------- temporal attention v2 (stride 48) ----------------
__global__ __launch_bounds__(256) void tattn(const float* __restrict__ qkv48, float* __restrict__ att){
  __shared__ float qs_a[4][T_*48], ss_a[4][2*T_*T_];
  int tid = threadIdx.x, wv = tid >> 6, ln = tid & 63;
  int p = blockIdx.x*4 + wv;
  int b = p / N_, n = p % N_;
  float* qs = &qs_a[wv][0];
  float* ss = &ss_a[wv][0];
  for (int idx = ln; idx < T_*48; idx += 64){
    int t = idx / 48, j = idx % 48;
    qs[idx] = qkv48[(((size_t)b*T_ + t)*N_ + n)*48 + j];
  }
  const float scale = 0.35355339059327373f;
  for (int idx = ln; idx < 2*T_*T_; idx += 64){
    int hh = idx / 144, r = (idx / T_) % T_, c = idx % T_;
    float acc = 0.f;
    for (int d = 0; d < 8; ++d) acc += qs[r*48 + hh*8 + d] * qs[c*48 + 16 + hh*8 + d];
    ss[idx] = acc * scale;
  }
  if (ln < 2*T_){
    int hh = ln / T_, r = ln % T_;
    float* row = ss + hh*144 + r*T_;
    float m = -INFINITY; for (int k = 0; k < T_; ++k) m = fmaxf(m, row[k]);
    float s = 0.f; for (int k = 0; k < T_; ++k){ float e = __expf(row[k] - m); row[k] = e; s += e; }
    float inv = 1.f / s; for (int k = 0; k < T_; ++k) row[k] *= inv;
  }
  for (int idx = ln; idx < T_*16; idx += 64){
    int t = idx / 16, o = idx % 16; int hh = o / 8, d = o % 8;
    float acc = 0.f;
    const float* row = ss + hh*144 + t*T_;
    for (int k = 0; k < T_; ++k) acc += row[k] * qs[k*48 + 32 + hh*8 + d];
    att[(((size_t)b*T_ + t)*N_ + n)*48 + o] = acc;
  }
}

// ---------------- geo attention v6: LDS-free, one wave per (bt,h,tile) ----------------
// All operands read as direct 16B global loads from attention-ready bf16 arrays.
// grid 4032: 21 blocks per bt, all on one XCD (bid&7). No barriers, no staging.
__global__ __launch_bounds__(256) void gattn(const unsigned short* __restrict__ Qg,
                                             const unsigned short* __restrict__ Kg,
                                             const unsigned short* __restrict__ Vg,
                                             const unsigned* __restrict__ bm,
                                             float* __restrict__ att){
  int bid = blockIdx.x;
  int bt = (bid & 7)*24 + (bid >> 3)/21;       // [0,192), XCD-affine
  int blkin = (bid >> 3) % 21;
  int wv = threadIdx.x >> 6, ln = threadIdx.x & 63;
  int unit = blkin*4 + wv;                     // [0,84)
  int h = unit / 21, tile = unit % 21;
  int g = ln >> 4, r = ln & 15, g4 = g*4;
  bool gzero = (g == 0);
  const bf16x8 z8 = {0,0,0,0,0,0,0,0};
  size_t hb = (size_t)bt*4 + h;
  int qb = tile*16;
  int qc = min(qb + r, N_-1);
  const uint4* bmp = (const uint4*)(bm + (size_t)(qb + r)*MW);
  uint4 m0 = bmp[0], m1 = bmp[1], m2 = bmp[2];
  unsigned bmw[11] = {m0.x,m0.y,m0.z,m0.w, m1.x,m1.y,m1.z,m1.w, m2.x,m2.y,m2.z};
  bf16x8 aq = z8;
  if (gzero) aq = *(const bf16x8*)&Qg[(hb*N_ + qc)*8];
  const unsigned short* Kh = Kg + hb*352*8;
  const unsigned short* Vh = Vg + (hb*16 + r)*352;
  float ssum = 0.f;
  f32x4 acc = {0.f,0.f,0.f,0.f};
  #pragma unroll
  for (int ks = 0; ks < 11; ++ks){
    bf16x8 akA = z8, akB = z8;
    if (gzero){
      akA = *(const bf16x8*)&Kh[(ks*32 + r)*8];
      akB = *(const bf16x8*)&Kh[(ks*32 + 16 + r)*8];
    }
    f32x4 dA = {0.f,0.f,0.f,0.f}, dB = {0.f,0.f,0.f,0.f};
    dA = __builtin_amdgcn_mfma_f32_16x16x32_bf16(akA, aq, dA, 0,0,0);
    dB = __builtin_amdgcn_mfma_f32_16x16x32_bf16(akB, aq, dB, 0,0,0);
    unsigned wm = bmw[ks];
    unsigned bA = (wm >> g4) & 0xFu;
    unsigned bB = (wm >> (g4 + 16)) & 0xFu;
    float pA[4], pB[4];
    #pragma unroll
    for (int rg = 0; rg < 4; ++rg){
      float eA = exp2f(dA[rg]);
      float eB = exp2f(dB[rg]);
      eA = (bA & (1u << rg)) ? 0.f : eA;
      eB = (bB & (1u << rg)) ? 0.f : eB;
      ssum += eA; ssum += eB;
      pA[rg] = eA; pB[rg] = eB;
    }
    uint4 pw = { cvt2(pA[0],pA[1]), cvt2(pA[2],pA[3]),
                 cvt2(pB[0],pB[1]), cvt2(pB[2],pB[3]) };
    bf16x8 av = *(const bf16x8*)&Vh[ks*32 + g*8];
    acc = __builtin_amdgcn_mfma_f32_16x16x32_bf16(av, u2b(pw), acc, 0,0,0);
  }
  ssum += __shfl_xor(ssum, 16);
  ssum += __shfl_xor(ssum, 32);
  float inv = (ssum > 0.f) ? __builtin_amdgcn_rcpf(ssum) : 0.f;
  int qq = qb + r;
  if (g < 2 && qq < N_){
    float4 o = make_float4(acc[0]*inv, acc[1]*inv, acc[2]*inv, acc[3]*inv);
    *(float4*)(att + ((size_t)bt*N_ + qq)*48 + 16 + h*8 + g4) = o;
  }
}

// ---------------- final projection: MFMA GEMM (unchanged) ----------------
__global__ __launch_bounds__(256) void proj_k(const float* __restrict__ att,
                                              const unsigned short* __restrict__ Wpb,
                                              const float* __restrict__ b_proj,
                                              float* __restrict__ out){
  int tid = threadIdx.x, wv = tid >> 6, ln = tid & 63;
  int g = ln >> 4, r = ln & 15;
  long r0 = ((long)blockIdx.x*4 + wv)*16;
  const float* arow = att + (r0 + r)*48;
  float4 qa = *(const float4*)&arow[g*8];
  float4 qb = *(const float4*)&arow[g*8 + 4];
  uint4 u0 = { cvt2(qa.x,qa.y), cvt2(qa.z,qa.w), cvt2(qb.x,qb.y), cvt2(qb.z,qb.w) };
  bf16x8 a0 = u2b(u0);
  bf16x8 a1 = {0,0,0,0,0,0,0,0};
  if (g < 2){
    float4 qc = *(const float4*)&arow[32 + g*8];
    float4 qd = *(const float4*)&arow[36 + g*8];
    uint4 u1 = { cvt2(qc.x,qc.y), cvt2(qc.z,qc.w), cvt2(qd.x,qd.y), cvt2(qd.z,qd.w) };
    a1 = u2b(u1);
  }
  #pragma unroll
  for (int dt = 0; dt < 4; ++dt){
    f32x4 acc = {0.f,0.f,0.f,0.f};
    bf16x8 b0 = *(const bf16x8*)&Wpb[((0*4+g)*64 + dt*16 + r)*8];
    bf16x8 b1 = *(const bf16x8*)&Wpb[((1*4+g)*64 + dt*16 + r)*8];
    acc = __builtin_amdgcn_mfma_f32_16x16x32_bf16(a0, b0, acc, 0,0,0);
    acc = __builtin_amdgcn_mfma_f32_16x16x32_bf16(a1, b1, acc, 0,0,0);
    float bias = b_proj[dt*16 + r];
    #pragma unroll
    for (int rg = 0; rg < 4; ++rg)
      out[(r0 + g*4 + rg)*64 + dt*16 + r] = acc[rg] + bias;
  }
}

extern "C" void kernel_launch(void* const* d_in, const int* in_sizes, int n_in,
                              void* d_out, int out_size, void* d_ws, size_t ws_size,
                              hipStream_t stream){
  const float* x      = (const float*)d_in[0];
  const int*   ind    = (const int*)  d_in[1];
  const unsigned char* gmask_raw = (const unsigned char*)d_in[4];
  const float* p1     = (const float*)d_in[5];
  const float* p2     = (const float*)d_in[6];
  const float* p3     = (const float*)d_in[7];
  const float* pk     = (const float*)d_in[8];
  const float* W_r1   = (const float*)d_in[9];
  const float* b_r1   = (const float*)d_in[10];
  const float* W_gcn  = (const float*)d_in[11];
  const float* b_gcn  = (const float*)d_in[12];
  const float* W_r2   = (const float*)d_in[13];
  const float* b_r2   = (const float*)d_in[14];
  const float* Wtq    = (const float*)d_in[15];
  const float* Wtk    = (const float*)d_in[16];
  const float* Wtv    = (const float*)d_in[17];
  const float* Wgq    = (const float*)d_in[18];
  const float* Wgk    = (const float*)d_in[19];
  const float* Wgv    = (const float*)d_in[20];
  const float* W_proj = (const float*)d_in[21];
  const float* b_proj = (const float*)d_in[22];
  float* out = (float*)d_out;

  float* ws = (float*)d_ws;
  float* A1    = ws; ws += B_*DIMS_*DIMS_;
  float* bc    = ws; ws += 64;
  float* p3t   = ws; ws += DIMS_*N_;
  float* qkv48 = ws; ws += (size_t)B_*T_*N_*48;
  float* att   = ws; ws += (size_t)B_*T_*N_*48;
  int*   mmode = (int*)ws; ws += 16;
  unsigned* bm = (unsigned*)ws; ws += NQP*MW;
  unsigned short* us = (unsigned short*)ws;
  unsigned short* adp_bf = us; us += (size_t)B_*N_*VP;
  unsigned short* ht     = us; us += (size_t)B_*384*VP;
  unsigned short* x1t    = us; us += (size_t)B_*384*VP;
  unsigned short* x2t    = us; us += (size_t)B_*384*VP;
  unsigned short* xg_bf  = us; us += (size_t)B_*T_*N_*64;
  unsigned short* Qg     = us; us += (size_t)192*4*N_*8;
  unsigned short* Kg     = us; us += (size_t)192*4*352*8;
  unsigned short* Vg     = us; us += (size_t)192*4*16*352;
  unsigned short* Wcb    = us; us += 3*4*64*8;
  unsigned short* Wallb  = us; us += 2*4*144*8;
  unsigned short* Wpb    = us; us += 2*4*64*8;
  unsigned short* Wr1b   = us; us += 2*4*32*8;

  mask_detect <<<1,         256, 0, stream>>>(gmask_raw, mmode);
  setup_k     <<<33,        256, 0, stream>>>(p1, pk, ind, A1, gmask_raw, mmode, bm, p3, p3t);
  dg_adp      <<<B_*N_,     128, 0, stream>>>(p2, p3t, A1, adp_bf);
  prep_weights<<<4,         256, 0, stream>>>(W_gcn, b_gcn, W_r2, b_r2,
                                              Wtq, Wtk, Wtv, Wgq, Wgk, Wgv,
                                              W_proj, W_r1, bc, Wcb, Wallb, Wpb, Wr1b);
  hproj_mfma  <<<192*6,     256, 0, stream>>>(x, Wr1b, b_r1, ht);
  gcn_mfma    <<<B_*36,     256, 0, stream>>>(adp_bf, ht,  x1t);
  gcn_mfma    <<<B_*36,     256, 0, stream>>>(adp_bf, x1t, x2t);
  xg_k        <<<(B_*N_)/4, 256, 0, stream>>>(ht, x1t, x2t, Wcb, bc, xg_bf);
  qkv_k       <<<192*6,     256, 0, stream>>>(xg_bf, Wallb, qkv48, Qg, Kg, Vg);
  tattn       <<<(B_*N_)/4, 256, 0, stream>>>(qkv48, att);
  gattn       <<<4032,      256, 0, stream>>>(Qg, Kg, Vg, bm, att);
  proj_k      <<<(B_*T_*N_/16)/4, 256, 0, stream>>>(att, Wpb, b_proj, out);
}

// Round 12
// 182.636 us; speedup vs baseline: 2.2925x; 1.0996x over previous
//
#include <hip/hip_runtime.h>
#include <hip/hip_bf16.h>
#include <math.h>

#define B_ 16
#define T_ 12
#define N_ 325
#define DIMS_ 40
#define DAYS_ 288
#define MW 12          // bitmask words per mask row (11 used, 1 pad)
#define NQP 336        // padded q-rows for mask (21*16)
#define VP 352         // padded v/ct-row stride for transposed bf16 arrays (11*32)

typedef __attribute__((ext_vector_type(8))) short bf16x8;
typedef __attribute__((ext_vector_type(4))) float f32x4;

__device__ __forceinline__ unsigned short cvt1(float f){
  unsigned w;
  asm("v_cvt_pk_bf16_f32 %0, %1, %2" : "=v"(w) : "v"(f), "v"(f));
  return (unsigned short)w;
}
__device__ __forceinline__ unsigned cvt2(float a, float b){
  unsigned w;
  asm("v_cvt_pk_bf16_f32 %0, %1, %2" : "=v"(w) : "v"(a), "v"(b));
  return w;
}
__device__ __forceinline__ bf16x8 u2b(uint4 u){ return __builtin_bit_cast(bf16x8, u); }

// ---------------- mask dtype detection ----------------
__global__ void mask_detect(const unsigned char* __restrict__ raw, int* __restrict__ mode){
  __shared__ int f3F_m1, f3F_m3, fNZ_o;
  if (threadIdx.x == 0){ f3F_m1 = 0; f3F_m3 = 0; fNZ_o = 0; }
  __syncthreads();
  for (int i = threadIdx.x; i < 4096; i += 256){
    unsigned char v = raw[i];
    int m4 = i & 3;
    if (v == 0x3F && m4 == 1) atomicOr(&f3F_m1, 1);
    if (v == 0x3F && m4 == 3) atomicOr(&f3F_m3, 1);
    if (v != 0 && m4 != 0)    atomicOr(&fNZ_o, 1);
  }
  __syncthreads();
  if (threadIdx.x == 0){
    int m;
    if (f3F_m1) m = 2;
    else if (f3F_m3) m = 3;
    else if (fNZ_o) m = 0;
    else m = 1;
    *mode = m;
  }
}

// ---------------- fused setup: 0-15 dg_a1, 16-31 mask_bits, 32 p3 transpose ----------------
__global__ void setup_k(const float* __restrict__ p1, const float* __restrict__ pk,
                        const int* __restrict__ ind, float* __restrict__ A1,
                        const unsigned char* __restrict__ raw, const int* __restrict__ mode_p,
                        unsigned* __restrict__ bm,
                        const float* __restrict__ p3, float* __restrict__ p3t){
  if (blockIdx.x < 16){
    int b = blockIdx.x;
    __shared__ float te[DIMS_];
    int day = ind[b] % DAYS_; if (day < 0) day += DAYS_;
    for (int i = threadIdx.x; i < DIMS_; i += blockDim.x) te[i] = p1[day*DIMS_ + i];
    __syncthreads();
    for (int jk = threadIdx.x; jk < DIMS_*DIMS_; jk += blockDim.x){
      float acc = 0.f;
      for (int i = 0; i < DIMS_; ++i) acc += te[i] * pk[i*DIMS_*DIMS_ + jk];
      A1[b*DIMS_*DIMS_ + jk] = acc;
    }
  } else if (blockIdx.x < 32){
    int idx = (blockIdx.x - 16) * 256 + threadIdx.x;
    if (idx >= NQP * MW) return;
    int mode = *mode_p;
    int q = idx / MW, w = idx % MW;
    if (q >= N_) { bm[idx] = 0xFFFFFFFFu; return; }
    unsigned bits = 0;
    for (int j = 0; j < 32; ++j){
      int k = w*32 + j;
      int v;
      if (k >= N_) v = 1;
      else {
        size_t i = (size_t)q*N_ + k;
        if (mode == 0)      v = raw[i] != 0;
        else if (mode == 1) v = ((const int*)raw)[i] != 0;
        else if (mode == 2) { unsigned short u = ((const unsigned short*)raw)[i]; v = (u & 0x7FFF) != 0; }
        else                { float f = ((const float*)raw)[i]; v = (f != 0.f); }
      }
      bits |= (unsigned)v << j;
    }
    bm[idx] = bits;
  } else {
    for (int idx = threadIdx.x; idx < DIMS_*N_; idx += 256){
      int k = idx / N_, c = idx % N_;
      p3t[idx] = p3[c*DIMS_ + k];
    }
  }
}

// adp_bf[b][n][c] bf16, row stride VP, cols >= N_ zeroed (pad-safe for MFMA K)
__global__ void dg_adp(const float* __restrict__ p2, const float* __restrict__ p3t,
                       const float* __restrict__ A1, unsigned short* __restrict__ adp_bf){
  int bid = blockIdx.x; int b = bid / N_; int n = bid % N_;
  __shared__ float p2r[DIMS_], t2[DIMS_], sbuf[N_], red[128];
  int tid = threadIdx.x;
  if (tid < DIMS_) p2r[tid] = p2[n*DIMS_ + tid];
  __syncthreads();
  if (tid < DIMS_){
    float acc = 0.f;
    const float* a1 = A1 + b*DIMS_*DIMS_;
    for (int j = 0; j < DIMS_; ++j) acc += p2r[j] * a1[j*DIMS_ + tid];
    t2[tid] = acc;
  }
  __syncthreads();
  float lm = -INFINITY;
  for (int c = tid; c < N_; c += 128){
    float acc = 0.f;
    for (int k = 0; k < DIMS_; ++k) acc += p3t[k*N_ + c] * t2[k];
    acc = fmaxf(acc, 0.f);
    sbuf[c] = acc; lm = fmaxf(lm, acc);
  }
  red[tid] = lm; __syncthreads();
  for (int off = 64; off; off >>= 1){ if (tid < off) red[tid] = fmaxf(red[tid], red[tid+off]); __syncthreads(); }
  float m = red[0]; __syncthreads();
  float ls = 0.f;
  for (int c = tid; c < N_; c += 128){ float e = __expf(sbuf[c] - m); sbuf[c] = e; ls += e; }
  red[tid] = ls; __syncthreads();
  for (int off = 64; off; off >>= 1){ if (tid < off) red[tid] += red[tid+off]; __syncthreads(); }
  float inv = 1.f / red[0];
  unsigned short* outp = adp_bf + ((size_t)b*N_ + n) * VP;
  for (int c = tid; c < VP; c += 128)
    outp[c] = (c < N_) ? cvt1(sbuf[c] * inv) : (unsigned short)0;
}

// ---------------- weight prep (unchanged) ----------------
__global__ void prep_weights(const float* W_gcn, const float* b_gcn, const float* W_r2, const float* b_r2,
                             const float* Wtq, const float* Wtk, const float* Wtv,
                             const float* Wgq, const float* Wgk, const float* Wgv,
                             const float* W_proj, const float* W_r1,
                             float* bc, unsigned short* Wcb, unsigned short* Wallb,
                             unsigned short* Wpb, unsigned short* Wr1b){
  int tid = threadIdx.x;
  if (blockIdx.x == 0){
    __shared__ float WcS[64*96];
    for (int idx = tid; idx < 64*96; idx += 256){
      int d = idx / 96, c = idx % 96;
      float acc = 0.f;
      for (int o = 0; o < 32; ++o) acc += W_r2[d*32 + o] * W_gcn[o*96 + c];
      WcS[idx] = acc;
    }
    for (int d = tid; d < 64; d += 256){
      float acc = b_r2[d];
      for (int o = 0; o < 32; ++o) acc += W_r2[d*32 + o] * b_gcn[o];
      bc[d] = acc;
    }
    __syncthreads();
    for (int idx = tid; idx < 3*4*64*8; idx += 256){
      int jj = idx & 7, rest = idx >> 3;
      int d = rest % 64, gk = rest / 64;
      int g = gk & 3, kc = gk >> 2;
      Wcb[idx] = cvt1(WcS[d*96 + kc*32 + g*8 + jj]);
    }
  } else if (blockIdx.x == 1){
    for (int idx = tid; idx < 2*4*144*8; idx += 256){
      int jj = idx & 7, rest = idx >> 3;
      int j = rest % 144, gk = rest / 144;
      int g = gk & 3, kc = gk >> 2;
      int dd = kc*32 + g*8 + jj;
      const float* src; int rsrc;
      if      (j < 16) { src = Wtq; rsrc = j; }
      else if (j < 32) { src = Wtk; rsrc = j - 16; }
      else if (j < 48) { src = Wtv; rsrc = j - 32; }
      else if (j < 80) { src = Wgq; rsrc = j - 48; }
      else if (j < 112){ src = Wgk; rsrc = j - 80; }
      else             { src = Wgv; rsrc = j - 112; }
      Wallb[idx] = cvt1(src[rsrc*64 + dd]);
    }
  } else if (blockIdx.x == 2){
    for (int idx = tid; idx < 2*4*64*8; idx += 256){
      int jj = idx & 7, rest = idx >> 3;
      int d = rest % 64, gk = rest / 64;
      int g = gk & 3, kc = gk >> 2;
      int k = kc*32 + g*8 + jj;
      Wpb[idx] = (k < 48) ? cvt1(W_proj[d*48 + k]) : (unsigned short)0;
    }
  } else {
    for (int idx = tid; idx < 2*4*32*8; idx += 256){
      int jj = idx & 7, rest = idx >> 3;
      int c = rest % 32, gk = rest / 32;
      int g = gk & 3, kc = gk >> 2;
      Wr1b[idx] = cvt1(W_r1[c*64 + kc*32 + g*8 + jj]);
    }
  }
}

// ---------------- hproj as MFMA GEMM; writes ht (transposed) AND hn (row-major) ----------------
__global__ __launch_bounds__(256) void hproj_mfma(const float* __restrict__ x,
                                                  const unsigned short* __restrict__ Wr1b,
                                                  const float* __restrict__ b_r1,
                                                  unsigned short* __restrict__ ht,
                                                  unsigned short* __restrict__ hn){
  int tid = threadIdx.x, wv = tid >> 6, ln = tid & 63;
  int bt = blockIdx.x / 6;
  int nt = (blockIdx.x % 6)*4 + wv;
  if (nt >= 21) return;
  int g = ln >> 4, r = ln & 15;
  int n0 = nt*16;
  int nc = min(n0 + r, N_-1);
  int b = bt / T_, t = bt % T_;
  const float* xrow = x + ((size_t)bt*N_ + nc)*64;
  float4 xa = *(const float4*)&xrow[g*8];
  float4 xb = *(const float4*)&xrow[g*8 + 4];
  uint4 u0 = { cvt2(xa.x,xa.y), cvt2(xa.z,xa.w), cvt2(xb.x,xb.y), cvt2(xb.z,xb.w) };
  bf16x8 bv0 = u2b(u0);
  float4 xc = *(const float4*)&xrow[32 + g*8];
  float4 xd = *(const float4*)&xrow[32 + g*8 + 4];
  uint4 u1 = { cvt2(xc.x,xc.y), cvt2(xc.z,xc.w), cvt2(xd.x,xd.y), cvt2(xd.z,xd.w) };
  bf16x8 bv1 = u2b(u1);
  int n = n0 + r;
  #pragma unroll
  for (int ct = 0; ct < 2; ++ct){
    f32x4 acc = {0.f,0.f,0.f,0.f};
    bf16x8 a0 = *(const bf16x8*)&Wr1b[((0*4+g)*32 + ct*16 + r)*8];
    bf16x8 a1 = *(const bf16x8*)&Wr1b[((1*4+g)*32 + ct*16 + r)*8];
    acc = __builtin_amdgcn_mfma_f32_16x16x32_bf16(a0, bv0, acc, 0,0,0);
    acc = __builtin_amdgcn_mfma_f32_16x16x32_bf16(a1, bv1, acc, 0,0,0);
    if (n < N_){
      float v0 = acc[0] + b_r1[ct*16 + g*4 + 0];
      float v1 = acc[1] + b_r1[ct*16 + g*4 + 1];
      float v2 = acc[2] + b_r1[ct*16 + g*4 + 2];
      float v3 = acc[3] + b_r1[ct*16 + g*4 + 3];
      int c0 = ct*16 + g*4;
      ht[((size_t)b*384 + t*32 + c0+0)*VP + n] = cvt1(v0);
      ht[((size_t)b*384 + t*32 + c0+1)*VP + n] = cvt1(v1);
      ht[((size_t)b*384 + t*32 + c0+2)*VP + n] = cvt1(v2);
      ht[((size_t)b*384 + t*32 + c0+3)*VP + n] = cvt1(v3);
      uint2 hp = { cvt2(v0, v1), cvt2(v2, v3) };
      *(uint2*)&hn[((size_t)b*N_ + n)*384 + t*32 + c0] = hp;
    }
  }
}

// ---------------- GCN hop as MFMA GEMM; out_t (transposed, nullable) + out_n (row-major) ----------------
__global__ __launch_bounds__(256) void gcn_mfma(const unsigned short* __restrict__ adp_bf,
                                                const unsigned short* __restrict__ in_t,
                                                unsigned short* __restrict__ out_t,
                                                unsigned short* __restrict__ out_n){
  int bi = blockIdx.x;
  int b = bi / 36, rest = bi % 36;
  int wt = rest / 6, ctb = rest % 6;
  int tid = threadIdx.x, wv = tid >> 6, ln = tid & 63, g = ln >> 4, r = ln & 15;
  int w0 = wt*64 + wv*16;
  int ct0 = ctb*64;
  int wr = min(w0 + r, N_-1);
  const unsigned short* arow  = adp_bf + ((size_t)b*N_ + wr)*VP;
  const unsigned short* bbase = in_t  + ((size_t)b*384 + ct0)*VP;
  f32x4 acc0={0.f,0.f,0.f,0.f}, acc1=acc0, acc2=acc0, acc3=acc0;
  #pragma unroll
  for (int ks = 0; ks < 11; ++ks){
    int ko = ks*32 + g*8;
    bf16x8 a  = *(const bf16x8*)&arow[ko];
    bf16x8 b0 = *(const bf16x8*)&bbase[(size_t)( 0 + r)*VP + ko];
    bf16x8 b1 = *(const bf16x8*)&bbase[(size_t)(16 + r)*VP + ko];
    bf16x8 b2 = *(const bf16x8*)&bbase[(size_t)(32 + r)*VP + ko];
    bf16x8 b3 = *(const bf16x8*)&bbase[(size_t)(48 + r)*VP + ko];
    acc0 = __builtin_amdgcn_mfma_f32_16x16x32_bf16(a, b0, acc0, 0,0,0);
    acc1 = __builtin_amdgcn_mfma_f32_16x16x32_bf16(a, b1, acc1, 0,0,0);
    acc2 = __builtin_amdgcn_mfma_f32_16x16x32_bf16(a, b2, acc2, 0,0,0);
    acc3 = __builtin_amdgcn_mfma_f32_16x16x32_bf16(a, b3, acc3, 0,0,0);
  }
  f32x4 av[4] = {acc0, acc1, acc2, acc3};
  if (out_t && w0 + 15 < VP){
    #pragma unroll
    for (int dt = 0; dt < 4; ++dt){
      int ct = ct0 + dt*16 + r;
      uint2 pk2 = { cvt2(av[dt][0], av[dt][1]), cvt2(av[dt][2], av[dt][3]) };
      *(uint2*)&out_t[((size_t)b*384 + ct)*VP + w0 + g*4] = pk2;
    }
  }
  #pragma unroll
  for (int dt = 0; dt < 4; ++dt){
    int ct = ct0 + dt*16 + r;
    #pragma unroll
    for (int rg = 0; rg < 4; ++rg){
      int w = w0 + g*4 + rg;
      if (w < N_) out_n[((size_t)b*N_ + w)*384 + ct] = cvt1(av[dt][rg]);
    }
  }
}

// ---------------- xg: LDS-free MFMA GEMM per (b,n), row-major inputs ----------------
__global__ __launch_bounds__(256) void xg_k(const unsigned short* __restrict__ hn,
                                            const unsigned short* __restrict__ x1n,
                                            const unsigned short* __restrict__ x2n,
                                            const unsigned short* __restrict__ Wcb,
                                            const float* __restrict__ bc,
                                            unsigned short* __restrict__ xg_bf){
  int tid = threadIdx.x, wv = tid >> 6, ln = tid & 63;
  int p = blockIdx.x*4 + wv;
  int b = p / N_, n = p % N_;
  int g = ln >> 4, r = ln & 15;
  int rr = min(r, 11);                     // A rows 12-15 duplicate row 11 (D rows unused)
  size_t base = ((size_t)b*N_ + n)*384;
  bf16x8 a0 = *(const bf16x8*)&hn [base + rr*32 + g*8];
  bf16x8 a1 = *(const bf16x8*)&x1n[base + rr*32 + g*8];
  bf16x8 a2 = *(const bf16x8*)&x2n[base + rr*32 + g*8];
  #pragma unroll
  for (int dt = 0; dt < 4; ++dt){
    f32x4 acc = {0.f,0.f,0.f,0.f};
    bf16x8 b0 = *(const bf16x8*)&Wcb[((0*4+g)*64 + dt*16 + r)*8];
    bf16x8 b1 = *(const bf16x8*)&Wcb[((1*4+g)*64 + dt*16 + r)*8];
    bf16x8 b2 = *(const bf16x8*)&Wcb[((2*4+g)*64 + dt*16 + r)*8];
    acc = __builtin_amdgcn_mfma_f32_16x16x32_bf16(a0, b0, acc, 0,0,0);
    acc = __builtin_amdgcn_mfma_f32_16x16x32_bf16(a1, b1, acc, 0,0,0);
    acc = __builtin_amdgcn_mfma_f32_16x16x32_bf16(a2, b2, acc, 0,0,0);
    float bias = bc[dt*16 + r];
    if (g < 3){
      #pragma unroll
      for (int rg = 0; rg < 4; ++rg){
        int t = g*4 + rg;   // < 12
        xg_bf[(((size_t)b*T_ + t)*N_ + n)*64 + dt*16 + r] = cvt1(acc[rg] + bias);
      }
    }
  }
}

// ---------------- qkv v2: t-channels -> qkv48 (f32); geo -> attention-ready bf16 ----------------
// Qg[hb][n][8]; Kg[hb][k][8] scaled; Vg[hb][ks][d*32+pos] (1KB per-chunk tiles).
__global__ __launch_bounds__(256) void qkv_k(const unsigned short* __restrict__ xg_bf,
                                             const unsigned short* __restrict__ Wallb,
                                             float* __restrict__ qkv48,
                                             unsigned short* __restrict__ Qg,
                                             unsigned short* __restrict__ Kg,
                                             unsigned short* __restrict__ Vg){
  int tid = threadIdx.x, wv = tid >> 6, ln = tid & 63;
  int bt = blockIdx.x / 6;
  int nt = (blockIdx.x % 6)*4 + wv;
  if (nt >= 21) return;
  int g = ln >> 4, r = ln & 15;
  int n0 = nt*16;
  int nc = min(n0 + r, N_-1);
  const unsigned short* arow = xg_bf + ((size_t)bt*N_ + nc)*64;
  bf16x8 a0 = *(const bf16x8*)&arow[g*8];
  bf16x8 a1 = *(const bf16x8*)&arow[32 + g*8];
  const float kscale = 0.35355339059327373f * 1.4426950408889634f;
  int hh = r >> 3, dd = r & 7;
  #pragma unroll
  for (int jt = 0; jt < 9; ++jt){
    f32x4 acc = {0.f,0.f,0.f,0.f};
    bf16x8 b0 = *(const bf16x8*)&Wallb[((0*4+g)*144 + jt*16 + r)*8];
    bf16x8 b1 = *(const bf16x8*)&Wallb[((1*4+g)*144 + jt*16 + r)*8];
    acc = __builtin_amdgcn_mfma_f32_16x16x32_bf16(a0, b0, acc, 0,0,0);
    acc = __builtin_amdgcn_mfma_f32_16x16x32_bf16(a1, b1, acc, 0,0,0);
    #pragma unroll
    for (int rg = 0; rg < 4; ++rg){
      int n = n0 + g*4 + rg;
      if (n >= N_) continue;
      float v = acc[rg];
      if (jt < 3){
        qkv48[((size_t)bt*N_ + n)*48 + jt*16 + r] = v;
      } else if (jt < 5){
        int h = (jt-3)*2 + hh;
        Qg[(((size_t)bt*4 + h)*N_ + n)*8 + dd] = cvt1(v);
      } else if (jt < 7){
        int h = (jt-5)*2 + hh;
        Kg[(((size_t)bt*4 + h)*352 + n)*8 + dd] = cvt1(v * kscale);
      } else {
        int h = (jt-7)*2 + hh;
        int m = n & 31, ks = n >> 5;
        int p32 = (((m & 15) >> 2) << 3) | (m & 3) | ((m & 16) >> 2);
        Vg[(((size_t)bt*4 + h)*11 + ks)*512 + dd*32 + p32] = cvt1(v);
      }
    }
  }
}

// ---------------- temporal attention v2 (stride 48, unchanged) ----------------
__global__ __launch_bounds__(256) void tattn(const float* __restrict__ qkv48, float* __restrict__ att){
  __shared__ float qs_a[4][T_*48], ss_a[4][2*T_*T_];
  int tid = threadIdx.x, wv = tid >> 6, ln = tid & 63;
  int p = blockIdx.x*4 + wv;
  int b = p / N_, n = p % N_;
  float* qs = &qs_a[wv][0];
  float* ss = &ss_a[wv][0];
  for (int idx = ln; idx < T_*48; idx += 64){
    int t = idx / 48, j = idx % 48;
    qs[idx] = qkv48[(((size_t)b*T_ + t)*N_ + n)*48 + j];
  }
  const float scale = 0.35355339059327373f;
  for (int idx = ln; idx < 2*T_*T_; idx += 64){
    int hh = idx / 144, r = (idx / T_) % T_, c = idx % T_;
    float acc = 0.f;
    for (int d = 0; d < 8; ++d) acc += qs[r*48 + hh*8 + d] * qs[c*48 + 16 + hh*8 + d];
    ss[idx] = acc * scale;
  }
  if (ln < 2*T_){
    int hh = ln / T_, r = ln % T_;
    float* row = ss + hh*144 + r*T_;
    float m = -INFINITY; for (int k = 0; k < T_; ++k) m = fmaxf(m, row[k]);
    float s = 0.f; for (int k = 0; k < T_; ++k){ float e = __expf(row[k] - m); row[k] = e; s += e; }
    float inv = 1.f / s; for (int k = 0; k < T_; ++k) row[k] *= inv;
  }
  for (int idx = ln; idx < T_*16; idx += 64){
    int t = idx / 16, o = idx % 16; int hh = o / 8, d = o % 8;
    float acc = 0.f;
    const float* row = ss + hh*144 + t*T_;
    for (int k = 0; k < T_; ++k) acc += row[k] * qs[k*48 + 32 + hh*8 + d];
    att[(((size_t)b*T_ + t)*N_ + n)*48 + o] = acc;
  }
}

// ---------------- geo attention v7: LDS-free, wave-coalesced V tiles ----------------
__global__ __launch_bounds__(256) void gattn(const unsigned short* __restrict__ Qg,
                                             const unsigned short* __restrict__ Kg,
                                             const unsigned short* __restrict__ Vg,
                                             const unsigned* __restrict__ bm,
                                             float* __restrict__ att){
  int bid = blockIdx.x;
  int bt = (bid & 7)*24 + (bid >> 3)/21;       // [0,192), XCD-affine
  int blkin = (bid >> 3) % 21;
  int wv = threadIdx.x >> 6, ln = threadIdx.x & 63;
  int unit = blkin*4 + wv;                     // [0,84)
  int h = unit / 21, tile = unit % 21;
  int g = ln >> 4, r = ln & 15, g4 = g*4;
  bool gzero = (g == 0);
  const bf16x8 z8 = {0,0,0,0,0,0,0,0};
  size_t hb = (size_t)bt*4 + h;
  int qb = tile*16;
  int qc = min(qb + r, N_-1);
  const uint4* bmp = (const uint4*)(bm + (size_t)(qb + r)*MW);
  uint4 m0 = bmp[0], m1 = bmp[1], m2 = bmp[2];
  unsigned bmw[11] = {m0.x,m0.y,m0.z,m0.w, m1.x,m1.y,m1.z,m1.w, m2.x,m2.y,m2.z};
  bf16x8 aq = z8;
  if (gzero) aq = *(const bf16x8*)&Qg[(hb*N_ + qc)*8];
  const unsigned short* Kh = Kg + hb*352*8;
  const unsigned short* Vh = Vg + hb*11*512;
  float ssum = 0.f;
  f32x4 acc = {0.f,0.f,0.f,0.f};
  #pragma unroll
  for (int ks = 0; ks < 11; ++ks){
    bf16x8 akA = z8, akB = z8;
    if (gzero){
      akA = *(const bf16x8*)&Kh[(ks*32 + r)*8];
      akB = *(const bf16x8*)&Kh[(ks*32 + 16 + r)*8];
    }
    f32x4 dA = {0.f,0.f,0.f,0.f}, dB = {0.f,0.f,0.f,0.f};
    dA = __builtin_amdgcn_mfma_f32_16x16x32_bf16(akA, aq, dA, 0,0,0);
    dB = __builtin_amdgcn_mfma_f32_16x16x32_bf16(akB, aq, dB, 0,0,0);
    unsigned wm = bmw[ks];
    unsigned bA = (wm >> g4) & 0xFu;
    unsigned bB = (wm >> (g4 + 16)) & 0xFu;
    float pA[4], pB[4];
    #pragma unroll
    for (int rg = 0; rg < 4; ++rg){
      float eA = exp2f(dA[rg]);
      float eB = exp2f(dB[rg]);
      eA = (bA & (1u << rg)) ? 0.f : eA;
      eB = (bB & (1u << rg)) ? 0.f : eB;
      ssum += eA; ssum += eB;
      pA[rg] = eA; pB[rg] = eB;
    }
    uint4 pw = { cvt2(pA[0],pA[1]), cvt2(pA[2],pA[3]),
                 cvt2(pB[0],pB[1]), cvt2(pB[2],pB[3]) };
    bf16x8 av = *(const bf16x8*)&Vh[ks*512 + r*32 + g*8];
    acc = __builtin_amdgcn_mfma_f32_16x16x32_bf16(av, u2b(pw), acc, 0,0,0);
  }
  ssum += __shfl_xor(ssum, 16);
  ssum += __shfl_xor(ssum, 32);
  float inv = (ssum > 0.f) ? __builtin_amdgcn_rcpf(ssum) : 0.f;
  int qq = qb + r;
  if (g < 2 && qq < N_){
    float4 o = make_float4(acc[0]*inv, acc[1]*inv, acc[2]*inv, acc[3]*inv);
    *(float4*)(att + ((size_t)bt*N_ + qq)*48 + 16 + h*8 + g4) = o;
  }
}

// ---------------- final projection: MFMA GEMM (unchanged) ----------------
__global__ __launch_bounds__(256) void proj_k(const float* __restrict__ att,
                                              const unsigned short* __restrict__ Wpb,
                                              const float* __restrict__ b_proj,
                                              float* __restrict__ out){
  int tid = threadIdx.x, wv = tid >> 6, ln = tid & 63;
  int g = ln >> 4, r = ln & 15;
  long r0 = ((long)blockIdx.x*4 + wv)*16;
  const float* arow = att + (r0 + r)*48;
  float4 qa = *(const float4*)&arow[g*8];
  float4 qb = *(const float4*)&arow[g*8 + 4];
  uint4 u0 = { cvt2(qa.x,qa.y), cvt2(qa.z,qa.w), cvt2(qb.x,qb.y), cvt2(qb.z,qb.w) };
  bf16x8 a0 = u2b(u0);
  bf16x8 a1 = {0,0,0,0,0,0,0,0};
  if (g < 2){
    float4 qc = *(const float4*)&arow[32 + g*8];
    float4 qd = *(const float4*)&arow[36 + g*8];
    uint4 u1 = { cvt2(qc.x,qc.y), cvt2(qc.z,qc.w), cvt2(qd.x,qd.y), cvt2(qd.z,qd.w) };
    a1 = u2b(u1);
  }
  #pragma unroll
  for (int dt = 0; dt < 4; ++dt){
    f32x4 acc = {0.f,0.f,0.f,0.f};
    bf16x8 b0 = *(const bf16x8*)&Wpb[((0*4+g)*64 + dt*16 + r)*8];
    bf16x8 b1 = *(const bf16x8*)&Wpb[((1*4+g)*64 + dt*16 + r)*8];
    acc = __builtin_amdgcn_mfma_f32_16x16x32_bf16(a0, b0, acc, 0,0,0);
    acc = __builtin_amdgcn_mfma_f32_16x16x32_bf16(a1, b1, acc, 0,0,0);
    float bias = b_proj[dt*16 + r];
    #pragma unroll
    for (int rg = 0; rg < 4; ++rg)
      out[(r0 + g*4 + rg)*64 + dt*16 + r] = acc[rg] + bias;
  }
}

extern "C" void kernel_launch(void* const* d_in, const int* in_sizes, int n_in,
                              void* d_out, int out_size, void* d_ws, size_t ws_size,
                              hipStream_t stream){
  const float* x      = (const float*)d_in[0];
  const int*   ind    = (const int*)  d_in[1];
  const unsigned char* gmask_raw = (const unsigned char*)d_in[4];
  const float* p1     = (const float*)d_in[5];
  const float* p2     = (const float*)d_in[6];
  const float* p3     = (const float*)d_in[7];
  const float* pk     = (const float*)d_in[8];
  const float* W_r1   = (const float*)d_in[9];
  const float* b_r1   = (const float*)d_in[10];
  const float* W_gcn  = (const float*)d_in[11];
  const float* b_gcn  = (const float*)d_in[12];
  const float* W_r2   = (const float*)d_in[13];
  const float* b_r2   = (const float*)d_in[14];
  const float* Wtq    = (const float*)d_in[15];
  const float* Wtk    = (const float*)d_in[16];
  const float* Wtv    = (const float*)d_in[17];
  const float* Wgq    = (const float*)d_in[18];
  const float* Wgk    = (const float*)d_in[19];
  const float* Wgv    = (const float*)d_in[20];
  const float* W_proj = (const float*)d_in[21];
  const float* b_proj = (const float*)d_in[22];
  float* out = (float*)d_out;

  float* ws = (float*)d_ws;
  float* A1    = ws; ws += B_*DIMS_*DIMS_;
  float* bc    = ws; ws += 64;
  float* p3t   = ws; ws += DIMS_*N_;
  float* qkv48 = ws; ws += (size_t)B_*T_*N_*48;
  float* att   = ws; ws += (size_t)B_*T_*N_*48;
  int*   mmode = (int*)ws; ws += 16;
  unsigned* bm = (unsigned*)ws; ws += NQP*MW;
  unsigned short* us = (unsigned short*)ws;
  unsigned short* adp_bf = us; us += (size_t)B_*N_*VP;
  unsigned short* ht     = us; us += (size_t)B_*384*VP;
  unsigned short* x1t    = us; us += (size_t)B_*384*VP;
  unsigned short* hn     = us; us += (size_t)B_*N_*384;
  unsigned short* x1n    = us; us += (size_t)B_*N_*384;
  unsigned short* x2n    = us; us += (size_t)B_*N_*384;
  unsigned short* xg_bf  = us; us += (size_t)B_*T_*N_*64;
  unsigned short* Qg     = us; us += (size_t)192*4*N_*8;
  unsigned short* Kg     = us; us += (size_t)192*4*352*8;
  unsigned short* Vg     = us; us += (size_t)192*4*11*512;
  unsigned short* Wcb    = us; us += 3*4*64*8;
  unsigned short* Wallb  = us; us += 2*4*144*8;
  unsigned short* Wpb    = us; us += 2*4*64*8;
  unsigned short* Wr1b   = us; us += 2*4*32*8;

  mask_detect <<<1,         256, 0, stream>>>(gmask_raw, mmode);
  setup_k     <<<33,        256, 0, stream>>>(p1, pk, ind, A1, gmask_raw, mmode, bm, p3, p3t);
  dg_adp      <<<B_*N_,     128, 0, stream>>>(p2, p3t, A1, adp_bf);
  prep_weights<<<4,         256, 0, stream>>>(W_gcn, b_gcn, W_r2, b_r2,
                                              Wtq, Wtk, Wtv, Wgq, Wgk, Wgv,
                                              W_proj, W_r1, bc, Wcb, Wallb, Wpb, Wr1b);
  hproj_mfma  <<<192*6,     256, 0, stream>>>(x, Wr1b, b_r1, ht, hn);
  gcn_mfma    <<<B_*36,     256, 0, stream>>>(adp_bf, ht,  x1t, x1n);
  gcn_mfma    <<<B_*36,     256, 0, stream>>>(adp_bf, x1t, (unsigned short*)nullptr, x2n);
  xg_k        <<<(B_*N_)/4, 256, 0, stream>>>(hn, x1n, x2n, Wcb, bc, xg_bf);
  qkv_k       <<<192*6,     256, 0, stream>>>(xg_bf, Wallb, qkv48, Qg, Kg, Vg);
  tattn       <<<(B_*N_)/4, 256, 0, stream>>>(qkv48, att);
  gattn       <<<4032,      256, 0, stream>>>(Qg, Kg, Vg, bm, att);
  proj_k      <<<(B_*T_*N_/16)/4, 256, 0, stream>>>(att, Wpb, b_proj, out);
}

// Round 14
// 154.314 us; speedup vs baseline: 2.7132x; 1.1835x over previous
//
#include <hip/hip_runtime.h>
#include <hip/hip_bf16.h>
#include <math.h>

#define B_ 16
#define T_ 12
#define N_ 325
#define DIMS_ 40
#define DAYS_ 288
#define MW 12          // bitmask words per mask row (11 used, 1 pad)
#define NQP 336        // padded q-rows for mask (21*16)
#define VP 352         // padded v/ct-row stride for transposed bf16 arrays (11*32)

typedef __attribute__((ext_vector_type(8))) short bf16x8;
typedef __attribute__((ext_vector_type(4))) float f32x4;

__device__ __forceinline__ unsigned short cvt1(float f){
  unsigned w;
  asm("v_cvt_pk_bf16_f32 %0, %1, %2" : "=v"(w) : "v"(f), "v"(f));
  return (unsigned short)w;
}
__device__ __forceinline__ unsigned cvt2(float a, float b){
  unsigned w;
  asm("v_cvt_pk_bf16_f32 %0, %1, %2" : "=v"(w) : "v"(a), "v"(b));
  return w;
}
__device__ __forceinline__ bf16x8 u2b(uint4 u){ return __builtin_bit_cast(bf16x8, u); }

// ---------------- fused setup ----------------
// blocks 0-15: dg_a1 | 16-31: mask_bits (inline dtype detect) | 32: p3 transpose
// blocks 33-36: weight prep (Wc/bc/Wcb, Wallb, Wpb, Wr1b)
__global__ void setup_k(const float* __restrict__ p1, const float* __restrict__ pk,
                        const int* __restrict__ ind, float* __restrict__ A1,
                        const unsigned char* __restrict__ raw, unsigned* __restrict__ bm,
                        const float* __restrict__ p3, float* __restrict__ p3t,
                        const float* W_gcn, const float* b_gcn, const float* W_r2, const float* b_r2,
                        const float* Wtq, const float* Wtk, const float* Wtv,
                        const float* Wgq, const float* Wgk, const float* Wgv,
                        const float* W_proj, const float* W_r1,
                        float* bc, unsigned short* Wcb, unsigned short* Wallb,
                        unsigned short* Wpb, unsigned short* Wr1b){
  int tid = threadIdx.x;
  if (blockIdx.x < 16){
    int b = blockIdx.x;
    __shared__ float te[DIMS_];
    int day = ind[b] % DAYS_; if (day < 0) day += DAYS_;
    for (int i = tid; i < DIMS_; i += blockDim.x) te[i] = p1[day*DIMS_ + i];
    __syncthreads();
    for (int jk = tid; jk < DIMS_*DIMS_; jk += blockDim.x){
      float acc = 0.f;
      for (int i = 0; i < DIMS_; ++i) acc += te[i] * pk[i*DIMS_*DIMS_ + jk];
      A1[b*DIMS_*DIMS_ + jk] = acc;
    }
  } else if (blockIdx.x < 32){
    // inline mask dtype detection (modes: 0=uint8, 1=int32, 2=bf16, 3=f32)
    __shared__ int f1, f3, fo;
    if (tid == 0){ f1 = 0; f3 = 0; fo = 0; }
    __syncthreads();
    for (int i = tid; i < 4096; i += 256){
      unsigned char v = raw[i];
      int m4 = i & 3;
      if (v == 0x3F && m4 == 1) atomicOr(&f1, 1);
      if (v == 0x3F && m4 == 3) atomicOr(&f3, 1);
      if (v != 0 && m4 != 0)    atomicOr(&fo, 1);
    }
    __syncthreads();
    int mode = f1 ? 2 : (f3 ? 3 : (fo ? 0 : 1));
    int idx = (blockIdx.x - 16) * 256 + tid;
    if (idx >= NQP * MW) return;
    int q = idx / MW, w = idx % MW;
    if (q >= N_) { bm[idx] = 0xFFFFFFFFu; return; }
    unsigned bits = 0;
    for (int j = 0; j < 32; ++j){
      int k = w*32 + j;
      int v;
      if (k >= N_) v = 1;
      else {
        size_t i = (size_t)q*N_ + k;
        if (mode == 0)      v = raw[i] != 0;
        else if (mode == 1) v = ((const int*)raw)[i] != 0;
        else if (mode == 2) { unsigned short u = ((const unsigned short*)raw)[i]; v = (u & 0x7FFF) != 0; }
        else                { float f = ((const float*)raw)[i]; v = (f != 0.f); }
      }
      bits |= (unsigned)v << j;
    }
    bm[idx] = bits;
  } else if (blockIdx.x == 32){
    for (int idx = tid; idx < DIMS_*N_; idx += 256){
      int k = idx / N_, c = idx % N_;
      p3t[idx] = p3[c*DIMS_ + k];
    }
  } else if (blockIdx.x == 33){
    __shared__ float WcS[64*96];
    for (int idx = tid; idx < 64*96; idx += 256){
      int d = idx / 96, c = idx % 96;
      float acc = 0.f;
      for (int o = 0; o < 32; ++o) acc += W_r2[d*32 + o] * W_gcn[o*96 + c];
      WcS[idx] = acc;
    }
    for (int d = tid; d < 64; d += 256){
      float acc = b_r2[d];
      for (int o = 0; o < 32; ++o) acc += W_r2[d*32 + o] * b_gcn[o];
      bc[d] = acc;
    }
    __syncthreads();
    for (int idx = tid; idx < 3*4*64*8; idx += 256){
      int jj = idx & 7, rest = idx >> 3;
      int d = rest % 64, gk = rest / 64;
      int g = gk & 3, kc = gk >> 2;
      Wcb[idx] = cvt1(WcS[d*96 + kc*32 + g*8 + jj]);
    }
  } else if (blockIdx.x == 34){
    for (int idx = tid; idx < 2*4*144*8; idx += 256){
      int jj = idx & 7, rest = idx >> 3;
      int j = rest % 144, gk = rest / 144;
      int g = gk & 3, kc = gk >> 2;
      int dd = kc*32 + g*8 + jj;
      const float* src; int rsrc;
      if      (j < 16) { src = Wtq; rsrc = j; }
      else if (j < 32) { src = Wtk; rsrc = j - 16; }
      else if (j < 48) { src = Wtv; rsrc = j - 32; }
      else if (j < 80) { src = Wgq; rsrc = j - 48; }
      else if (j < 112){ src = Wgk; rsrc = j - 80; }
      else             { src = Wgv; rsrc = j - 112; }
      Wallb[idx] = cvt1(src[rsrc*64 + dd]);
    }
  } else if (blockIdx.x == 35){
    for (int idx = tid; idx < 2*4*64*8; idx += 256){
      int jj = idx & 7, rest = idx >> 3;
      int d = rest % 64, gk = rest / 64;
      int g = gk & 3, kc = gk >> 2;
      int k = kc*32 + g*8 + jj;
      Wpb[idx] = (k < 48) ? cvt1(W_proj[d*48 + k]) : (unsigned short)0;
    }
  } else {
    for (int idx = tid; idx < 2*4*32*8; idx += 256){
      int jj = idx & 7, rest = idx >> 3;
      int c = rest % 32, gk = rest / 32;
      int g = gk & 3, kc = gk >> 2;
      Wr1b[idx] = cvt1(W_r1[c*64 + kc*32 + g*8 + jj]);
    }
  }
}

// adp_bf[b][n][c] bf16, row stride VP, cols >= N_ zeroed (pad-safe for MFMA K)
__global__ void dg_adp(const float* __restrict__ p2, const float* __restrict__ p3t,
                       const float* __restrict__ A1, unsigned short* __restrict__ adp_bf){
  int bid = blockIdx.x; int b = bid / N_; int n = bid % N_;
  __shared__ float p2r[DIMS_], t2[DIMS_], sbuf[N_], red[128];
  int tid = threadIdx.x;
  if (tid < DIMS_) p2r[tid] = p2[n*DIMS_ + tid];
  __syncthreads();
  if (tid < DIMS_){
    float acc = 0.f;
    const float* a1 = A1 + b*DIMS_*DIMS_;
    for (int j = 0; j < DIMS_; ++j) acc += p2r[j] * a1[j*DIMS_ + tid];
    t2[tid] = acc;
  }
  __syncthreads();
  float lm = -INFINITY;
  for (int c = tid; c < N_; c += 128){
    float acc = 0.f;
    for (int k = 0; k < DIMS_; ++k) acc += p3t[k*N_ + c] * t2[k];
    acc = fmaxf(acc, 0.f);
    sbuf[c] = acc; lm = fmaxf(lm, acc);
  }
  red[tid] = lm; __syncthreads();
  for (int off = 64; off; off >>= 1){ if (tid < off) red[tid] = fmaxf(red[tid], red[tid+off]); __syncthreads(); }
  float m = red[0]; __syncthreads();
  float ls = 0.f;
  for (int c = tid; c < N_; c += 128){ float e = __expf(sbuf[c] - m); sbuf[c] = e; ls += e; }
  red[tid] = ls; __syncthreads();
  for (int off = 64; off; off >>= 1){ if (tid < off) red[tid] += red[tid+off]; __syncthreads(); }
  float inv = 1.f / red[0];
  unsigned short* outp = adp_bf + ((size_t)b*N_ + n) * VP;
  for (int c = tid; c < VP; c += 128)
    outp[c] = (c < N_) ? cvt1(sbuf[c] * inv) : (unsigned short)0;
}

// ---------------- hproj as MFMA GEMM; writes ht (transposed) AND hn (row-major) ----------------
__global__ __launch_bounds__(256) void hproj_mfma(const float* __restrict__ x,
                                                  const unsigned short* __restrict__ Wr1b,
                                                  const float* __restrict__ b_r1,
                                                  unsigned short* __restrict__ ht,
                                                  unsigned short* __restrict__ hn){
  int tid = threadIdx.x, wv = tid >> 6, ln = tid & 63;
  int bt = blockIdx.x / 6;
  int nt = (blockIdx.x % 6)*4 + wv;
  if (nt >= 21) return;
  int g = ln >> 4, r = ln & 15;
  int n0 = nt*16;
  int nc = min(n0 + r, N_-1);
  int b = bt / T_, t = bt % T_;
  const float* xrow = x + ((size_t)bt*N_ + nc)*64;
  float4 xa = *(const float4*)&xrow[g*8];
  float4 xb = *(const float4*)&xrow[g*8 + 4];
  uint4 u0 = { cvt2(xa.x,xa.y), cvt2(xa.z,xa.w), cvt2(xb.x,xb.y), cvt2(xb.z,xb.w) };
  bf16x8 bv0 = u2b(u0);
  float4 xc = *(const float4*)&xrow[32 + g*8];
  float4 xd = *(const float4*)&xrow[32 + g*8 + 4];
  uint4 u1 = { cvt2(xc.x,xc.y), cvt2(xc.z,xc.w), cvt2(xd.x,xd.y), cvt2(xd.z,xd.w) };
  bf16x8 bv1 = u2b(u1);
  int n = n0 + r;
  #pragma unroll
  for (int ct = 0; ct < 2; ++ct){
    f32x4 acc = {0.f,0.f,0.f,0.f};
    bf16x8 a0 = *(const bf16x8*)&Wr1b[((0*4+g)*32 + ct*16 + r)*8];
    bf16x8 a1 = *(const bf16x8*)&Wr1b[((1*4+g)*32 + ct*16 + r)*8];
    acc = __builtin_amdgcn_mfma_f32_16x16x32_bf16(a0, bv0, acc, 0,0,0);
    acc = __builtin_amdgcn_mfma_f32_16x16x32_bf16(a1, bv1, acc, 0,0,0);
    if (n < N_){
      float v0 = acc[0] + b_r1[ct*16 + g*4 + 0];
      float v1 = acc[1] + b_r1[ct*16 + g*4 + 1];
      float v2 = acc[2] + b_r1[ct*16 + g*4 + 2];
      float v3 = acc[3] + b_r1[ct*16 + g*4 + 3];
      int c0 = ct*16 + g*4;
      ht[((size_t)b*384 + t*32 + c0+0)*VP + n] = cvt1(v0);
      ht[((size_t)b*384 + t*32 + c0+1)*VP + n] = cvt1(v1);
      ht[((size_t)b*384 + t*32 + c0+2)*VP + n] = cvt1(v2);
      ht[((size_t)b*384 + t*32 + c0+3)*VP + n] = cvt1(v3);
      uint2 hp = { cvt2(v0, v1), cvt2(v2, v3) };
      *(uint2*)&hn[((size_t)b*N_ + n)*384 + t*32 + c0] = hp;
    }
  }
}

// ---------------- GCN hop as MFMA GEMM; out_t (transposed, nullable) + out_n (row-major) ----------------
__global__ __launch_bounds__(256) void gcn_mfma(const unsigned short* __restrict__ adp_bf,
                                                const unsigned short* __restrict__ in_t,
                                                unsigned short* __restrict__ out_t,
                                                unsigned short* __restrict__ out_n){
  int bi = blockIdx.x;
  int b = bi / 36, rest = bi % 36;
  int wt = rest / 6, ctb = rest % 6;
  int tid = threadIdx.x, wv = tid >> 6, ln = tid & 63, g = ln >> 4, r = ln & 15;
  int w0 = wt*64 + wv*16;
  int ct0 = ctb*64;
  int wr = min(w0 + r, N_-1);
  const unsigned short* arow  = adp_bf + ((size_t)b*N_ + wr)*VP;
  const unsigned short* bbase = in_t  + ((size_t)b*384 + ct0)*VP;
  f32x4 acc0={0.f,0.f,0.f,0.f}, acc1=acc0, acc2=acc0, acc3=acc0;
  #pragma unroll
  for (int ks = 0; ks < 11; ++ks){
    int ko = ks*32 + g*8;
    bf16x8 a  = *(const bf16x8*)&arow[ko];
    bf16x8 b0 = *(const bf16x8*)&bbase[(size_t)( 0 + r)*VP + ko];
    bf16x8 b1 = *(const bf16x8*)&bbase[(size_t)(16 + r)*VP + ko];
    bf16x8 b2 = *(const bf16x8*)&bbase[(size_t)(32 + r)*VP + ko];
    bf16x8 b3 = *(const bf16x8*)&bbase[(size_t)(48 + r)*VP + ko];
    acc0 = __builtin_amdgcn_mfma_f32_16x16x32_bf16(a, b0, acc0, 0,0,0);
    acc1 = __builtin_amdgcn_mfma_f32_16x16x32_bf16(a, b1, acc1, 0,0,0);
    acc2 = __builtin_amdgcn_mfma_f32_16x16x32_bf16(a, b2, acc2, 0,0,0);
    acc3 = __builtin_amdgcn_mfma_f32_16x16x32_bf16(a, b3, acc3, 0,0,0);
  }
  f32x4 av[4] = {acc0, acc1, acc2, acc3};
  if (out_t && w0 + 15 < VP){
    #pragma unroll
    for (int dt = 0; dt < 4; ++dt){
      int ct = ct0 + dt*16 + r;
      uint2 pk2 = { cvt2(av[dt][0], av[dt][1]), cvt2(av[dt][2], av[dt][3]) };
      *(uint2*)&out_t[((size_t)b*384 + ct)*VP + w0 + g*4] = pk2;
    }
  }
  #pragma unroll
  for (int dt = 0; dt < 4; ++dt){
    int ct = ct0 + dt*16 + r;
    #pragma unroll
    for (int rg = 0; rg < 4; ++rg){
      int w = w0 + g*4 + rg;
      if (w < N_) out_n[((size_t)b*N_ + w)*384 + ct] = cvt1(av[dt][rg]);
    }
  }
}

// ---------------- xg: LDS-free MFMA GEMM per (b,n), row-major inputs ----------------
__global__ __launch_bounds__(256) void xg_k(const unsigned short* __restrict__ hn,
                                            const unsigned short* __restrict__ x1n,
                                            const unsigned short* __restrict__ x2n,
                                            const unsigned short* __restrict__ Wcb,
                                            const float* __restrict__ bc,
                                            unsigned short* __restrict__ xg_bf){
  int tid = threadIdx.x, wv = tid >> 6, ln = tid & 63;
  int p = blockIdx.x*4 + wv;
  int b = p / N_, n = p % N_;
  int g = ln >> 4, r = ln & 15;
  int rr = min(r, 11);
  size_t base = ((size_t)b*N_ + n)*384;
  bf16x8 a0 = *(const bf16x8*)&hn [base + rr*32 + g*8];
  bf16x8 a1 = *(const bf16x8*)&x1n[base + rr*32 + g*8];
  bf16x8 a2 = *(const bf16x8*)&x2n[base + rr*32 + g*8];
  #pragma unroll
  for (int dt = 0; dt < 4; ++dt){
    f32x4 acc = {0.f,0.f,0.f,0.f};
    bf16x8 b0 = *(const bf16x8*)&Wcb[((0*4+g)*64 + dt*16 + r)*8];
    bf16x8 b1 = *(const bf16x8*)&Wcb[((1*4+g)*64 + dt*16 + r)*8];
    bf16x8 b2 = *(const bf16x8*)&Wcb[((2*4+g)*64 + dt*16 + r)*8];
    acc = __builtin_amdgcn_mfma_f32_16x16x32_bf16(a0, b0, acc, 0,0,0);
    acc = __builtin_amdgcn_mfma_f32_16x16x32_bf16(a1, b1, acc, 0,0,0);
    acc = __builtin_amdgcn_mfma_f32_16x16x32_bf16(a2, b2, acc, 0,0,0);
    float bias = bc[dt*16 + r];
    if (g < 3){
      #pragma unroll
      for (int rg = 0; rg < 4; ++rg){
        int t = g*4 + rg;
        xg_bf[(((size_t)b*T_ + t)*N_ + n)*64 + dt*16 + r] = cvt1(acc[rg] + bias);
      }
    }
  }
}

// ---------------- qkv v2 (unchanged) ----------------
__global__ __launch_bounds__(256) void qkv_k(const unsigned short* __restrict__ xg_bf,
                                             const unsigned short* __restrict__ Wallb,
                                             float* __restrict__ qkv48,
                                             unsigned short* __restrict__ Qg,
                                             unsigned short* __restrict__ Kg,
                                             unsigned short* __restrict__ Vg){
  int tid = threadIdx.x, wv = tid >> 6, ln = tid & 63;
  int bt = blockIdx.x / 6;
  int nt = (blockIdx.x % 6)*4 + wv;
  if (nt >= 21) return;
  int g = ln >> 4, r = ln & 15;
  int n0 = nt*16;
  int nc = min(n0 + r, N_-1);
  const unsigned short* arow = xg_bf + ((size_t)bt*N_ + nc)*64;
  bf16x8 a0 = *(const bf16x8*)&arow[g*8];
  bf16x8 a1 = *(const bf16x8*)&arow[32 + g*8];
  const float kscale = 0.35355339059327373f * 1.4426950408889634f;
  int hh = r >> 3, dd = r & 7;
  #pragma unroll
  for (int jt = 0; jt < 9; ++jt){
    f32x4 acc = {0.f,0.f,0.f,0.f};
    bf16x8 b0 = *(const bf16x8*)&Wallb[((0*4+g)*144 + jt*16 + r)*8];
    bf16x8 b1 = *(const bf16x8*)&Wallb[((1*4+g)*144 + jt*16 + r)*8];
    acc = __builtin_amdgcn_mfma_f32_16x16x32_bf16(a0, b0, acc, 0,0,0);
    acc = __builtin_amdgcn_mfma_f32_16x16x32_bf16(a1, b1, acc, 0,0,0);
    #pragma unroll
    for (int rg = 0; rg < 4; ++rg){
      int n = n0 + g*4 + rg;
      if (n >= N_) continue;
      float v = acc[rg];
      if (jt < 3){
        qkv48[((size_t)bt*N_ + n)*48 + jt*16 + r] = v;
      } else if (jt < 5){
        int h = (jt-3)*2 + hh;
        Qg[(((size_t)bt*4 + h)*N_ + n)*8 + dd] = cvt1(v);
      } else if (jt < 7){
        int h = (jt-5)*2 + hh;
        Kg[(((size_t)bt*4 + h)*352 + n)*8 + dd] = cvt1(v * kscale);
      } else {
        int h = (jt-7)*2 + hh;
        int m = n & 31, ks = n >> 5;
        int p32 = (((m & 15) >> 2) << 3) | (m & 3) | ((m & 16) >> 2);
        Vg[(((size_t)bt*4 + h)*11 + ks)*512 + dd*32 + p32] = cvt1(v);
      }
    }
  }
}

// ---------------- fused attention: blocks [0,4032) = gattn v7, [4032,5332) = tattn ----------------
__global__ __launch_bounds__(256) void attn_fused(const float* __restrict__ qkv48,
                                                  const unsigned short* __restrict__ Qg,
                                                  const unsigned short* __restrict__ Kg,
                                                  const unsigned short* __restrict__ Vg,
                                                  const unsigned* __restrict__ bm,
                                                  float* __restrict__ att){
  __shared__ __align__(16) char smem[17408];
  int bid = blockIdx.x;
  int tid = threadIdx.x, wv = tid >> 6, ln = tid & 63;
  if (bid < 4032){
    // ---- geo attention v7 (byte-identical logic to round 12) ----
    unsigned short* Kb = (unsigned short*)smem;             // [352*8]
    unsigned short* Vt = (unsigned short*)(smem + 5632);    // [16*360]
    int bt = (bid & 7)*24 + (bid >> 3)/21;
    int blkin = (bid >> 3) % 21;
    int unit = blkin*4 + wv;
    int h = unit / 21, tile = unit % 21;
    int g = ln >> 4, r = ln & 15, g4 = g*4;
    bool gzero = (g == 0);
    const bf16x8 z8 = {0,0,0,0,0,0,0,0};
    size_t hb = (size_t)bt*4 + h;
    int qb = tile*16;
    int qc = min(qb + r, N_-1);
    const uint4* bmp = (const uint4*)(bm + (size_t)(qb + r)*MW);
    uint4 m0 = bmp[0], m1 = bmp[1], m2 = bmp[2];
    unsigned bmw[11] = {m0.x,m0.y,m0.z,m0.w, m1.x,m1.y,m1.z,m1.w, m2.x,m2.y,m2.z};
    bf16x8 aq = z8;
    if (gzero) aq = *(const bf16x8*)&Qg[(hb*N_ + qc)*8];
    const unsigned short* Kh = Kg + hb*352*8;
    const unsigned short* Vh = Vg + hb*11*512;
    float ssum = 0.f;
    f32x4 acc = {0.f,0.f,0.f,0.f};
    #pragma unroll
    for (int ks = 0; ks < 11; ++ks){
      bf16x8 akA = z8, akB = z8;
      if (gzero){
        akA = *(const bf16x8*)&Kh[(ks*32 + r)*8];
        akB = *(const bf16x8*)&Kh[(ks*32 + 16 + r)*8];
      }
      f32x4 dA = {0.f,0.f,0.f,0.f}, dB = {0.f,0.f,0.f,0.f};
      dA = __builtin_amdgcn_mfma_f32_16x16x32_bf16(akA, aq, dA, 0,0,0);
      dB = __builtin_amdgcn_mfma_f32_16x16x32_bf16(akB, aq, dB, 0,0,0);
      unsigned wm = bmw[ks];
      unsigned bA = (wm >> g4) & 0xFu;
      unsigned bB = (wm >> (g4 + 16)) & 0xFu;
      float pA[4], pB[4];
      #pragma unroll
      for (int rg = 0; rg < 4; ++rg){
        float eA = exp2f(dA[rg]);
        float eB = exp2f(dB[rg]);
        eA = (bA & (1u << rg)) ? 0.f : eA;
        eB = (bB & (1u << rg)) ? 0.f : eB;
        ssum += eA; ssum += eB;
        pA[rg] = eA; pB[rg] = eB;
      }
      uint4 pw = { cvt2(pA[0],pA[1]), cvt2(pA[2],pA[3]),
                   cvt2(pB[0],pB[1]), cvt2(pB[2],pB[3]) };
      bf16x8 avv = *(const bf16x8*)&Vh[ks*512 + r*32 + g*8];
      acc = __builtin_amdgcn_mfma_f32_16x16x32_bf16(avv, u2b(pw), acc, 0,0,0);
    }
    ssum += __shfl_xor(ssum, 16);
    ssum += __shfl_xor(ssum, 32);
    float inv = (ssum > 0.f) ? __builtin_amdgcn_rcpf(ssum) : 0.f;
    int qq = qb + r;
    if (g < 2 && qq < N_){
      float4 o = make_float4(acc[0]*inv, acc[1]*inv, acc[2]*inv, acc[3]*inv);
      *(float4*)(att + ((size_t)bt*N_ + qq)*48 + 16 + h*8 + g4) = o;
    }
    (void)Kb; (void)Vt;  // LDS unused in v7 global-operand path
  } else {
    // ---- temporal attention (byte-identical logic to round 12) ----
    int p = (bid - 4032)*4 + wv;
    int b = p / N_, n = p % N_;
    float* qs = (float*)smem + (size_t)wv*576;            // 4 x 576 floats = 9216B
    float* ss = (float*)(smem + 9216) + (size_t)wv*288;   // 4 x 288 floats = 4608B
    for (int idx = ln; idx < T_*48; idx += 64){
      int t = idx / 48, j = idx % 48;
      qs[idx] = qkv48[(((size_t)b*T_ + t)*N_ + n)*48 + j];
    }
    const float scale = 0.35355339059327373f;
    for (int idx = ln; idx < 2*T_*T_; idx += 64){
      int hh = idx / 144, r2 = (idx / T_) % T_, c = idx % T_;
      float acc = 0.f;
      for (int d = 0; d < 8; ++d) acc += qs[r2*48 + hh*8 + d] * qs[c*48 + 16 + hh*8 + d];
      ss[idx] = acc * scale;
    }
    if (ln < 2*T_){
      int hh = ln / T_, r2 = ln % T_;
      float* row = ss + hh*144 + r2*T_;
      float m = -INFINITY; for (int k = 0; k < T_; ++k) m = fmaxf(m, row[k]);
      float s = 0.f; for (int k = 0; k < T_; ++k){ float e = __expf(row[k] - m); row[k] = e; s += e; }
      float inv = 1.f / s; for (int k = 0; k < T_; ++k) row[k] *= inv;
    }
    for (int idx = ln; idx < T_*16; idx += 64){
      int t = idx / 16, o = idx % 16; int hh = o / 8, d = o % 8;
      float acc = 0.f;
      const float* row = ss + hh*144 + t*T_;
      for (int k = 0; k < T_; ++k) acc += row[k] * qs[k*48 + 32 + hh*8 + d];
      att[(((size_t)b*T_ + t)*N_ + n)*48 + o] = acc;
    }
  }
}

// ---------------- final projection: MFMA GEMM (unchanged) ----------------
__global__ __launch_bounds__(256) void proj_k(const float* __restrict__ att,
                                              const unsigned short* __restrict__ Wpb,
                                              const float* __restrict__ b_proj,
                                              float* __restrict__ out){
  int tid = threadIdx.x, wv = tid >> 6, ln = tid & 63;
  int g = ln >> 4, r = ln & 15;
  long r0 = ((long)blockIdx.x*4 + wv)*16;
  const float* arow = att + (r0 + r)*48;
  float4 qa = *(const float4*)&arow[g*8];
  float4 qb = *(const float4*)&arow[g*8 + 4];
  uint4 u0 = { cvt2(qa.x,qa.y), cvt2(qa.z,qa.w), cvt2(qb.x,qb.y), cvt2(qb.z,qb.w) };
  bf16x8 a0 = u2b(u0);
  bf16x8 a1 = {0,0,0,0,0,0,0,0};
  if (g < 2){
    float4 qc = *(const float4*)&arow[32 + g*8];
    float4 qd = *(const float4*)&arow[36 + g*8];
    uint4 u1 = { cvt2(qc.x,qc.y), cvt2(qc.z,qc.w), cvt2(qd.x,qd.y), cvt2(qd.z,qd.w) };
    a1 = u2b(u1);
  }
  #pragma unroll
  for (int dt = 0; dt < 4; ++dt){
    f32x4 acc = {0.f,0.f,0.f,0.f};
    bf16x8 b0 = *(const bf16x8*)&Wpb[((0*4+g)*64 + dt*16 + r)*8];
    bf16x8 b1 = *(const bf16x8*)&Wpb[((1*4+g)*64 + dt*16 + r)*8];
    acc = __builtin_amdgcn_mfma_f32_16x16x32_bf16(a0, b0, acc, 0,0,0);
    acc = __builtin_amdgcn_mfma_f32_16x16x32_bf16(a1, b1, acc, 0,0,0);
    float bias = b_proj[dt*16 + r];
    #pragma unroll
    for (int rg = 0; rg < 4; ++rg)
      out[(r0 + g*4 + rg)*64 + dt*16 + r] = acc[rg] + bias;
  }
}

extern "C" void kernel_launch(void* const* d_in, const int* in_sizes, int n_in,
                              void* d_out, int out_size, void* d_ws, size_t ws_size,
                              hipStream_t stream){
  const float* x      = (const float*)d_in[0];
  const int*   ind    = (const int*)  d_in[1];
  const unsigned char* gmask_raw = (const unsigned char*)d_in[4];
  const float* p1     = (const float*)d_in[5];
  const float* p2     = (const float*)d_in[6];
  const float* p3     = (const float*)d_in[7];
  const float* pk     = (const float*)d_in[8];
  const float* W_r1   = (const float*)d_in[9];
  const float* b_r1   = (const float*)d_in[10];
  const float* W_gcn  = (const float*)d_in[11];
  const float* b_gcn  = (const float*)d_in[12];
  const float* W_r2   = (const float*)d_in[13];
  const float* b_r2   = (const float*)d_in[14];
  const float* Wtq    = (const float*)d_in[15];
  const float* Wtk    = (const float*)d_in[16];
  const float* Wtv    = (const float*)d_in[17];
  const float* Wgq    = (const float*)d_in[18];
  const float* Wgk    = (const float*)d_in[19];
  const float* Wgv    = (const float*)d_in[20];
  const float* W_proj = (const float*)d_in[21];
  const float* b_proj = (const float*)d_in[22];
  float* out = (float*)d_out;

  float* ws = (float*)d_ws;
  float* A1    = ws; ws += B_*DIMS_*DIMS_;
  float* bc    = ws; ws += 64;
  float* p3t   = ws; ws += DIMS_*N_;
  float* qkv48 = ws; ws += (size_t)B_*T_*N_*48;
  float* att   = ws; ws += (size_t)B_*T_*N_*48;
  unsigned* bm = (unsigned*)ws; ws += NQP*MW;
  unsigned short* us = (unsigned short*)ws;
  unsigned short* adp_bf = us; us += (size_t)B_*N_*VP;
  unsigned short* ht     = us; us += (size_t)B_*384*VP;
  unsigned short* x1t    = us; us += (size_t)B_*384*VP;
  unsigned short* hn     = us; us += (size_t)B_*N_*384;
  unsigned short* x1n    = us; us += (size_t)B_*N_*384;
  unsigned short* x2n    = us; us += (size_t)B_*N_*384;
  unsigned short* xg_bf  = us; us += (size_t)B_*T_*N_*64;
  unsigned short* Qg     = us; us += (size_t)192*4*N_*8;
  unsigned short* Kg     = us; us += (size_t)192*4*352*8;
  unsigned short* Vg     = us; us += (size_t)192*4*11*512;
  unsigned short* Wcb    = us; us += 3*4*64*8;
  unsigned short* Wallb  = us; us += 2*4*144*8;
  unsigned short* Wpb    = us; us += 2*4*64*8;
  unsigned short* Wr1b   = us; us += 2*4*32*8;

  setup_k     <<<37,        256, 0, stream>>>(p1, pk, ind, A1, gmask_raw, bm, p3, p3t,
                                              W_gcn, b_gcn, W_r2, b_r2,
                                              Wtq, Wtk, Wtv, Wgq, Wgk, Wgv,
                                              W_proj, W_r1, bc, Wcb, Wallb, Wpb, Wr1b);
  dg_adp      <<<B_*N_,     128, 0, stream>>>(p2, p3t, A1, adp_bf);
  hproj_mfma  <<<192*6,     256, 0, stream>>>(x, Wr1b, b_r1, ht, hn);
  gcn_mfma    <<<B_*36,     256, 0, stream>>>(adp_bf, ht,  x1t, x1n);
  gcn_mfma    <<<B_*36,     256, 0, stream>>>(adp_bf, x1t, (unsigned short*)nullptr, x2n);
  xg_k        <<<(B_*N_)/4, 256, 0, stream>>>(hn, x1n, x2n, Wcb, bc, xg_bf);
  qkv_k       <<<192*6,     256, 0, stream>>>(xg_bf, Wallb, qkv48, Qg, Kg, Vg);
  attn_fused  <<<4032+1300, 256, 0, stream>>>(qkv48, Qg, Kg, Vg, bm, att);
  proj_k      <<<(B_*T_*N_/16)/4, 256, 0, stream>>>(att, Wpb, b_proj, out);
}